// Round 3
// baseline (917.394 us; speedup 1.0000x reference)
//
#include <hip/hip_runtime.h>
#include <cmath>

// RWKV7 time-mixing, B=4 L=2048 D=1024 H=16 Dh=64. Inputs/outputs fp32; internal bf16.
// convert(lora wts) -> mix -> [r,k,v (B=f32)] + lora1 -> lora2 -> prep_pack(stream) ->
// scan v7 (512 blocks = 8 row-eighths/head XCD-colocated, 32 lanes/row, DPP+swizzle
//          reductions, reg-prefetched, LDS double-buffered global_load_lds batches)
// -> gnorm -> out GEMM.

#define DEV __device__ __forceinline__

typedef unsigned short u16;
typedef unsigned int u32;
typedef __bf16 bf16x8 __attribute__((ext_vector_type(8)));
typedef float f32x4 __attribute__((ext_vector_type(4)));

constexpr int Bx = 4, Lx = 2048, Dx = 1024, Hx = 16, Dh = 64;
constexpr int NTOK = Bx * Lx;       // 8192
constexpr float EPS_GN = 0.00064f;
constexpr int STEP_U16 = 384;       // 768B per step: r|k|a|b|v|w (64 bf16 each)
constexpr int TB = 16;              // steps per scan batch
constexpr int NB = Lx / TB;         // 128 batches
constexpr int BATCH_U16 = TB * STEP_U16;   // 6144 u16 = 12288 B

DEV float bf2f(u16 u) { union { u32 i; float f; } c; c.i = ((u32)u) << 16; return c.f; }
DEV u16 f2bf(float f) {
    union { float f; u32 i; } c; c.f = f;
    u32 r = c.i + 0x7FFFu + ((c.i >> 16) & 1u);
    return (u16)(r >> 16);
}
DEV void unpack2(u32 u, float& a, float& b) {
    union { u32 i; float f; } c0, c1;
    c0.i = u << 16; c1.i = u & 0xFFFF0000u;
    a = c0.f; b = c1.f;
}

// DPP butterfly add: returns v + v[lane ^ mask] for masks {1,2,7,15} via pure-VALU DPP.
// 0xB1 = quad_perm[1,0,3,2] (xor1), 0x4E = quad_perm[2,3,0,1] (xor2),
// 0x141 = row_half_mirror (xor7 after quads uniform), 0x140 = row_mirror (xor15).
template <int CTRL>
DEV float dpp_add(float v) {
    int p = __builtin_amdgcn_update_dpp(0, __float_as_int(v), CTRL, 0xF, 0xF, true);
    return v + __int_as_float(p);
}

// Full 32-lane-group reduce: DPP xor1,2,(7->4),(15->8) + ds_swizzle xor16 (BitMode 0x401F).
DEV float red32(float x) {
    x = dpp_add<0xB1>(x);
    x = dpp_add<0x4E>(x);
    x = dpp_add<0x141>(x);
    x = dpp_add<0x140>(x);
    x += __int_as_float(__builtin_amdgcn_ds_swizzle(__float_as_int(x), 0x401F));
    return x;
}

// ---------------- lora-weight f32 -> bf16 conversion (8 small tensors) ----------------
__global__ __launch_bounds__(256) void conv_kernel(
    const float* s0, const float* s1, const float* s2, const float* s3,
    const float* s4, const float* s5, const float* s6, const float* s7,
    u16* d0, u16* d1, u16* d2, u16* d3, u16* d4, u16* d5, u16* d6, u16* d7)
{
    const float* srcs[8] = {s0,s1,s2,s3,s4,s5,s6,s7};
    u16* dsts[8] = {d0,d1,d2,d3,d4,d5,d6,d7};
    const int ns[8] = {65536,65536,32768,32768,65536,65536,131072,131072};
    int t = blockIdx.y;
    int i = (blockIdx.x * 256 + threadIdx.x) * 4;
    if (i >= ns[t]) return;
    float4 v = *(const float4*)(srcs[t] + i);
    ushort4 o;
    o.x = f2bf(v.x); o.y = f2bf(v.y); o.z = f2bf(v.z); o.w = f2bf(v.w);
    *(ushort4*)(dsts[t] + i) = o;
}

// ---------------- token-shift mix ----------------
__global__ __launch_bounds__(256) void mix_kernel(
    const float* __restrict__ x,
    const float* __restrict__ mr, const float* __restrict__ mw, const float* __restrict__ mk,
    const float* __restrict__ mv, const float* __restrict__ ma, const float* __restrict__ mg,
    u16* __restrict__ XR, u16* __restrict__ XW, u16* __restrict__ XK,
    u16* __restrict__ XV, u16* __restrict__ XA, u16* __restrict__ XG)
{
    int gi = blockIdx.x * 256 + threadIdx.x;
    int n  = gi >> 8;
    int d4 = (gi & 255) << 2;
    int l  = n & (Lx - 1);
    size_t o = (size_t)n * Dx + d4;
    float4 xc = *(const float4*)(x + o);
    float4 xp = make_float4(0.f, 0.f, 0.f, 0.f);
    if (l != 0) xp = *(const float4*)(x + o - Dx);
    float dx0 = xp.x - xc.x, dx1 = xp.y - xc.y, dx2 = xp.z - xc.z, dx3 = xp.w - xc.w;
    const float* mvs[6] = {mr, mw, mk, mv, ma, mg};
    u16* dsts[6] = {XR, XW, XK, XV, XA, XG};
#pragma unroll
    for (int j = 0; j < 6; ++j) {
        float4 m = *(const float4*)(mvs[j] + d4);
        ushort4 r;
        r.x = f2bf(fmaf(dx0, m.x, xc.x));
        r.y = f2bf(fmaf(dx1, m.y, xc.y));
        r.z = f2bf(fmaf(dx2, m.z, xc.z));
        r.w = f2bf(fmaf(dx3, m.w, xc.w));
        *(ushort4*)(dsts[j] + o) = r;
    }
}

// ---------------- bf16 MFMA GEMM, C[M,N] = act(A[M,K] . B[N,K]^T + bias_f32) ----------------
// ACT: 0 none, 1 sigmoid, 2 tanh, 3 exp(-0.606531*sigmoid). BF32: B matrix is f32 (converted in staging).
template <int BN, int ACT, bool BIAS, bool F32OUT, bool BF32>
__global__ __launch_bounds__(256) void gemm_nt(
    const u16* __restrict__ A, const void* __restrict__ Bmv,
    const float* __restrict__ bias, void* __restrict__ Cv,
    int M, int N, int K)
{
    constexpr int BM = 128, BK = 32;
    constexpr int LDT = BK + 8;
    constexpr int WGM = (BN == 128) ? 2 : 4;
    constexpr int WGN = (BN == 128) ? 2 : 1;
    constexpr int WTM = BM / WGM, WTN = BN / WGN;
    constexpr int ITM = WTM / 16, ITN = WTN / 16;
    __shared__ __align__(16) u16 Asm[BM * LDT];
    __shared__ __align__(16) u16 Bsm[BN * LDT];
    const int tid = threadIdx.x;
    const int wid = tid >> 6, lane = tid & 63;
    const int q = lane >> 4, r16 = lane & 15;
    const size_t m0 = (size_t)blockIdx.x * BM;
    const size_t n0 = (size_t)blockIdx.y * BN;
    const int wm = (wid % WGM) * WTM;
    const int wn = (wid / WGM) * WTN;
    f32x4 acc[ITM][ITN];
    const f32x4 zf = {0.f, 0.f, 0.f, 0.f};
#pragma unroll
    for (int i = 0; i < ITM; ++i)
#pragma unroll
        for (int j = 0; j < ITN; ++j) acc[i][j] = zf;

    const u16* B16 = (const u16*)Bmv;
    const float* B32 = (const float*)Bmv;

    for (int k0 = 0; k0 < K; k0 += BK) {
#pragma unroll
        for (int it = 0; it < (BM * BK) / 2048; ++it) {
            int pp = tid * 8 + it * 2048;
            int row = pp >> 5, col = pp & 31;
            *(uint4*)&Asm[row * LDT + col] = *(const uint4*)(A + (m0 + row) * K + k0 + col);
        }
#pragma unroll
        for (int it = 0; it < (BN * BK + 2047) / 2048; ++it) {
            int pp = tid * 8 + it * 2048;
            if (BN * BK >= 2048 || pp < BN * BK) {
                int row = pp >> 5, col = pp & 31;
                if constexpr (BF32) {
                    float4 f0 = *(const float4*)(B32 + (n0 + row) * K + k0 + col);
                    float4 f1 = *(const float4*)(B32 + (n0 + row) * K + k0 + col + 4);
                    ushort4 o0, o1;
                    o0.x = f2bf(f0.x); o0.y = f2bf(f0.y); o0.z = f2bf(f0.z); o0.w = f2bf(f0.w);
                    o1.x = f2bf(f1.x); o1.y = f2bf(f1.y); o1.z = f2bf(f1.z); o1.w = f2bf(f1.w);
                    *(ushort4*)&Bsm[row * LDT + col] = o0;
                    *(ushort4*)&Bsm[row * LDT + col + 4] = o1;
                } else {
                    *(uint4*)&Bsm[row * LDT + col] = *(const uint4*)(B16 + (n0 + row) * K + k0 + col);
                }
            }
        }
        __syncthreads();
        bf16x8 af[ITM], bfr[ITN];
#pragma unroll
        for (int im = 0; im < ITM; ++im)
            af[im] = *(const bf16x8*)&Asm[(wm + im * 16 + r16) * LDT + q * 8];
#pragma unroll
        for (int in = 0; in < ITN; ++in)
            bfr[in] = *(const bf16x8*)&Bsm[(wn + in * 16 + r16) * LDT + q * 8];
#pragma unroll
        for (int im = 0; im < ITM; ++im)
#pragma unroll
            for (int in = 0; in < ITN; ++in)
                acc[im][in] = __builtin_amdgcn_mfma_f32_16x16x32_bf16(af[im], bfr[in], acc[im][in], 0, 0, 0);
        __syncthreads();
    }
#pragma unroll
    for (int im = 0; im < ITM; ++im) {
#pragma unroll
        for (int in = 0; in < ITN; ++in) {
#pragma unroll
            for (int e = 0; e < 4; ++e) {
                size_t row = m0 + wm + im * 16 + q * 4 + e;
                size_t col = n0 + wn + in * 16 + r16;
                float val = acc[im][in][e];
                if constexpr (BIAS) val += bias[col];
                if constexpr (ACT == 1) val = 1.f / (1.f + __expf(-val));
                else if constexpr (ACT == 2) val = tanhf(val);
                else if constexpr (ACT == 3) val = __expf(-0.606531f / (1.f + __expf(-val)));
                if constexpr (F32OUT) ((float*)Cv)[row * (size_t)N + col] = val;
                else ((u16*)Cv)[row * (size_t)N + col] = f2bf(val);
            }
        }
    }
}

// ---------------- prep + pack: kk-norm, a/b, k/v updates, emit packed stream ----------------
__global__ __launch_bounds__(256) void prep_pack_kernel(
    u16* __restrict__ Kb, u16* __restrict__ Vb,
    const u16* __restrict__ Rb, const u16* __restrict__ Wd16,
    const u16* __restrict__ ICLR, const u16* __restrict__ VVb, const float* __restrict__ vfirst,
    const float* __restrict__ k_k, const float* __restrict__ k_a,
    u16* __restrict__ stream)
{
    int g = blockIdx.x * 4 + (threadIdx.x >> 6);   // (token,head) pair: n = g>>4, h = g&15
    int lane = threadIdx.x & 63;
    int h = g & (Hx - 1);
    int n = g >> 4;
    size_t idx = (size_t)g * 64 + lane;            // == n*1024 + h*64 + lane
    int hd = h * 64 + lane;
    int l = n & (Lx - 1), b = n >> 11;
    size_t so = ((size_t)((b * 16 + h) * Lx + l)) * STEP_U16;

    float k = bf2f(Kb[idx]);
    float iclr = bf2f(ICLR[idx]);
    float kkn = k * k_k[hd];
    float s = kkn * kkn;
#pragma unroll
    for (int off = 32; off > 0; off >>= 1) s += __shfl_xor(s, off, 64);
    float nrm = fmaxf(sqrtf(s), 1e-7f);
    float kk = kkn / nrm;
    u16 knew = f2bf(k * (1.f + (iclr - 1.f) * k_a[hd]));
    float v = bf2f(Vb[idx]), vv = bf2f(VVb[idx]), vf = vfirst[idx];
    u16 vnew = f2bf(fmaf(vf - v, vv, v));
    Kb[idx] = knew;
    Vb[idx] = vnew;
    stream[so + lane]       = Rb[idx];
    stream[so + 64 + lane]  = knew;
    stream[so + 128 + lane] = f2bf(-kk);
    stream[so + 192 + lane] = f2bf(kk * iclr);
    stream[so + 256 + lane] = vnew;
    stream[so + 320 + lane] = Wd16[idx];
}

// ---------------- WKV7 scan v7 ----------------
// 512 blocks = 64 (b,h) x 8 row-eighths, XCD-swizzled so all 8 blocks of a (b,h)
// land on one XCD (L2 serves the duplicated stream reads). 4 waves/block;
// wave = 2 rows x 32 lanes/row; lane: rhalf=lane>>5, col=lane&31 (cols 2col,2col+1).
// S[2]/thread. Row reduce: 4 DPP (xor1,2,4,8) + ds_swizzle xor16.
// 2 waves/SIMD (2048 waves total) hide the serial-chain stalls.
__global__ __launch_bounds__(256, 2) void scan_kernel(
    const u16* __restrict__ stream, float* __restrict__ Y)
{
    const int bid = blockIdx.x;                   // 0..511; dispatch round-robins XCDs
    const int xcd = bid & 7, slot = bid >> 3;
    const int bh = xcd + ((slot & 7) << 3);       // 0..63: bh%8 == XCD -> co-located
    const int part = slot >> 3;                   // 0..7 (8 rows each)
    const int tid = threadIdx.x;
    const int lane = tid & 63;
    const int w = tid >> 6;
    const int col = lane & 31;                    // owns cols 2col, 2col+1
    const int rhalf = lane >> 5;
    const int lr = w * 2 + rhalf;                 // local row 0..7
    const int row = part * 8 + lr;                // global row 0..63
    const size_t sbase = (size_t)bh * Lx * STEP_U16;
    const size_t ybase = (size_t)(bh >> 4) * ((size_t)Lx * Dx) + (size_t)(bh & 15) * 64;

    __shared__ __align__(16) u16 sbuf[2 * BATCH_U16];   // 24 KB
    __shared__ __align__(16) float ylds[TB * 8];        // 0.5 KB

    float S0 = 0.f, S1 = 0.f;

    // stage batch 0 into buf 0 (wave w handles 1KB chunks 3w..3w+2)
    {
        const u16* g = stream + sbase;
#pragma unroll
        for (int c = 0; c < 3; ++c) {
            const u16* gp = g + (3 * w + c) * 512 + lane * 8;
            u16* lp = sbuf + (3 * w + c) * 512;
            __builtin_amdgcn_global_load_lds(
                (const __attribute__((address_space(1))) void*)gp,
                (__attribute__((address_space(3))) void*)lp, 16, 0, 0);
        }
    }

    for (int bt = 0; bt < NB; ++bt) {
        const int cur = bt & 1;
        __syncthreads();   // vmcnt(0): batch bt resident; ylds free from prev flush
        if (bt + 1 < NB) {
            const u16* g = stream + sbase + (size_t)(bt + 1) * BATCH_U16;
            u16* lbase = sbuf + (1 - cur) * BATCH_U16;
#pragma unroll
            for (int c = 0; c < 3; ++c) {
                const u16* gp = g + (3 * w + c) * 512 + lane * 8;
                u16* lp = lbase + (3 * w + c) * 512;
                __builtin_amdgcn_global_load_lds(
                    (const __attribute__((address_space(1))) void*)gp,
                    (__attribute__((address_space(3))) void*)lp, 16, 0, 0);
            }
        }
        const u16* bp = sbuf + cur * BATCH_U16;
        const u16* cp = bp + col * 2;             // byte offset col*4: cols 2col,2col+1
        u32 r2 = *(const u32*)(cp);
        u32 k2 = *(const u32*)(cp + 64);
        u32 a2 = *(const u32*)(cp + 128);
        u32 b2 = *(const u32*)(cp + 192);
        u32 w2 = *(const u32*)(cp + 320);
        float v = bf2f(bp[256 + row]);
#pragma unroll
        for (int s = 0; s < TB; ++s) {
            u32 nr = 0, nk = 0, na = 0, nb = 0, nw = 0;
            float nv = 0.f;
            if (s + 1 < TB) {          // compile-time under full unroll
                const u16* np = cp + (s + 1) * STEP_U16;
                nr = *(const u32*)(np);
                nk = *(const u32*)(np + 64);
                na = *(const u32*)(np + 128);
                nb = *(const u32*)(np + 192);
                nw = *(const u32*)(np + 320);
                nv = bf2f(bp[(s + 1) * STEP_U16 + 256 + row]);
            }
            float rr0, rr1, kk0, kk1, aa0, aa1, bb0, bb1, ww0, ww1;
            unpack2(r2, rr0, rr1);
            unpack2(k2, kk0, kk1);
            unpack2(a2, aa0, aa1);
            unpack2(b2, bb0, bb1);
            unpack2(w2, ww0, ww1);
            // sa_i = sum_j S_ij * a_j  (2 local + 32-lane reduce)
            float sa = fmaf(S1, aa1, S0 * aa0);
            sa = red32(sa);
            // S_ij = S_ij*w_j + v_i*k_j + sa_i*b_j ; y_i = sum_j S_ij*r_j
            float t0 = fmaf(v, kk0, sa * bb0);
            float t1 = fmaf(v, kk1, sa * bb1);
            S0 = fmaf(S0, ww0, t0);
            S1 = fmaf(S1, ww1, t1);
            float y = fmaf(S1, rr1, S0 * rr0);
            y = red32(y);
            if (col == 0) ylds[s * 8 + lr] = y;
            r2 = nr; k2 = nk; a2 = na; b2 = nb; w2 = nw; v = nv;
        }
        __syncthreads();   // ylds visible; batch bt+1 loads still in flight (vmem)
        // flush: 128 threads x 1 float = 128 = 16 steps x 8 rows
        if (tid < TB * 8) {
            int s = tid >> 3, j = tid & 7;
            Y[ybase + (size_t)(bt * TB + s) * Dx + part * 8 + j] = ylds[s * 8 + j];
        }
    }
}

// ---------------- group-norm + rkr residual + gate (OG in-place over GATE) ----------------
__global__ __launch_bounds__(256) void gnorm_kernel(
    const float* __restrict__ Y, const u16* __restrict__ Rb, const u16* __restrict__ Kb,
    const u16* __restrict__ Vb, const float* __restrict__ r_k,
    const float* __restrict__ gnw, const float* __restrict__ gnb,
    u16* __restrict__ GATE_OG)
{
    int g = blockIdx.x * 4 + (threadIdx.x >> 6);
    int lane = threadIdx.x & 63;
    int h = g & (Hx - 1);
    size_t idx = (size_t)g * 64 + lane;
    int hd = h * 64 + lane;
    float y = Y[idx];
    float r = bf2f(Rb[idx]), k = bf2f(Kb[idx]), v = bf2f(Vb[idx]);
    float rkr = r * k * r_k[hd];
    float s1 = y, s2 = y * y, s3 = rkr;
#pragma unroll
    for (int off = 32; off > 0; off >>= 1) {
        s1 += __shfl_xor(s1, off, 64);
        s2 += __shfl_xor(s2, off, 64);
        s3 += __shfl_xor(s3, off, 64);
    }
    float mean = s1 * (1.f / 64.f);
    float var  = s2 * (1.f / 64.f) - mean * mean;
    float inv = 1.f / sqrtf(var + EPS_GN);
    float o = gnw[hd] * ((y - mean) * inv) + gnb[hd];
    o += s3 * v;
    GATE_OG[idx] = f2bf(o * bf2f(GATE_OG[idx]));
}

// ---------------- launch ----------------
extern "C" void kernel_launch(void* const* d_in, const int* in_sizes, int n_in,
                              void* d_out, int out_size, void* d_ws, size_t ws_size,
                              hipStream_t stream_)
{
    const float* x      = (const float*)d_in[0];
    const float* vfirst = (const float*)d_in[1];
    const float* x_r = (const float*)d_in[2];
    const float* x_w = (const float*)d_in[3];
    const float* x_k = (const float*)d_in[4];
    const float* x_v = (const float*)d_in[5];
    const float* x_a = (const float*)d_in[6];
    const float* x_g = (const float*)d_in[7];
    const float* k_k = (const float*)d_in[8];
    const float* k_a = (const float*)d_in[9];
    const float* r_k = (const float*)d_in[10];
    const float* Wr  = (const float*)d_in[11];
    const float* Wk  = (const float*)d_in[12];
    const float* Wv  = (const float*)d_in[13];
    const float* Wo  = (const float*)d_in[14];
    const float* gnw = (const float*)d_in[15];
    const float* gnb = (const float*)d_in[16];
    const float* wA  = (const float*)d_in[17];
    const float* wB  = (const float*)d_in[18];
    const float* wb  = (const float*)d_in[19];
    const float* vA  = (const float*)d_in[20];
    const float* vB  = (const float*)d_in[21];
    const float* vb  = (const float*)d_in[22];
    const float* aA  = (const float*)d_in[23];
    const float* aB  = (const float*)d_in[24];
    const float* ab  = (const float*)d_in[25];
    const float* gA  = (const float*)d_in[26];
    const float* gB  = (const float*)d_in[27];

    char* ws = (char*)d_ws;
    const size_t SLOT = (size_t)NTOK * Dx * 2;   // 16 MiB; 14 slots total (224 MiB, proven)
    u16* XR = (u16*)(ws + 0 * SLOT);
    u16* XW = (u16*)(ws + 1 * SLOT);
    u16* XK = (u16*)(ws + 2 * SLOT);
    u16* XV = (u16*)(ws + 3 * SLOT);
    u16* XA = (u16*)(ws + 4 * SLOT);
    u16* XG = (u16*)(ws + 5 * SLOT);
    u16* STREAM = (u16*)(ws + 0 * SLOT);         // 96MB, overwrites XR..XG after consumption
    u16* Rbuf = (u16*)(ws + 6 * SLOT);
    u16* Kbuf = (u16*)(ws + 7 * SLOT);
    u16* Vbuf = (u16*)(ws + 8 * SLOT);
    u16* HW = (u16*)(ws + 9 * SLOT);             // lora hiddens (4.7MB)
    u16* HA = HW + (size_t)NTOK * 64;
    u16* HV = HA + (size_t)NTOK * 64;
    u16* HG = HV + (size_t)NTOK * 32;
    u16* SW = (u16*)(ws + 9 * SLOT + 8 * 1024 * 1024);  // small bf16 weights (1.2MB)
    u16* wAB = SW;
    u16* wBB = wAB + 65536;
    u16* vAB = wBB + 65536;
    u16* vBB = vAB + 32768;
    u16* aAB = vBB + 32768;
    u16* aBB = aAB + 65536;
    u16* gAB = aBB + 65536;
    u16* gBB = gAB + 131072;
    u16* Wdec16 = (u16*)(ws + 10 * SLOT);        // bf16 decay; dead after prep_pack
    u16* ICLR   = (u16*)(ws + 11 * SLOT);        // dead after prep_pack
    u16* VVb    = (u16*)(ws + 12 * SLOT);        // dead after prep_pack
    float* Yb   = (float*)(ws + 10 * SLOT);      // fp32, slots 10-11 (aliases Wdec16/ICLR, ordered)
    u16* GATE   = (u16*)(ws + 13 * SLOT);        // gnorm writes OG in-place

    dim3 blk(256);
    conv_kernel<<<dim3(128, 8), blk, 0, stream_>>>(wA, wB, vA, vB, aA, aB, gA, gB,
                                                   wAB, wBB, vAB, vBB, aAB, aBB, gAB, gBB);
    mix_kernel<<<(NTOK * Dx / 4) / 256, blk, 0, stream_>>>(x, x_r, x_w, x_k, x_v, x_a, x_g,
                                                           XR, XW, XK, XV, XA, XG);
    // big projections (B = f32 weights, converted in staging)
    gemm_nt<128, 0, false, false, true><<<dim3(64, 8), blk, 0, stream_>>>(XR, Wr, nullptr, Rbuf, NTOK, 1024, 1024);
    gemm_nt<128, 0, false, false, true><<<dim3(64, 8), blk, 0, stream_>>>(XK, Wk, nullptr, Kbuf, NTOK, 1024, 1024);
    gemm_nt<128, 0, false, false, true><<<dim3(64, 8), blk, 0, stream_>>>(XV, Wv, nullptr, Vbuf, NTOK, 1024, 1024);
    // lora stage 1
    gemm_nt<64, 2, false, false, false><<<dim3(64, 1), blk, 0, stream_>>>(XW, wAB, nullptr, HW, NTOK, 64, 1024);
    gemm_nt<64, 0, false, false, false><<<dim3(64, 1), blk, 0, stream_>>>(XA, aAB, nullptr, HA, NTOK, 64, 1024);
    gemm_nt<32, 0, false, false, false><<<dim3(64, 1), blk, 0, stream_>>>(XV, vAB, nullptr, HV, NTOK, 32, 1024);
    gemm_nt<128, 1, false, false, false><<<dim3(64, 1), blk, 0, stream_>>>(XG, gAB, nullptr, HG, NTOK, 128, 1024);
    // lora stage 2
    gemm_nt<128, 3, true,  false, false><<<dim3(64, 8), blk, 0, stream_>>>(HW, wBB, wb, Wdec16, NTOK, 1024, 64);
    gemm_nt<128, 1, true,  false, false><<<dim3(64, 8), blk, 0, stream_>>>(HA, aBB, ab, ICLR, NTOK, 1024, 64);
    gemm_nt<128, 1, true,  false, false><<<dim3(64, 8), blk, 0, stream_>>>(HV, vBB, vb, VVb, NTOK, 1024, 32);
    gemm_nt<128, 0, false, false, false><<<dim3(64, 8), blk, 0, stream_>>>(HG, gBB, nullptr, GATE, NTOK, 1024, 128);

    prep_pack_kernel<<<(NTOK * Hx) / 4, blk, 0, stream_>>>(Kbuf, Vbuf, Rbuf, Wdec16, ICLR, VVb,
                                                           vfirst, k_k, k_a, STREAM);
    scan_kernel<<<512, blk, 0, stream_>>>(STREAM, Yb);
    gnorm_kernel<<<(NTOK * Hx) / 4, blk, 0, stream_>>>(Yb, Rbuf, Kbuf, Vbuf, r_k, gnw, gnb, GATE);
    gemm_nt<128, 0, false, true, true><<<dim3(64, 8), blk, 0, stream_>>>(GATE, Wo, nullptr, d_out, NTOK, 1024, 1024);
}

// Round 4
// 897.679 us; speedup vs baseline: 1.0220x; 1.0220x over previous
//
#include <hip/hip_runtime.h>
#include <cmath>

// RWKV7 time-mixing, B=4 L=2048 D=1024 H=16 Dh=64. Inputs/outputs fp32; internal bf16.
// convert(lora wts) -> mix -> [r,k,v (B=f32)] + lora1 -> lora2 -> prep_pack(stream) ->
// scan v8 (512 blocks = 8 row-eighths/head XCD-colocated; 32-lane rows SPLIT as
//          lanes {0-15,32-47}/{16-31,48-63} so the cross-16 reduce hop is a pure-VALU
//          v_permlane32_swap_b32; 4xDPP + permlane reduce; reg-prefetched; LDS
//          double-buffered global_load_lds batches) -> gnorm -> out GEMM.

#define DEV __device__ __forceinline__

typedef unsigned short u16;
typedef unsigned int u32;
typedef __bf16 bf16x8 __attribute__((ext_vector_type(8)));
typedef float f32x4 __attribute__((ext_vector_type(4)));

constexpr int Bx = 4, Lx = 2048, Dx = 1024, Hx = 16, Dh = 64;
constexpr int NTOK = Bx * Lx;       // 8192
constexpr float EPS_GN = 0.00064f;
constexpr int STEP_U16 = 384;       // 768B per step: r|k|a|b|v|w (64 bf16 each)
constexpr int TB = 16;              // steps per scan batch
constexpr int NB = Lx / TB;         // 128 batches
constexpr int BATCH_U16 = TB * STEP_U16;   // 6144 u16 = 12288 B

DEV float bf2f(u16 u) { union { u32 i; float f; } c; c.i = ((u32)u) << 16; return c.f; }
DEV u16 f2bf(float f) {
    union { float f; u32 i; } c; c.f = f;
    u32 r = c.i + 0x7FFFu + ((c.i >> 16) & 1u);
    return (u16)(r >> 16);
}
DEV void unpack2(u32 u, float& a, float& b) {
    union { u32 i; float f; } c0, c1;
    c0.i = u << 16; c1.i = u & 0xFFFF0000u;
    a = c0.f; b = c1.f;
}

// DPP butterfly add: returns v + v[lane ^ mask] for masks {1,2,7,15} via pure-VALU DPP.
// 0xB1 = quad_perm[1,0,3,2] (xor1), 0x4E = quad_perm[2,3,0,1] (xor2),
// 0x141 = row_half_mirror (xor7 == xor4 once quads uniform), 0x140 = row_mirror (xor15).
template <int CTRL>
DEV float dpp_add(float v) {
    int p = __builtin_amdgcn_update_dpp(0, __float_as_int(v), CTRL, 0xF, 0xF, true);
    return v + __int_as_float(p);
}

// xor32 add via v_permlane32_swap_b32 (pure VALU): t.x/t.y are the two half-crossed
// registers; t.x + t.y == p[lane] + p[lane^32] in every lane.
DEV float xor32_add(float x) {
    float a = x, b = x;
    asm volatile("s_nop 1\n\tv_permlane32_swap_b32 %0, %1" : "+v"(a), "+v"(b));
    return a + b;
}

// Full reduce over a 32-lane row laid out as a 16-group pair {G, G^2} (lanes i, i+32):
// 4 DPP hops (16-group sums) + xor32 cross. All VALU, no LDS pipe.
DEV float red32(float x) {
    x = dpp_add<0xB1>(x);
    x = dpp_add<0x4E>(x);
    x = dpp_add<0x141>(x);
    x = dpp_add<0x140>(x);
    return xor32_add(x);
}

// ---------------- lora-weight f32 -> bf16 conversion (8 small tensors) ----------------
__global__ __launch_bounds__(256) void conv_kernel(
    const float* s0, const float* s1, const float* s2, const float* s3,
    const float* s4, const float* s5, const float* s6, const float* s7,
    u16* d0, u16* d1, u16* d2, u16* d3, u16* d4, u16* d5, u16* d6, u16* d7)
{
    const float* srcs[8] = {s0,s1,s2,s3,s4,s5,s6,s7};
    u16* dsts[8] = {d0,d1,d2,d3,d4,d5,d6,d7};
    const int ns[8] = {65536,65536,32768,32768,65536,65536,131072,131072};
    int t = blockIdx.y;
    int i = (blockIdx.x * 256 + threadIdx.x) * 4;
    if (i >= ns[t]) return;
    float4 v = *(const float4*)(srcs[t] + i);
    ushort4 o;
    o.x = f2bf(v.x); o.y = f2bf(v.y); o.z = f2bf(v.z); o.w = f2bf(v.w);
    *(ushort4*)(dsts[t] + i) = o;
}

// ---------------- token-shift mix ----------------
__global__ __launch_bounds__(256) void mix_kernel(
    const float* __restrict__ x,
    const float* __restrict__ mr, const float* __restrict__ mw, const float* __restrict__ mk,
    const float* __restrict__ mv, const float* __restrict__ ma, const float* __restrict__ mg,
    u16* __restrict__ XR, u16* __restrict__ XW, u16* __restrict__ XK,
    u16* __restrict__ XV, u16* __restrict__ XA, u16* __restrict__ XG)
{
    int gi = blockIdx.x * 256 + threadIdx.x;
    int n  = gi >> 8;
    int d4 = (gi & 255) << 2;
    int l  = n & (Lx - 1);
    size_t o = (size_t)n * Dx + d4;
    float4 xc = *(const float4*)(x + o);
    float4 xp = make_float4(0.f, 0.f, 0.f, 0.f);
    if (l != 0) xp = *(const float4*)(x + o - Dx);
    float dx0 = xp.x - xc.x, dx1 = xp.y - xc.y, dx2 = xp.z - xc.z, dx3 = xp.w - xc.w;
    const float* mvs[6] = {mr, mw, mk, mv, ma, mg};
    u16* dsts[6] = {XR, XW, XK, XV, XA, XG};
#pragma unroll
    for (int j = 0; j < 6; ++j) {
        float4 m = *(const float4*)(mvs[j] + d4);
        ushort4 r;
        r.x = f2bf(fmaf(dx0, m.x, xc.x));
        r.y = f2bf(fmaf(dx1, m.y, xc.y));
        r.z = f2bf(fmaf(dx2, m.z, xc.z));
        r.w = f2bf(fmaf(dx3, m.w, xc.w));
        *(ushort4*)(dsts[j] + o) = r;
    }
}

// ---------------- bf16 MFMA GEMM, C[M,N] = act(A[M,K] . B[N,K]^T + bias_f32) ----------------
// ACT: 0 none, 1 sigmoid, 2 tanh, 3 exp(-0.606531*sigmoid). BF32: B matrix is f32 (converted in staging).
template <int BN, int ACT, bool BIAS, bool F32OUT, bool BF32>
__global__ __launch_bounds__(256) void gemm_nt(
    const u16* __restrict__ A, const void* __restrict__ Bmv,
    const float* __restrict__ bias, void* __restrict__ Cv,
    int M, int N, int K)
{
    constexpr int BM = 128, BK = 32;
    constexpr int LDT = BK + 8;
    constexpr int WGM = (BN == 128) ? 2 : 4;
    constexpr int WGN = (BN == 128) ? 2 : 1;
    constexpr int WTM = BM / WGM, WTN = BN / WGN;
    constexpr int ITM = WTM / 16, ITN = WTN / 16;
    __shared__ __align__(16) u16 Asm[BM * LDT];
    __shared__ __align__(16) u16 Bsm[BN * LDT];
    const int tid = threadIdx.x;
    const int wid = tid >> 6, lane = tid & 63;
    const int q = lane >> 4, r16 = lane & 15;
    const size_t m0 = (size_t)blockIdx.x * BM;
    const size_t n0 = (size_t)blockIdx.y * BN;
    const int wm = (wid % WGM) * WTM;
    const int wn = (wid / WGM) * WTN;
    f32x4 acc[ITM][ITN];
    const f32x4 zf = {0.f, 0.f, 0.f, 0.f};
#pragma unroll
    for (int i = 0; i < ITM; ++i)
#pragma unroll
        for (int j = 0; j < ITN; ++j) acc[i][j] = zf;

    const u16* B16 = (const u16*)Bmv;
    const float* B32 = (const float*)Bmv;

    for (int k0 = 0; k0 < K; k0 += BK) {
#pragma unroll
        for (int it = 0; it < (BM * BK) / 2048; ++it) {
            int pp = tid * 8 + it * 2048;
            int row = pp >> 5, col = pp & 31;
            *(uint4*)&Asm[row * LDT + col] = *(const uint4*)(A + (m0 + row) * K + k0 + col);
        }
#pragma unroll
        for (int it = 0; it < (BN * BK + 2047) / 2048; ++it) {
            int pp = tid * 8 + it * 2048;
            if (BN * BK >= 2048 || pp < BN * BK) {
                int row = pp >> 5, col = pp & 31;
                if constexpr (BF32) {
                    float4 f0 = *(const float4*)(B32 + (n0 + row) * K + k0 + col);
                    float4 f1 = *(const float4*)(B32 + (n0 + row) * K + k0 + col + 4);
                    ushort4 o0, o1;
                    o0.x = f2bf(f0.x); o0.y = f2bf(f0.y); o0.z = f2bf(f0.z); o0.w = f2bf(f0.w);
                    o1.x = f2bf(f1.x); o1.y = f2bf(f1.y); o1.z = f2bf(f1.z); o1.w = f2bf(f1.w);
                    *(ushort4*)&Bsm[row * LDT + col] = o0;
                    *(ushort4*)&Bsm[row * LDT + col + 4] = o1;
                } else {
                    *(uint4*)&Bsm[row * LDT + col] = *(const uint4*)(B16 + (n0 + row) * K + k0 + col);
                }
            }
        }
        __syncthreads();
        bf16x8 af[ITM], bfr[ITN];
#pragma unroll
        for (int im = 0; im < ITM; ++im)
            af[im] = *(const bf16x8*)&Asm[(wm + im * 16 + r16) * LDT + q * 8];
#pragma unroll
        for (int in = 0; in < ITN; ++in)
            bfr[in] = *(const bf16x8*)&Bsm[(wn + in * 16 + r16) * LDT + q * 8];
#pragma unroll
        for (int im = 0; im < ITM; ++im)
#pragma unroll
            for (int in = 0; in < ITN; ++in)
                acc[im][in] = __builtin_amdgcn_mfma_f32_16x16x32_bf16(af[im], bfr[in], acc[im][in], 0, 0, 0);
        __syncthreads();
    }
#pragma unroll
    for (int im = 0; im < ITM; ++im) {
#pragma unroll
        for (int in = 0; in < ITN; ++in) {
#pragma unroll
            for (int e = 0; e < 4; ++e) {
                size_t row = m0 + wm + im * 16 + q * 4 + e;
                size_t col = n0 + wn + in * 16 + r16;
                float val = acc[im][in][e];
                if constexpr (BIAS) val += bias[col];
                if constexpr (ACT == 1) val = 1.f / (1.f + __expf(-val));
                else if constexpr (ACT == 2) val = tanhf(val);
                else if constexpr (ACT == 3) val = __expf(-0.606531f / (1.f + __expf(-val)));
                if constexpr (F32OUT) ((float*)Cv)[row * (size_t)N + col] = val;
                else ((u16*)Cv)[row * (size_t)N + col] = f2bf(val);
            }
        }
    }
}

// ---------------- prep + pack: kk-norm, a/b, k/v updates, emit packed stream ----------------
__global__ __launch_bounds__(256) void prep_pack_kernel(
    u16* __restrict__ Kb, u16* __restrict__ Vb,
    const u16* __restrict__ Rb, const u16* __restrict__ Wd16,
    const u16* __restrict__ ICLR, const u16* __restrict__ VVb, const float* __restrict__ vfirst,
    const float* __restrict__ k_k, const float* __restrict__ k_a,
    u16* __restrict__ stream)
{
    int g = blockIdx.x * 4 + (threadIdx.x >> 6);   // (token,head) pair: n = g>>4, h = g&15
    int lane = threadIdx.x & 63;
    int h = g & (Hx - 1);
    int n = g >> 4;
    size_t idx = (size_t)g * 64 + lane;            // == n*1024 + h*64 + lane
    int hd = h * 64 + lane;
    int l = n & (Lx - 1), b = n >> 11;
    size_t so = ((size_t)((b * 16 + h) * Lx + l)) * STEP_U16;

    float k = bf2f(Kb[idx]);
    float iclr = bf2f(ICLR[idx]);
    float kkn = k * k_k[hd];
    float s = kkn * kkn;
#pragma unroll
    for (int off = 32; off > 0; off >>= 1) s += __shfl_xor(s, off, 64);
    float nrm = fmaxf(sqrtf(s), 1e-7f);
    float kk = kkn / nrm;
    u16 knew = f2bf(k * (1.f + (iclr - 1.f) * k_a[hd]));
    float v = bf2f(Vb[idx]), vv = bf2f(VVb[idx]), vf = vfirst[idx];
    u16 vnew = f2bf(fmaf(vf - v, vv, v));
    Kb[idx] = knew;
    Vb[idx] = vnew;
    stream[so + lane]       = Rb[idx];
    stream[so + 64 + lane]  = knew;
    stream[so + 128 + lane] = f2bf(-kk);
    stream[so + 192 + lane] = f2bf(kk * iclr);
    stream[so + 256 + lane] = vnew;
    stream[so + 320 + lane] = Wd16[idx];
}

// ---------------- WKV7 scan v8 ----------------
// 512 blocks = 64 (b,h) x 8 row-eighths, XCD-swizzled so all 8 blocks of a (b,h)
// land on one XCD (L2 serves the duplicated stream reads). 4 waves/block;
// wave = 2 rows x 32 lanes/row, but a row's 32 lanes are the 16-group pair
// {0-15 U 32-47} (row A) / {16-31 U 48-63} (row B), so the cross-16 combine is
// xor32 = v_permlane32_swap (pure VALU). lane: c=(lane&15)|((lane>>1)&16) owns
// cols 2c,2c+1; rhalf=(lane>>4)&1. S[2]/thread. 2 waves/SIMD hide chain stalls.
__global__ __launch_bounds__(256, 2) void scan_kernel(
    const u16* __restrict__ stream, float* __restrict__ Y)
{
    const int bid = blockIdx.x;                   // 0..511; dispatch round-robins XCDs
    const int xcd = bid & 7, slot = bid >> 3;
    const int bh = xcd + ((slot & 7) << 3);       // 0..63: bh%8 == XCD -> co-located
    const int part = slot >> 3;                   // 0..7 (8 rows each)
    const int tid = threadIdx.x;
    const int lane = tid & 63;
    const int w = tid >> 6;
    const int c = (lane & 15) | ((lane >> 1) & 16);   // col-pair idx 0..31 (cols 2c,2c+1)
    const int rhalf = (lane >> 4) & 1;
    const int lr = w * 2 + rhalf;                 // local row 0..7
    const int row = part * 8 + lr;                // global row 0..63
    const size_t sbase = (size_t)bh * Lx * STEP_U16;
    const size_t ybase = (size_t)(bh >> 4) * ((size_t)Lx * Dx) + (size_t)(bh & 15) * 64;

    __shared__ __align__(16) u16 sbuf[2 * BATCH_U16];   // 24 KB
    __shared__ __align__(16) float ylds[TB * 8];        // 0.5 KB

    float S0 = 0.f, S1 = 0.f;

    // stage batch 0 into buf 0 (wave w handles 1KB chunks 3w..3w+2)
    {
        const u16* g = stream + sbase;
#pragma unroll
        for (int cc = 0; cc < 3; ++cc) {
            const u16* gp = g + (3 * w + cc) * 512 + lane * 8;
            u16* lp = sbuf + (3 * w + cc) * 512;
            __builtin_amdgcn_global_load_lds(
                (const __attribute__((address_space(1))) void*)gp,
                (__attribute__((address_space(3))) void*)lp, 16, 0, 0);
        }
    }

    for (int bt = 0; bt < NB; ++bt) {
        const int cur = bt & 1;
        __syncthreads();   // vmcnt(0): batch bt resident; ylds free from prev flush
        if (bt + 1 < NB) {
            const u16* g = stream + sbase + (size_t)(bt + 1) * BATCH_U16;
            u16* lbase = sbuf + (1 - cur) * BATCH_U16;
#pragma unroll
            for (int cc = 0; cc < 3; ++cc) {
                const u16* gp = g + (3 * w + cc) * 512 + lane * 8;
                u16* lp = lbase + (3 * w + cc) * 512;
                __builtin_amdgcn_global_load_lds(
                    (const __attribute__((address_space(1))) void*)gp,
                    (__attribute__((address_space(3))) void*)lp, 16, 0, 0);
            }
        }
        const u16* bp = sbuf + cur * BATCH_U16;
        const u16* cp = bp + c * 2;               // u16 offset 2c: cols 2c,2c+1
        u32 r2 = *(const u32*)(cp);
        u32 k2 = *(const u32*)(cp + 64);
        u32 a2 = *(const u32*)(cp + 128);
        u32 b2 = *(const u32*)(cp + 192);
        u32 w2 = *(const u32*)(cp + 320);
        float v = bf2f(bp[256 + row]);
#pragma unroll
        for (int s = 0; s < TB; ++s) {
            u32 nr = 0, nk = 0, na = 0, nb = 0, nw = 0;
            float nv = 0.f;
            if (s + 1 < TB) {          // compile-time under full unroll
                const u16* np = cp + (s + 1) * STEP_U16;
                nr = *(const u32*)(np);
                nk = *(const u32*)(np + 64);
                na = *(const u32*)(np + 128);
                nb = *(const u32*)(np + 192);
                nw = *(const u32*)(np + 320);
                nv = bf2f(bp[(s + 1) * STEP_U16 + 256 + row]);
            }
            float rr0, rr1, kk0, kk1, aa0, aa1, bb0, bb1, ww0, ww1;
            unpack2(r2, rr0, rr1);
            unpack2(k2, kk0, kk1);
            unpack2(a2, aa0, aa1);
            unpack2(b2, bb0, bb1);
            unpack2(w2, ww0, ww1);
            // sa_i = sum_j S_ij * a_j  (2 local + 32-lane all-VALU reduce)
            float sa = fmaf(S1, aa1, S0 * aa0);
            sa = red32(sa);
            // S_ij = S_ij*w_j + v_i*k_j + sa_i*b_j ; y_i = sum_j S_ij*r_j
            float t0 = fmaf(v, kk0, sa * bb0);
            float t1 = fmaf(v, kk1, sa * bb1);
            S0 = fmaf(S0, ww0, t0);
            S1 = fmaf(S1, ww1, t1);
            float y = fmaf(S1, rr1, S0 * rr0);
            y = red32(y);
            if ((lane & 47) == 0) ylds[s * 8 + lr] = y;   // lanes 0 (row A), 16 (row B)
            r2 = nr; k2 = nk; a2 = na; b2 = nb; w2 = nw; v = nv;
        }
        __syncthreads();   // ylds visible; batch bt+1 loads still in flight (vmem)
        // flush: 128 threads x 1 float = 128 = 16 steps x 8 rows
        if (tid < TB * 8) {
            int s = tid >> 3, j = tid & 7;
            Y[ybase + (size_t)(bt * TB + s) * Dx + part * 8 + j] = ylds[s * 8 + j];
        }
    }
}

// ---------------- group-norm + rkr residual + gate (OG in-place over GATE) ----------------
__global__ __launch_bounds__(256) void gnorm_kernel(
    const float* __restrict__ Y, const u16* __restrict__ Rb, const u16* __restrict__ Kb,
    const u16* __restrict__ Vb, const float* __restrict__ r_k,
    const float* __restrict__ gnw, const float* __restrict__ gnb,
    u16* __restrict__ GATE_OG)
{
    int g = blockIdx.x * 4 + (threadIdx.x >> 6);
    int lane = threadIdx.x & 63;
    int h = g & (Hx - 1);
    size_t idx = (size_t)g * 64 + lane;
    int hd = h * 64 + lane;
    float y = Y[idx];
    float r = bf2f(Rb[idx]), k = bf2f(Kb[idx]), v = bf2f(Vb[idx]);
    float rkr = r * k * r_k[hd];
    float s1 = y, s2 = y * y, s3 = rkr;
#pragma unroll
    for (int off = 32; off > 0; off >>= 1) {
        s1 += __shfl_xor(s1, off, 64);
        s2 += __shfl_xor(s2, off, 64);
        s3 += __shfl_xor(s3, off, 64);
    }
    float mean = s1 * (1.f / 64.f);
    float var  = s2 * (1.f / 64.f) - mean * mean;
    float inv = 1.f / sqrtf(var + EPS_GN);
    float o = gnw[hd] * ((y - mean) * inv) + gnb[hd];
    o += s3 * v;
    GATE_OG[idx] = f2bf(o * bf2f(GATE_OG[idx]));
}

// ---------------- launch ----------------
extern "C" void kernel_launch(void* const* d_in, const int* in_sizes, int n_in,
                              void* d_out, int out_size, void* d_ws, size_t ws_size,
                              hipStream_t stream_)
{
    const float* x      = (const float*)d_in[0];
    const float* vfirst = (const float*)d_in[1];
    const float* x_r = (const float*)d_in[2];
    const float* x_w = (const float*)d_in[3];
    const float* x_k = (const float*)d_in[4];
    const float* x_v = (const float*)d_in[5];
    const float* x_a = (const float*)d_in[6];
    const float* x_g = (const float*)d_in[7];
    const float* k_k = (const float*)d_in[8];
    const float* k_a = (const float*)d_in[9];
    const float* r_k = (const float*)d_in[10];
    const float* Wr  = (const float*)d_in[11];
    const float* Wk  = (const float*)d_in[12];
    const float* Wv  = (const float*)d_in[13];
    const float* Wo  = (const float*)d_in[14];
    const float* gnw = (const float*)d_in[15];
    const float* gnb = (const float*)d_in[16];
    const float* wA  = (const float*)d_in[17];
    const float* wB  = (const float*)d_in[18];
    const float* wb  = (const float*)d_in[19];
    const float* vA  = (const float*)d_in[20];
    const float* vB  = (const float*)d_in[21];
    const float* vb  = (const float*)d_in[22];
    const float* aA  = (const float*)d_in[23];
    const float* aB  = (const float*)d_in[24];
    const float* ab  = (const float*)d_in[25];
    const float* gA  = (const float*)d_in[26];
    const float* gB  = (const float*)d_in[27];

    char* ws = (char*)d_ws;
    const size_t SLOT = (size_t)NTOK * Dx * 2;   // 16 MiB; 14 slots total (224 MiB, proven)
    u16* XR = (u16*)(ws + 0 * SLOT);
    u16* XW = (u16*)(ws + 1 * SLOT);
    u16* XK = (u16*)(ws + 2 * SLOT);
    u16* XV = (u16*)(ws + 3 * SLOT);
    u16* XA = (u16*)(ws + 4 * SLOT);
    u16* XG = (u16*)(ws + 5 * SLOT);
    u16* STREAM = (u16*)(ws + 0 * SLOT);         // 96MB, overwrites XR..XG after consumption
    u16* Rbuf = (u16*)(ws + 6 * SLOT);
    u16* Kbuf = (u16*)(ws + 7 * SLOT);
    u16* Vbuf = (u16*)(ws + 8 * SLOT);
    u16* HW = (u16*)(ws + 9 * SLOT);             // lora hiddens (4.7MB)
    u16* HA = HW + (size_t)NTOK * 64;
    u16* HV = HA + (size_t)NTOK * 64;
    u16* HG = HV + (size_t)NTOK * 32;
    u16* SW = (u16*)(ws + 9 * SLOT + 8 * 1024 * 1024);  // small bf16 weights (1.2MB)
    u16* wAB = SW;
    u16* wBB = wAB + 65536;
    u16* vAB = wBB + 65536;
    u16* vBB = vAB + 32768;
    u16* aAB = vBB + 32768;
    u16* aBB = aAB + 65536;
    u16* gAB = aBB + 65536;
    u16* gBB = gAB + 131072;
    u16* Wdec16 = (u16*)(ws + 10 * SLOT);        // bf16 decay; dead after prep_pack
    u16* ICLR   = (u16*)(ws + 11 * SLOT);        // dead after prep_pack
    u16* VVb    = (u16*)(ws + 12 * SLOT);        // dead after prep_pack
    float* Yb   = (float*)(ws + 10 * SLOT);      // fp32, slots 10-11 (aliases Wdec16/ICLR, ordered)
    u16* GATE   = (u16*)(ws + 13 * SLOT);        // gnorm writes OG in-place

    dim3 blk(256);
    conv_kernel<<<dim3(128, 8), blk, 0, stream_>>>(wA, wB, vA, vB, aA, aB, gA, gB,
                                                   wAB, wBB, vAB, vBB, aAB, aBB, gAB, gBB);
    mix_kernel<<<(NTOK * Dx / 4) / 256, blk, 0, stream_>>>(x, x_r, x_w, x_k, x_v, x_a, x_g,
                                                           XR, XW, XK, XV, XA, XG);
    // big projections (B = f32 weights, converted in staging)
    gemm_nt<128, 0, false, false, true><<<dim3(64, 8), blk, 0, stream_>>>(XR, Wr, nullptr, Rbuf, NTOK, 1024, 1024);
    gemm_nt<128, 0, false, false, true><<<dim3(64, 8), blk, 0, stream_>>>(XK, Wk, nullptr, Kbuf, NTOK, 1024, 1024);
    gemm_nt<128, 0, false, false, true><<<dim3(64, 8), blk, 0, stream_>>>(XV, Wv, nullptr, Vbuf, NTOK, 1024, 1024);
    // lora stage 1
    gemm_nt<64, 2, false, false, false><<<dim3(64, 1), blk, 0, stream_>>>(XW, wAB, nullptr, HW, NTOK, 64, 1024);
    gemm_nt<64, 0, false, false, false><<<dim3(64, 1), blk, 0, stream_>>>(XA, aAB, nullptr, HA, NTOK, 64, 1024);
    gemm_nt<32, 0, false, false, false><<<dim3(64, 1), blk, 0, stream_>>>(XV, vAB, nullptr, HV, NTOK, 32, 1024);
    gemm_nt<128, 1, false, false, false><<<dim3(64, 1), blk, 0, stream_>>>(XG, gAB, nullptr, HG, NTOK, 128, 1024);
    // lora stage 2
    gemm_nt<128, 3, true,  false, false><<<dim3(64, 8), blk, 0, stream_>>>(HW, wBB, wb, Wdec16, NTOK, 1024, 64);
    gemm_nt<128, 1, true,  false, false><<<dim3(64, 8), blk, 0, stream_>>>(HA, aBB, ab, ICLR, NTOK, 1024, 64);
    gemm_nt<128, 1, true,  false, false><<<dim3(64, 8), blk, 0, stream_>>>(HV, vBB, vb, VVb, NTOK, 1024, 32);
    gemm_nt<128, 0, false, false, false><<<dim3(64, 8), blk, 0, stream_>>>(HG, gBB, nullptr, GATE, NTOK, 1024, 128);

    prep_pack_kernel<<<(NTOK * Hx) / 4, blk, 0, stream_>>>(Kbuf, Vbuf, Rbuf, Wdec16, ICLR, VVb,
                                                           vfirst, k_k, k_a, STREAM);
    scan_kernel<<<512, blk, 0, stream_>>>(STREAM, Yb);
    gnorm_kernel<<<(NTOK * Hx) / 4, blk, 0, stream_>>>(Yb, Rbuf, Kbuf, Vbuf, r_k, gnw, gnb, GATE);
    gemm_nt<128, 0, false, true, true><<<dim3(64, 8), blk, 0, stream_>>>(GATE, Wo, nullptr, d_out, NTOK, 1024, 1024);
}

// Round 5
// 738.310 us; speedup vs baseline: 1.2426x; 1.2159x over previous
//
#include <hip/hip_runtime.h>
#include <cmath>

// RWKV7 time-mixing, B=4 L=2048 D=1024 H=16 Dh=64. Inputs/outputs fp32; internal bf16.
// conv(all wts->bf16) -> mix -> [r,k,v] + lora1(fused) -> lora2 -> prep_pack(stream) ->
// scan v9 (v8 lane layout + deferred y-reduction via padded LDS partials) ->
// gnorm -> out GEMM (bf16 Wo).

#define DEV __device__ __forceinline__

typedef unsigned short u16;
typedef unsigned int u32;
typedef __bf16 bf16x8 __attribute__((ext_vector_type(8)));
typedef float f32x4 __attribute__((ext_vector_type(4)));

constexpr int Bx = 4, Lx = 2048, Dx = 1024, Hx = 16, Dh = 64;
constexpr int NTOK = Bx * Lx;       // 8192
constexpr float EPS_GN = 0.00064f;
constexpr int STEP_U16 = 384;       // 768B per step: r|k|a|b|v|w (64 bf16 each)
constexpr int TB = 16;              // steps per scan batch
constexpr int NB = Lx / TB;         // 128 batches
constexpr int BATCH_U16 = TB * STEP_U16;   // 6144 u16 = 12288 B

DEV float bf2f(u16 u) { union { u32 i; float f; } c; c.i = ((u32)u) << 16; return c.f; }
DEV u16 f2bf(float f) {
    union { float f; u32 i; } c; c.f = f;
    u32 r = c.i + 0x7FFFu + ((c.i >> 16) & 1u);
    return (u16)(r >> 16);
}
DEV void unpack2(u32 u, float& a, float& b) {
    union { u32 i; float f; } c0, c1;
    c0.i = u << 16; c1.i = u & 0xFFFF0000u;
    a = c0.f; b = c1.f;
}

// DPP butterfly add: v + v[lane ^ mask] for masks {1,2,7,15}, pure VALU.
template <int CTRL>
DEV float dpp_add(float v) {
    int p = __builtin_amdgcn_update_dpp(0, __float_as_int(v), CTRL, 0xF, 0xF, true);
    return v + __int_as_float(p);
}

// xor32 add via v_permlane32_swap_b32 (pure VALU).
DEV float xor32_add(float x) {
    float a = x, b = x;
    asm volatile("s_nop 1\n\tv_permlane32_swap_b32 %0, %1" : "+v"(a), "+v"(b));
    return a + b;
}

// Full reduce over a 32-lane row laid out as 16-group pair {G, G^32} (lanes i, i+32):
// 4 DPP hops (16-group sums) + xor32 cross. All VALU, no LDS pipe.
DEV float red32(float x) {
    x = dpp_add<0xB1>(x);
    x = dpp_add<0x4E>(x);
    x = dpp_add<0x141>(x);
    x = dpp_add<0x140>(x);
    return xor32_add(x);
}

// ---------------- f32 -> bf16 conversion: 8 lora tensors + 4 big projection weights ----------------
__global__ __launch_bounds__(256) void conv_kernel(
    const float* s0, const float* s1, const float* s2, const float* s3,
    const float* s4, const float* s5, const float* s6, const float* s7,
    const float* s8, const float* s9, const float* s10, const float* s11,
    u16* d0, u16* d1, u16* d2, u16* d3, u16* d4, u16* d5, u16* d6, u16* d7,
    u16* d8, u16* d9, u16* d10, u16* d11)
{
    const float* srcs[12] = {s0,s1,s2,s3,s4,s5,s6,s7,s8,s9,s10,s11};
    u16* dsts[12] = {d0,d1,d2,d3,d4,d5,d6,d7,d8,d9,d10,d11};
    const int ns[12] = {65536,65536,32768,32768,65536,65536,131072,131072,
                        1048576,1048576,1048576,1048576};
    int t = blockIdx.y;
    int i = (blockIdx.x * 256 + threadIdx.x) * 4;
    if (i >= ns[t]) return;
    float4 v = *(const float4*)(srcs[t] + i);
    ushort4 o;
    o.x = f2bf(v.x); o.y = f2bf(v.y); o.z = f2bf(v.z); o.w = f2bf(v.w);
    *(ushort4*)(dsts[t] + i) = o;
}

// ---------------- token-shift mix ----------------
__global__ __launch_bounds__(256) void mix_kernel(
    const float* __restrict__ x,
    const float* __restrict__ mr, const float* __restrict__ mw, const float* __restrict__ mk,
    const float* __restrict__ mv, const float* __restrict__ ma, const float* __restrict__ mg,
    u16* __restrict__ XR, u16* __restrict__ XW, u16* __restrict__ XK,
    u16* __restrict__ XV, u16* __restrict__ XA, u16* __restrict__ XG)
{
    int gi = blockIdx.x * 256 + threadIdx.x;
    int n  = gi >> 8;
    int d4 = (gi & 255) << 2;
    int l  = n & (Lx - 1);
    size_t o = (size_t)n * Dx + d4;
    float4 xc = *(const float4*)(x + o);
    float4 xp = make_float4(0.f, 0.f, 0.f, 0.f);
    if (l != 0) xp = *(const float4*)(x + o - Dx);
    float dx0 = xp.x - xc.x, dx1 = xp.y - xc.y, dx2 = xp.z - xc.z, dx3 = xp.w - xc.w;
    const float* mvs[6] = {mr, mw, mk, mv, ma, mg};
    u16* dsts[6] = {XR, XW, XK, XV, XA, XG};
#pragma unroll
    for (int j = 0; j < 6; ++j) {
        float4 m = *(const float4*)(mvs[j] + d4);
        ushort4 r;
        r.x = f2bf(fmaf(dx0, m.x, xc.x));
        r.y = f2bf(fmaf(dx1, m.y, xc.y));
        r.z = f2bf(fmaf(dx2, m.z, xc.z));
        r.w = f2bf(fmaf(dx3, m.w, xc.w));
        *(ushort4*)(dsts[j] + o) = r;
    }
}

// ---------------- bf16 MFMA GEMM, C[M,N] = act(A[M,K] . B[N,K]^T + bias_f32) ----------------
// ACT: 0 none, 1 sigmoid, 2 tanh, 3 exp(-0.606531*sigmoid).
template <int BN, int ACT, bool BIAS, bool F32OUT>
__global__ __launch_bounds__(256) void gemm_nt(
    const u16* __restrict__ A, const u16* __restrict__ B16,
    const float* __restrict__ bias, void* __restrict__ Cv,
    int M, int N, int K)
{
    constexpr int BM = 128, BK = 32;
    constexpr int LDT = BK + 8;
    constexpr int WGM = (BN == 128) ? 2 : 4;
    constexpr int WGN = (BN == 128) ? 2 : 1;
    constexpr int WTM = BM / WGM, WTN = BN / WGN;
    constexpr int ITM = WTM / 16, ITN = WTN / 16;
    __shared__ __align__(16) u16 Asm[BM * LDT];
    __shared__ __align__(16) u16 Bsm[BN * LDT];
    const int tid = threadIdx.x;
    const int wid = tid >> 6, lane = tid & 63;
    const int q = lane >> 4, r16 = lane & 15;
    const size_t m0 = (size_t)blockIdx.x * BM;
    const size_t n0 = (size_t)blockIdx.y * BN;
    const int wm = (wid % WGM) * WTM;
    const int wn = (wid / WGM) * WTN;
    f32x4 acc[ITM][ITN];
    const f32x4 zf = {0.f, 0.f, 0.f, 0.f};
#pragma unroll
    for (int i = 0; i < ITM; ++i)
#pragma unroll
        for (int j = 0; j < ITN; ++j) acc[i][j] = zf;

    for (int k0 = 0; k0 < K; k0 += BK) {
#pragma unroll
        for (int it = 0; it < (BM * BK) / 2048; ++it) {
            int pp = tid * 8 + it * 2048;
            int row = pp >> 5, col = pp & 31;
            *(uint4*)&Asm[row * LDT + col] = *(const uint4*)(A + (m0 + row) * K + k0 + col);
        }
#pragma unroll
        for (int it = 0; it < (BN * BK + 2047) / 2048; ++it) {
            int pp = tid * 8 + it * 2048;
            if (BN * BK >= 2048 || pp < BN * BK) {
                int row = pp >> 5, col = pp & 31;
                *(uint4*)&Bsm[row * LDT + col] = *(const uint4*)(B16 + (n0 + row) * K + k0 + col);
            }
        }
        __syncthreads();
        bf16x8 af[ITM], bfr[ITN];
#pragma unroll
        for (int im = 0; im < ITM; ++im)
            af[im] = *(const bf16x8*)&Asm[(wm + im * 16 + r16) * LDT + q * 8];
#pragma unroll
        for (int in = 0; in < ITN; ++in)
            bfr[in] = *(const bf16x8*)&Bsm[(wn + in * 16 + r16) * LDT + q * 8];
#pragma unroll
        for (int im = 0; im < ITM; ++im)
#pragma unroll
            for (int in = 0; in < ITN; ++in)
                acc[im][in] = __builtin_amdgcn_mfma_f32_16x16x32_bf16(af[im], bfr[in], acc[im][in], 0, 0, 0);
        __syncthreads();
    }
#pragma unroll
    for (int im = 0; im < ITM; ++im) {
#pragma unroll
        for (int in = 0; in < ITN; ++in) {
#pragma unroll
            for (int e = 0; e < 4; ++e) {
                size_t row = m0 + wm + im * 16 + q * 4 + e;
                size_t col = n0 + wn + in * 16 + r16;
                float val = acc[im][in][e];
                if constexpr (BIAS) val += bias[col];
                if constexpr (ACT == 1) val = 1.f / (1.f + __expf(-val));
                else if constexpr (ACT == 2) val = tanhf(val);
                else if constexpr (ACT == 3) val = __expf(-0.606531f / (1.f + __expf(-val)));
                if constexpr (F32OUT) ((float*)Cv)[row * (size_t)N + col] = val;
                else ((u16*)Cv)[row * (size_t)N + col] = f2bf(val);
            }
        }
    }
}

// ---------------- fused lora stage-1: 4 GEMMs in one dispatch (grid y = slice) ----------------
// y0: XW.wA^T tanh -> HW(64); y1: XA.aA^T -> HA(64); y2: XV.vA^T -> HV(32);
// y3/y4: XG.gA^T sigmoid -> HG cols 0-63 / 64-127 (ldC=128).
__global__ __launch_bounds__(256) void lora1_kernel(
    const u16* __restrict__ XW, const u16* __restrict__ XA,
    const u16* __restrict__ XV, const u16* __restrict__ XG,
    const u16* __restrict__ wAB, const u16* __restrict__ aAB,
    const u16* __restrict__ vAB, const u16* __restrict__ gAB,
    u16* __restrict__ HW, u16* __restrict__ HA,
    u16* __restrict__ HV, u16* __restrict__ HG)
{
    constexpr int BM = 128, BN = 64, BK = 32, K = 1024;
    constexpr int LDT = BK + 8;
    constexpr int ITM = 2, ITN = 4;   // wave: 32 rows x 64 cols (WGM=4, WGN=1)
    const int cfg = blockIdx.y;
    const u16* A; const u16* Bm; u16* C; int ldC, Nv, act;
    if (cfg == 0)      { A = XW; Bm = wAB;            C = HW;      ldC = 64;  Nv = 64; act = 2; }
    else if (cfg == 1) { A = XA; Bm = aAB;            C = HA;      ldC = 64;  Nv = 64; act = 0; }
    else if (cfg == 2) { A = XV; Bm = vAB;            C = HV;      ldC = 32;  Nv = 32; act = 0; }
    else if (cfg == 3) { A = XG; Bm = gAB;            C = HG;      ldC = 128; Nv = 64; act = 1; }
    else               { A = XG; Bm = gAB + 64 * K;   C = HG + 64; ldC = 128; Nv = 64; act = 1; }

    __shared__ __align__(16) u16 Asm[BM * LDT];
    __shared__ __align__(16) u16 Bsm[BN * LDT];
    const int tid = threadIdx.x;
    const int wid = tid >> 6, lane = tid & 63;
    const int q = lane >> 4, r16 = lane & 15;
    const size_t m0 = (size_t)blockIdx.x * BM;
    const int wm = wid * 32;
    f32x4 acc[ITM][ITN];
    const f32x4 zf = {0.f, 0.f, 0.f, 0.f};
#pragma unroll
    for (int i = 0; i < ITM; ++i)
#pragma unroll
        for (int j = 0; j < ITN; ++j) acc[i][j] = zf;

    for (int k0 = 0; k0 < K; k0 += BK) {
#pragma unroll
        for (int it = 0; it < 2; ++it) {
            int pp = tid * 8 + it * 2048;
            int row = pp >> 5, col = pp & 31;
            *(uint4*)&Asm[row * LDT + col] = *(const uint4*)(A + (m0 + row) * K + k0 + col);
        }
        {
            int pp = tid * 8;
            int row = pp >> 5, col = pp & 31;
            *(uint4*)&Bsm[row * LDT + col] = *(const uint4*)(Bm + row * K + k0 + col);
        }
        __syncthreads();
        bf16x8 af[ITM], bfr[ITN];
#pragma unroll
        for (int im = 0; im < ITM; ++im)
            af[im] = *(const bf16x8*)&Asm[(wm + im * 16 + r16) * LDT + q * 8];
#pragma unroll
        for (int in = 0; in < ITN; ++in)
            bfr[in] = *(const bf16x8*)&Bsm[(in * 16 + r16) * LDT + q * 8];
#pragma unroll
        for (int im = 0; im < ITM; ++im)
#pragma unroll
            for (int in = 0; in < ITN; ++in)
                acc[im][in] = __builtin_amdgcn_mfma_f32_16x16x32_bf16(af[im], bfr[in], acc[im][in], 0, 0, 0);
        __syncthreads();
    }
#pragma unroll
    for (int im = 0; im < ITM; ++im) {
#pragma unroll
        for (int in = 0; in < ITN; ++in) {
#pragma unroll
            for (int e = 0; e < 4; ++e) {
                size_t row = m0 + wm + im * 16 + q * 4 + e;
                int col = in * 16 + r16;
                if (col < Nv) {
                    float val = acc[im][in][e];
                    if (act == 1) val = 1.f / (1.f + __expf(-val));
                    else if (act == 2) val = tanhf(val);
                    C[row * (size_t)ldC + col] = f2bf(val);
                }
            }
        }
    }
}

// ---------------- prep + pack: kk-norm, a/b, k/v updates, emit packed stream ----------------
__global__ __launch_bounds__(256) void prep_pack_kernel(
    u16* __restrict__ Kb, u16* __restrict__ Vb,
    const u16* __restrict__ Rb, const u16* __restrict__ Wd16,
    const u16* __restrict__ ICLR, const u16* __restrict__ VVb, const float* __restrict__ vfirst,
    const float* __restrict__ k_k, const float* __restrict__ k_a,
    u16* __restrict__ stream)
{
    int g = blockIdx.x * 4 + (threadIdx.x >> 6);   // (token,head) pair: n = g>>4, h = g&15
    int lane = threadIdx.x & 63;
    int h = g & (Hx - 1);
    int n = g >> 4;
    size_t idx = (size_t)g * 64 + lane;            // == n*1024 + h*64 + lane
    int hd = h * 64 + lane;
    int l = n & (Lx - 1), b = n >> 11;
    size_t so = ((size_t)((b * 16 + h) * Lx + l)) * STEP_U16;

    float k = bf2f(Kb[idx]);
    float iclr = bf2f(ICLR[idx]);
    float kkn = k * k_k[hd];
    float s = kkn * kkn;
#pragma unroll
    for (int off = 32; off > 0; off >>= 1) s += __shfl_xor(s, off, 64);
    float nrm = fmaxf(sqrtf(s), 1e-7f);
    float kk = kkn / nrm;
    u16 knew = f2bf(k * (1.f + (iclr - 1.f) * k_a[hd]));
    float v = bf2f(Vb[idx]), vv = bf2f(VVb[idx]), vf = vfirst[idx];
    u16 vnew = f2bf(fmaf(vf - v, vv, v));
    Kb[idx] = knew;
    Vb[idx] = vnew;
    stream[so + lane]       = Rb[idx];
    stream[so + 64 + lane]  = knew;
    stream[so + 128 + lane] = f2bf(-kk);
    stream[so + 192 + lane] = f2bf(kk * iclr);
    stream[so + 256 + lane] = vnew;
    stream[so + 320 + lane] = Wd16[idx];
}

// ---------------- WKV7 scan v9 ----------------
// v8 layout: 512 blocks = 64 (b,h) x 8 row-eighths, XCD-colocated; 4 waves/block;
// wave = 2 rows x 32 lanes, row lanes = {0-15 U 32-47} / {16-31 U 48-63};
// c=(lane&15)|((lane>>1)&16) owns cols 2c,2c+1. sa reduce = 4 DPP + permlane32_swap.
// NEW: y reduction DEFERRED — per-step each lane writes its 2-col partial to padded
// LDS (stride 36 floats, conflict-free); per-batch flush sums 32 partials/row with
// ds_read_b128. Removes 8 VALU + reduce chain from every step.
__global__ __launch_bounds__(256, 2) void scan_kernel(
    const u16* __restrict__ stream, float* __restrict__ Y)
{
    const int bid = blockIdx.x;                   // 0..511; dispatch round-robins XCDs
    const int xcd = bid & 7, slot = bid >> 3;
    const int bh = xcd + ((slot & 7) << 3);       // 0..63: bh%8 == XCD -> co-located
    const int part = slot >> 3;                   // 0..7 (8 rows each)
    const int tid = threadIdx.x;
    const int lane = tid & 63;
    const int w = tid >> 6;
    const int c = (lane & 15) | ((lane >> 1) & 16);   // col-pair idx 0..31 (cols 2c,2c+1)
    const int rhalf = (lane >> 4) & 1;
    const int lr = w * 2 + rhalf;                 // local row 0..7
    const int row = part * 8 + lr;                // global row 0..63
    const size_t sbase = (size_t)bh * Lx * STEP_U16;
    const size_t ybase = (size_t)(bh >> 4) * ((size_t)Lx * Dx) + (size_t)(bh & 15) * 64;

    __shared__ __align__(16) u16 sbuf[2 * BATCH_U16];   // 24 KB
    __shared__ __align__(16) float yp[TB * 8 * 36];     // 18 KB padded partials

    float S0 = 0.f, S1 = 0.f;

    // stage batch 0 into buf 0 (wave w handles 1KB chunks 3w..3w+2)
    {
        const u16* g = stream + sbase;
#pragma unroll
        for (int cc = 0; cc < 3; ++cc) {
            const u16* gp = g + (3 * w + cc) * 512 + lane * 8;
            u16* lp = sbuf + (3 * w + cc) * 512;
            __builtin_amdgcn_global_load_lds(
                (const __attribute__((address_space(1))) void*)gp,
                (__attribute__((address_space(3))) void*)lp, 16, 0, 0);
        }
    }

    for (int bt = 0; bt < NB; ++bt) {
        const int cur = bt & 1;
        __syncthreads();   // vmcnt(0): batch bt resident; yp free from prev flush
        if (bt + 1 < NB) {
            const u16* g = stream + sbase + (size_t)(bt + 1) * BATCH_U16;
            u16* lbase = sbuf + (1 - cur) * BATCH_U16;
#pragma unroll
            for (int cc = 0; cc < 3; ++cc) {
                const u16* gp = g + (3 * w + cc) * 512 + lane * 8;
                u16* lp = lbase + (3 * w + cc) * 512;
                __builtin_amdgcn_global_load_lds(
                    (const __attribute__((address_space(1))) void*)gp,
                    (__attribute__((address_space(3))) void*)lp, 16, 0, 0);
            }
        }
        const u16* bp = sbuf + cur * BATCH_U16;
        const u16* cp = bp + c * 2;               // u16 offset 2c: cols 2c,2c+1
        u32 r2 = *(const u32*)(cp);
        u32 k2 = *(const u32*)(cp + 64);
        u32 a2 = *(const u32*)(cp + 128);
        u32 b2 = *(const u32*)(cp + 192);
        u32 w2 = *(const u32*)(cp + 320);
        float v = bf2f(bp[256 + row]);
#pragma unroll
        for (int s = 0; s < TB; ++s) {
            u32 nr = 0, nk = 0, na = 0, nb = 0, nw = 0;
            float nv = 0.f;
            if (s + 1 < TB) {          // compile-time under full unroll
                const u16* np = cp + (s + 1) * STEP_U16;
                nr = *(const u32*)(np);
                nk = *(const u32*)(np + 64);
                na = *(const u32*)(np + 128);
                nb = *(const u32*)(np + 192);
                nw = *(const u32*)(np + 320);
                nv = bf2f(bp[(s + 1) * STEP_U16 + 256 + row]);
            }
            float rr0, rr1, kk0, kk1, aa0, aa1, bb0, bb1, ww0, ww1;
            unpack2(r2, rr0, rr1);
            unpack2(k2, kk0, kk1);
            unpack2(a2, aa0, aa1);
            unpack2(b2, bb0, bb1);
            unpack2(w2, ww0, ww1);
            // sa_i = sum_j S_ij * a_j  (2 local + 32-lane all-VALU reduce)
            float sa = fmaf(S1, aa1, S0 * aa0);
            sa = red32(sa);
            // S_ij = S_ij*w_j + v_i*k_j + sa_i*b_j
            float t0 = fmaf(v, kk0, sa * bb0);
            float t1 = fmaf(v, kk1, sa * bb1);
            S0 = fmaf(S0, ww0, t0);
            S1 = fmaf(S1, ww1, t1);
            // y partial (2 cols) -> LDS; reduction deferred to flush
            float y = fmaf(S1, rr1, S0 * rr0);
            yp[(s * 8 + lr) * 36 + c] = y;
            r2 = nr; k2 = nk; a2 = na; b2 = nb; w2 = nw; v = nv;
        }
        __syncthreads();   // yp visible; batch bt+1 loads still in flight (vmem)
        // flush: 128 threads, each sums 32 partials of one (step,row) and stores
        if (tid < TB * 8) {
            const float* rp = &yp[tid * 36];
            f32x4 a4 = *(const f32x4*)(rp);
#pragma unroll
            for (int i = 1; i < 8; ++i) {
                f32x4 t4 = *(const f32x4*)(rp + i * 4);
                a4 += t4;
            }
            float yy = (a4[0] + a4[1]) + (a4[2] + a4[3]);
            int s = tid >> 3, j = tid & 7;
            Y[ybase + (size_t)(bt * TB + s) * Dx + part * 8 + j] = yy;
        }
    }
}

// ---------------- group-norm + rkr residual + gate (OG in-place over GATE) ----------------
__global__ __launch_bounds__(256) void gnorm_kernel(
    const float* __restrict__ Y, const u16* __restrict__ Rb, const u16* __restrict__ Kb,
    const u16* __restrict__ Vb, const float* __restrict__ r_k,
    const float* __restrict__ gnw, const float* __restrict__ gnb,
    u16* __restrict__ GATE_OG)
{
    int g = blockIdx.x * 4 + (threadIdx.x >> 6);
    int lane = threadIdx.x & 63;
    int h = g & (Hx - 1);
    size_t idx = (size_t)g * 64 + lane;
    int hd = h * 64 + lane;
    float y = Y[idx];
    float r = bf2f(Rb[idx]), k = bf2f(Kb[idx]), v = bf2f(Vb[idx]);
    float rkr = r * k * r_k[hd];
    float s1 = y, s2 = y * y, s3 = rkr;
#pragma unroll
    for (int off = 32; off > 0; off >>= 1) {
        s1 += __shfl_xor(s1, off, 64);
        s2 += __shfl_xor(s2, off, 64);
        s3 += __shfl_xor(s3, off, 64);
    }
    float mean = s1 * (1.f / 64.f);
    float var  = s2 * (1.f / 64.f) - mean * mean;
    float inv = 1.f / sqrtf(var + EPS_GN);
    float o = gnw[hd] * ((y - mean) * inv) + gnb[hd];
    o += s3 * v;
    GATE_OG[idx] = f2bf(o * bf2f(GATE_OG[idx]));
}

// ---------------- launch ----------------
extern "C" void kernel_launch(void* const* d_in, const int* in_sizes, int n_in,
                              void* d_out, int out_size, void* d_ws, size_t ws_size,
                              hipStream_t stream_)
{
    const float* x      = (const float*)d_in[0];
    const float* vfirst = (const float*)d_in[1];
    const float* x_r = (const float*)d_in[2];
    const float* x_w = (const float*)d_in[3];
    const float* x_k = (const float*)d_in[4];
    const float* x_v = (const float*)d_in[5];
    const float* x_a = (const float*)d_in[6];
    const float* x_g = (const float*)d_in[7];
    const float* k_k = (const float*)d_in[8];
    const float* k_a = (const float*)d_in[9];
    const float* r_k = (const float*)d_in[10];
    const float* Wr  = (const float*)d_in[11];
    const float* Wk  = (const float*)d_in[12];
    const float* Wv  = (const float*)d_in[13];
    const float* Wo  = (const float*)d_in[14];
    const float* gnw = (const float*)d_in[15];
    const float* gnb = (const float*)d_in[16];
    const float* wA  = (const float*)d_in[17];
    const float* wB  = (const float*)d_in[18];
    const float* wb  = (const float*)d_in[19];
    const float* vA  = (const float*)d_in[20];
    const float* vB  = (const float*)d_in[21];
    const float* vb  = (const float*)d_in[22];
    const float* aA  = (const float*)d_in[23];
    const float* aB  = (const float*)d_in[24];
    const float* ab  = (const float*)d_in[25];
    const float* gA  = (const float*)d_in[26];
    const float* gB  = (const float*)d_in[27];

    char* ws = (char*)d_ws;
    const size_t SLOT = (size_t)NTOK * Dx * 2;   // 16 MiB; 14 slots total (224 MiB, proven)
    u16* XR = (u16*)(ws + 0 * SLOT);
    u16* XW = (u16*)(ws + 1 * SLOT);
    u16* XK = (u16*)(ws + 2 * SLOT);
    u16* XV = (u16*)(ws + 3 * SLOT);
    u16* XA = (u16*)(ws + 4 * SLOT);
    u16* XG = (u16*)(ws + 5 * SLOT);
    u16* STREAM = (u16*)(ws + 0 * SLOT);         // 96MB, overwrites XR..XG after consumption
    u16* Rbuf = (u16*)(ws + 6 * SLOT);
    u16* Kbuf = (u16*)(ws + 7 * SLOT);
    u16* Vbuf = (u16*)(ws + 8 * SLOT);
    // slot 9 internal layout:
    u16* HW = (u16*)(ws + 9 * SLOT);             // lora hiddens (4.5MB)
    u16* HA = HW + (size_t)NTOK * 64;
    u16* HV = HA + (size_t)NTOK * 64;
    u16* HG = HV + (size_t)NTOK * 32;
    u16* Wo16 = HG + (size_t)NTOK * 128;         // +4.5MB, 2MB
    u16* SW = (u16*)(ws + 9 * SLOT + 8 * 1024 * 1024);  // small bf16 weights (1.2MB)
    u16* wAB = SW;
    u16* wBB = wAB + 65536;
    u16* vAB = wBB + 65536;
    u16* vBB = vAB + 32768;
    u16* aAB = vBB + 32768;
    u16* aBB = aAB + 65536;
    u16* gAB = aBB + 65536;
    u16* gBB = gAB + 131072;
    u16* Wr16 = (u16*)(ws + 9 * SLOT + 10 * 1024 * 1024);  // 3 x 2MB -> ends at 16MB
    u16* Wk16 = Wr16 + 1048576;
    u16* Wv16 = Wk16 + 1048576;
    u16* Wdec16 = (u16*)(ws + 10 * SLOT);        // bf16 decay; dead after prep_pack
    u16* ICLR   = (u16*)(ws + 11 * SLOT);        // dead after prep_pack
    u16* VVb    = (u16*)(ws + 12 * SLOT);        // dead after prep_pack
    float* Yb   = (float*)(ws + 10 * SLOT);      // fp32, slots 10-11 (aliases Wdec16/ICLR, ordered)
    u16* GATE   = (u16*)(ws + 13 * SLOT);        // gnorm writes OG in-place

    dim3 blk(256);
    conv_kernel<<<dim3(1024, 12), blk, 0, stream_>>>(
        wA, wB, vA, vB, aA, aB, gA, gB, Wr, Wk, Wv, Wo,
        wAB, wBB, vAB, vBB, aAB, aBB, gAB, gBB, Wr16, Wk16, Wv16, Wo16);
    mix_kernel<<<(NTOK * Dx / 4) / 256, blk, 0, stream_>>>(x, x_r, x_w, x_k, x_v, x_a, x_g,
                                                           XR, XW, XK, XV, XA, XG);
    // big projections (bf16 weights)
    gemm_nt<128, 0, false, false><<<dim3(64, 8), blk, 0, stream_>>>(XR, Wr16, nullptr, Rbuf, NTOK, 1024, 1024);
    gemm_nt<128, 0, false, false><<<dim3(64, 8), blk, 0, stream_>>>(XK, Wk16, nullptr, Kbuf, NTOK, 1024, 1024);
    gemm_nt<128, 0, false, false><<<dim3(64, 8), blk, 0, stream_>>>(XV, Wv16, nullptr, Vbuf, NTOK, 1024, 1024);
    // lora stage 1 (fused: W,A,V,G-lo,G-hi)
    lora1_kernel<<<dim3(64, 5), blk, 0, stream_>>>(XW, XA, XV, XG, wAB, aAB, vAB, gAB,
                                                   HW, HA, HV, HG);
    // lora stage 2
    gemm_nt<128, 3, true,  false><<<dim3(64, 8), blk, 0, stream_>>>(HW, wBB, wb, Wdec16, NTOK, 1024, 64);
    gemm_nt<128, 1, true,  false><<<dim3(64, 8), blk, 0, stream_>>>(HA, aBB, ab, ICLR, NTOK, 1024, 64);
    gemm_nt<128, 1, true,  false><<<dim3(64, 8), blk, 0, stream_>>>(HV, vBB, vb, VVb, NTOK, 1024, 32);
    gemm_nt<128, 0, false, false><<<dim3(64, 8), blk, 0, stream_>>>(HG, gBB, nullptr, GATE, NTOK, 1024, 128);

    prep_pack_kernel<<<(NTOK * Hx) / 4, blk, 0, stream_>>>(Kbuf, Vbuf, Rbuf, Wdec16, ICLR, VVb,
                                                           vfirst, k_k, k_a, STREAM);
    scan_kernel<<<512, blk, 0, stream_>>>(STREAM, Yb);
    gnorm_kernel<<<(NTOK * Hx) / 4, blk, 0, stream_>>>(Yb, Rbuf, Kbuf, Vbuf, r_k, gnw, gnb, GATE);
    gemm_nt<128, 0, false, true><<<dim3(64, 8), blk, 0, stream_>>>(GATE, Wo16, nullptr, d_out, NTOK, 1024, 1024);
}

// Round 6
// 706.209 us; speedup vs baseline: 1.2990x; 1.0455x over previous
//
#include <hip/hip_runtime.h>
#include <cmath>

// RWKV7 time-mixing, B=4 L=2048 D=1024 H=16 Dh=64. Inputs/outputs fp32; internal bf16.
// conv(all wts->bf16) -> mix -> fused RKV GEMM + lora1(fused) -> lora2 -> prep_pack ->
// scan v9 (XCD-colocated, permlane reduce, deferred y) -> gnorm -> out GEMM.
// GEMMs: m97-style staging (global_load_lds width=16, linear LDS, 2-barrier K-loop).

#define DEV __device__ __forceinline__

typedef unsigned short u16;
typedef unsigned int u32;
typedef __bf16 bf16x8 __attribute__((ext_vector_type(8)));
typedef float f32x4 __attribute__((ext_vector_type(4)));

constexpr int Bx = 4, Lx = 2048, Dx = 1024, Hx = 16, Dh = 64;
constexpr int NTOK = Bx * Lx;       // 8192
constexpr float EPS_GN = 0.00064f;
constexpr int STEP_U16 = 384;       // 768B per step: r|k|a|b|v|w (64 bf16 each)
constexpr int TB = 16;              // steps per scan batch
constexpr int NB = Lx / TB;         // 128 batches
constexpr int BATCH_U16 = TB * STEP_U16;   // 6144 u16 = 12288 B

DEV float bf2f(u16 u) { union { u32 i; float f; } c; c.i = ((u32)u) << 16; return c.f; }
DEV u16 f2bf(float f) {
    union { float f; u32 i; } c; c.f = f;
    u32 r = c.i + 0x7FFFu + ((c.i >> 16) & 1u);
    return (u16)(r >> 16);
}
DEV void unpack2(u32 u, float& a, float& b) {
    union { u32 i; float f; } c0, c1;
    c0.i = u << 16; c1.i = u & 0xFFFF0000u;
    a = c0.f; b = c1.f;
}

// DPP butterfly add: v + v[lane ^ mask] for masks {1,2,7,15}, pure VALU.
template <int CTRL>
DEV float dpp_add(float v) {
    int p = __builtin_amdgcn_update_dpp(0, __float_as_int(v), CTRL, 0xF, 0xF, true);
    return v + __int_as_float(p);
}

// xor32 add via v_permlane32_swap_b32 (pure VALU).
DEV float xor32_add(float x) {
    float a = x, b = x;
    asm volatile("s_nop 1\n\tv_permlane32_swap_b32 %0, %1" : "+v"(a), "+v"(b));
    return a + b;
}

// Full reduce over a 32-lane row laid out as 16-group pair {G, G^32} (lanes i, i+32):
// 4 DPP hops (16-group sums) + xor32 cross. All VALU, no LDS pipe.
DEV float red32(float x) {
    x = dpp_add<0xB1>(x);
    x = dpp_add<0x4E>(x);
    x = dpp_add<0x141>(x);
    x = dpp_add<0x140>(x);
    return xor32_add(x);
}

// ---------------- f32 -> bf16 conversion: 8 lora tensors + 4 big projection weights ----------------
__global__ __launch_bounds__(256) void conv_kernel(
    const float* s0, const float* s1, const float* s2, const float* s3,
    const float* s4, const float* s5, const float* s6, const float* s7,
    const float* s8, const float* s9, const float* s10, const float* s11,
    u16* d0, u16* d1, u16* d2, u16* d3, u16* d4, u16* d5, u16* d6, u16* d7,
    u16* d8, u16* d9, u16* d10, u16* d11)
{
    const float* srcs[12] = {s0,s1,s2,s3,s4,s5,s6,s7,s8,s9,s10,s11};
    u16* dsts[12] = {d0,d1,d2,d3,d4,d5,d6,d7,d8,d9,d10,d11};
    const int ns[12] = {65536,65536,32768,32768,65536,65536,131072,131072,
                        1048576,1048576,1048576,1048576};
    int t = blockIdx.y;
    int i = (blockIdx.x * 256 + threadIdx.x) * 4;
    if (i >= ns[t]) return;
    float4 v = *(const float4*)(srcs[t] + i);
    ushort4 o;
    o.x = f2bf(v.x); o.y = f2bf(v.y); o.z = f2bf(v.z); o.w = f2bf(v.w);
    *(ushort4*)(dsts[t] + i) = o;
}

// ---------------- token-shift mix ----------------
__global__ __launch_bounds__(256) void mix_kernel(
    const float* __restrict__ x,
    const float* __restrict__ mr, const float* __restrict__ mw, const float* __restrict__ mk,
    const float* __restrict__ mv, const float* __restrict__ ma, const float* __restrict__ mg,
    u16* __restrict__ XR, u16* __restrict__ XW, u16* __restrict__ XK,
    u16* __restrict__ XV, u16* __restrict__ XA, u16* __restrict__ XG)
{
    int gi = blockIdx.x * 256 + threadIdx.x;
    int n  = gi >> 8;
    int d4 = (gi & 255) << 2;
    int l  = n & (Lx - 1);
    size_t o = (size_t)n * Dx + d4;
    float4 xc = *(const float4*)(x + o);
    float4 xp = make_float4(0.f, 0.f, 0.f, 0.f);
    if (l != 0) xp = *(const float4*)(x + o - Dx);
    float dx0 = xp.x - xc.x, dx1 = xp.y - xc.y, dx2 = xp.z - xc.z, dx3 = xp.w - xc.w;
    const float* mvs[6] = {mr, mw, mk, mv, ma, mg};
    u16* dsts[6] = {XR, XW, XK, XV, XA, XG};
#pragma unroll
    for (int j = 0; j < 6; ++j) {
        float4 m = *(const float4*)(mvs[j] + d4);
        ushort4 r;
        r.x = f2bf(fmaf(dx0, m.x, xc.x));
        r.y = f2bf(fmaf(dx1, m.y, xc.y));
        r.z = f2bf(fmaf(dx2, m.z, xc.z));
        r.w = f2bf(fmaf(dx3, m.w, xc.w));
        *(ushort4*)(dsts[j] + o) = r;
    }
}

// ---------------- bf16 MFMA GEMM body, C[M,N] = act(A[M,K] . B[N,K]^T + bias_f32) ----------------
// m97-style staging: global_load_lds width=16 into LINEAR LDS (row-major [*,BK], no pad);
// 2-barrier K-loop. ACT: 0 none, 1 sigmoid, 2 tanh, 3 exp(-0.606531*sigmoid).
template <int BN, int ACT, bool BIAS, bool F32OUT>
DEV void gemm_body(const u16* __restrict__ A, const u16* __restrict__ B16,
                   const float* __restrict__ bias, void* __restrict__ Cv,
                   int M, int N, int K, int bx, int by)
{
    constexpr int BM = 128, BK = 32;
    constexpr int WGM = (BN == 128) ? 2 : 4;
    constexpr int WGN = (BN == 128) ? 2 : 1;
    constexpr int WTM = BM / WGM, WTN = BN / WGN;
    constexpr int ITM = WTM / 16, ITN = WTN / 16;
    __shared__ __align__(16) u16 Asm[BM * BK];   // 8 KB
    __shared__ __align__(16) u16 Bsm[BN * BK];   // <= 8 KB
    const int tid = threadIdx.x;
    const int wid = tid >> 6, lane = tid & 63;
    const int q = lane >> 4, r16 = lane & 15;
    const size_t m0 = (size_t)bx * BM;
    const size_t n0 = (size_t)by * BN;
    const int wm = (wid % WGM) * WTM;
    const int wn = (wid / WGM) * WTN;
    f32x4 acc[ITM][ITN];
    const f32x4 zf = {0.f, 0.f, 0.f, 0.f};
#pragma unroll
    for (int i = 0; i < ITM; ++i)
#pragma unroll
        for (int j = 0; j < ITN; ++j) acc[i][j] = zf;

    for (int k0 = 0; k0 < K; k0 += BK) {
        // stage A: 8 KB = 2 chunks x (4 waves x 64 lanes x 16 B); dest wave-uniform, +lane*16 by HW
#pragma unroll
        for (int it = 0; it < 2; ++it) {
            int base = it * 2048 + wid * 512;            // u16 index, wave-uniform
            int pp = base + lane * 8;
            int row = pp >> 5, col = pp & 31;
            __builtin_amdgcn_global_load_lds(
                (const __attribute__((address_space(1))) void*)(A + (m0 + row) * K + k0 + col),
                (__attribute__((address_space(3))) void*)(Asm + base), 16, 0, 0);
        }
        // stage B
#pragma unroll
        for (int it = 0; it < (BN * BK + 2047) / 2048; ++it) {
            int base = it * 2048 + wid * 512;
            if (BN * BK >= 2048 || base < BN * BK) {
                int pp = base + lane * 8;
                int row = pp >> 5, col = pp & 31;
                __builtin_amdgcn_global_load_lds(
                    (const __attribute__((address_space(1))) void*)(B16 + (n0 + row) * K + k0 + col),
                    (__attribute__((address_space(3))) void*)(Bsm + base), 16, 0, 0);
            }
        }
        __syncthreads();   // vmcnt(0): tiles resident
        bf16x8 af[ITM], bfr[ITN];
#pragma unroll
        for (int im = 0; im < ITM; ++im)
            af[im] = *(const bf16x8*)&Asm[(wm + im * 16 + r16) * BK + q * 8];
#pragma unroll
        for (int in = 0; in < ITN; ++in)
            bfr[in] = *(const bf16x8*)&Bsm[(wn + in * 16 + r16) * BK + q * 8];
#pragma unroll
        for (int im = 0; im < ITM; ++im)
#pragma unroll
            for (int in = 0; in < ITN; ++in)
                acc[im][in] = __builtin_amdgcn_mfma_f32_16x16x32_bf16(af[im], bfr[in], acc[im][in], 0, 0, 0);
        __syncthreads();   // all reads done before next stage overwrites
    }
#pragma unroll
    for (int im = 0; im < ITM; ++im) {
#pragma unroll
        for (int in = 0; in < ITN; ++in) {
#pragma unroll
            for (int e = 0; e < 4; ++e) {
                size_t row = m0 + wm + im * 16 + q * 4 + e;
                size_t col = n0 + wn + in * 16 + r16;
                float val = acc[im][in][e];
                if constexpr (BIAS) val += bias[col];
                if constexpr (ACT == 1) val = 1.f / (1.f + __expf(-val));
                else if constexpr (ACT == 2) val = tanhf(val);
                else if constexpr (ACT == 3) val = __expf(-0.606531f / (1.f + __expf(-val)));
                if constexpr (F32OUT) ((float*)Cv)[row * (size_t)N + col] = val;
                else ((u16*)Cv)[row * (size_t)N + col] = f2bf(val);
            }
        }
    }
}

template <int BN, int ACT, bool BIAS, bool F32OUT>
__global__ __launch_bounds__(256) void gemm_nt(
    const u16* __restrict__ A, const u16* __restrict__ B16,
    const float* __restrict__ bias, void* __restrict__ Cv,
    int M, int N, int K)
{
    gemm_body<BN, ACT, BIAS, F32OUT>(A, B16, bias, Cv, M, N, K, blockIdx.x, blockIdx.y);
}

// fused R/K/V projections: grid.z picks the matrix (identical shapes)
__global__ __launch_bounds__(256) void gemm_rkv_kernel(
    const u16* __restrict__ XR, const u16* __restrict__ XK, const u16* __restrict__ XV,
    const u16* __restrict__ Wr16, const u16* __restrict__ Wk16, const u16* __restrict__ Wv16,
    u16* __restrict__ Rbuf, u16* __restrict__ Kbuf, u16* __restrict__ Vbuf)
{
    const u16* A; const u16* Bm; u16* C;
    if (blockIdx.z == 0)      { A = XR; Bm = Wr16; C = Rbuf; }
    else if (blockIdx.z == 1) { A = XK; Bm = Wk16; C = Kbuf; }
    else                      { A = XV; Bm = Wv16; C = Vbuf; }
    gemm_body<128, 0, false, false>(A, Bm, nullptr, C, NTOK, 1024, 1024, blockIdx.x, blockIdx.y);
}

// ---------------- fused lora stage-1: 4 GEMMs in one dispatch (grid y = slice) ----------------
// y0: XW.wA^T tanh -> HW(64); y1: XA.aA^T -> HA(64); y2: XV.vA^T -> HV(32);
// y3/y4: XG.gA^T sigmoid -> HG cols 0-63 / 64-127 (ldC=128).
__global__ __launch_bounds__(256) void lora1_kernel(
    const u16* __restrict__ XW, const u16* __restrict__ XA,
    const u16* __restrict__ XV, const u16* __restrict__ XG,
    const u16* __restrict__ wAB, const u16* __restrict__ aAB,
    const u16* __restrict__ vAB, const u16* __restrict__ gAB,
    u16* __restrict__ HW, u16* __restrict__ HA,
    u16* __restrict__ HV, u16* __restrict__ HG)
{
    constexpr int BM = 128, BN = 64, BK = 32, K = 1024;
    constexpr int ITM = 2, ITN = 4;   // wave: 32 rows x 64 cols (WGM=4, WGN=1)
    const int cfg = blockIdx.y;
    const u16* A; const u16* Bm; u16* C; int ldC, Nv, act;
    if (cfg == 0)      { A = XW; Bm = wAB;            C = HW;      ldC = 64;  Nv = 64; act = 2; }
    else if (cfg == 1) { A = XA; Bm = aAB;            C = HA;      ldC = 64;  Nv = 64; act = 0; }
    else if (cfg == 2) { A = XV; Bm = vAB;            C = HV;      ldC = 32;  Nv = 32; act = 0; }
    else if (cfg == 3) { A = XG; Bm = gAB;            C = HG;      ldC = 128; Nv = 64; act = 1; }
    else               { A = XG; Bm = gAB + 64 * K;   C = HG + 64; ldC = 128; Nv = 64; act = 1; }

    __shared__ __align__(16) u16 Asm[BM * BK];
    __shared__ __align__(16) u16 Bsm[BN * BK];
    const int tid = threadIdx.x;
    const int wid = tid >> 6, lane = tid & 63;
    const int q = lane >> 4, r16 = lane & 15;
    const size_t m0 = (size_t)blockIdx.x * BM;
    const int wm = wid * 32;
    f32x4 acc[ITM][ITN];
    const f32x4 zf = {0.f, 0.f, 0.f, 0.f};
#pragma unroll
    for (int i = 0; i < ITM; ++i)
#pragma unroll
        for (int j = 0; j < ITN; ++j) acc[i][j] = zf;

    for (int k0 = 0; k0 < K; k0 += BK) {
#pragma unroll
        for (int it = 0; it < 2; ++it) {
            int base = it * 2048 + wid * 512;
            int pp = base + lane * 8;
            int row = pp >> 5, col = pp & 31;
            __builtin_amdgcn_global_load_lds(
                (const __attribute__((address_space(1))) void*)(A + (m0 + row) * K + k0 + col),
                (__attribute__((address_space(3))) void*)(Asm + base), 16, 0, 0);
        }
        {
            int base = wid * 512;                        // BN*BK = 2048 u16 = 4 wave-chunks
            int pp = base + lane * 8;
            int row = pp >> 5, col = pp & 31;
            __builtin_amdgcn_global_load_lds(
                (const __attribute__((address_space(1))) void*)(Bm + row * K + k0 + col),
                (__attribute__((address_space(3))) void*)(Bsm + base), 16, 0, 0);
        }
        __syncthreads();
        bf16x8 af[ITM], bfr[ITN];
#pragma unroll
        for (int im = 0; im < ITM; ++im)
            af[im] = *(const bf16x8*)&Asm[(wm + im * 16 + r16) * BK + q * 8];
#pragma unroll
        for (int in = 0; in < ITN; ++in)
            bfr[in] = *(const bf16x8*)&Bsm[(in * 16 + r16) * BK + q * 8];
#pragma unroll
        for (int im = 0; im < ITM; ++im)
#pragma unroll
            for (int in = 0; in < ITN; ++in)
                acc[im][in] = __builtin_amdgcn_mfma_f32_16x16x32_bf16(af[im], bfr[in], acc[im][in], 0, 0, 0);
        __syncthreads();
    }
#pragma unroll
    for (int im = 0; im < ITM; ++im) {
#pragma unroll
        for (int in = 0; in < ITN; ++in) {
#pragma unroll
            for (int e = 0; e < 4; ++e) {
                size_t row = m0 + wm + im * 16 + q * 4 + e;
                int col = in * 16 + r16;
                if (col < Nv) {
                    float val = acc[im][in][e];
                    if (act == 1) val = 1.f / (1.f + __expf(-val));
                    else if (act == 2) val = tanhf(val);
                    C[row * (size_t)ldC + col] = f2bf(val);
                }
            }
        }
    }
}

// ---------------- prep + pack: kk-norm, a/b, k/v updates, emit packed stream ----------------
__global__ __launch_bounds__(256) void prep_pack_kernel(
    u16* __restrict__ Kb, u16* __restrict__ Vb,
    const u16* __restrict__ Rb, const u16* __restrict__ Wd16,
    const u16* __restrict__ ICLR, const u16* __restrict__ VVb, const float* __restrict__ vfirst,
    const float* __restrict__ k_k, const float* __restrict__ k_a,
    u16* __restrict__ stream)
{
    int g = blockIdx.x * 4 + (threadIdx.x >> 6);   // (token,head) pair: n = g>>4, h = g&15
    int lane = threadIdx.x & 63;
    int h = g & (Hx - 1);
    int n = g >> 4;
    size_t idx = (size_t)g * 64 + lane;            // == n*1024 + h*64 + lane
    int hd = h * 64 + lane;
    int l = n & (Lx - 1), b = n >> 11;
    size_t so = ((size_t)((b * 16 + h) * Lx + l)) * STEP_U16;

    float k = bf2f(Kb[idx]);
    float iclr = bf2f(ICLR[idx]);
    float kkn = k * k_k[hd];
    float s = kkn * kkn;
#pragma unroll
    for (int off = 32; off > 0; off >>= 1) s += __shfl_xor(s, off, 64);
    float nrm = fmaxf(sqrtf(s), 1e-7f);
    float kk = kkn / nrm;
    u16 knew = f2bf(k * (1.f + (iclr - 1.f) * k_a[hd]));
    float v = bf2f(Vb[idx]), vv = bf2f(VVb[idx]), vf = vfirst[idx];
    u16 vnew = f2bf(fmaf(vf - v, vv, v));
    Kb[idx] = knew;
    Vb[idx] = vnew;
    stream[so + lane]       = Rb[idx];
    stream[so + 64 + lane]  = knew;
    stream[so + 128 + lane] = f2bf(-kk);
    stream[so + 192 + lane] = f2bf(kk * iclr);
    stream[so + 256 + lane] = vnew;
    stream[so + 320 + lane] = Wd16[idx];
}

// ---------------- WKV7 scan v9 (unchanged) ----------------
// 512 blocks = 64 (b,h) x 8 row-eighths, XCD-colocated; 4 waves/block;
// wave = 2 rows x 32 lanes, row lanes = {0-15 U 32-47} / {16-31 U 48-63};
// c=(lane&15)|((lane>>1)&16) owns cols 2c,2c+1. sa reduce = 4 DPP + permlane32_swap.
// y reduction deferred: per-step partial to padded LDS; per-batch flush sums.
__global__ __launch_bounds__(256, 2) void scan_kernel(
    const u16* __restrict__ stream, float* __restrict__ Y)
{
    const int bid = blockIdx.x;                   // 0..511; dispatch round-robins XCDs
    const int xcd = bid & 7, slot = bid >> 3;
    const int bh = xcd + ((slot & 7) << 3);       // 0..63: bh%8 == XCD -> co-located
    const int part = slot >> 3;                   // 0..7 (8 rows each)
    const int tid = threadIdx.x;
    const int lane = tid & 63;
    const int w = tid >> 6;
    const int c = (lane & 15) | ((lane >> 1) & 16);   // col-pair idx 0..31 (cols 2c,2c+1)
    const int rhalf = (lane >> 4) & 1;
    const int lr = w * 2 + rhalf;                 // local row 0..7
    const int row = part * 8 + lr;                // global row 0..63
    const size_t sbase = (size_t)bh * Lx * STEP_U16;
    const size_t ybase = (size_t)(bh >> 4) * ((size_t)Lx * Dx) + (size_t)(bh & 15) * 64;

    __shared__ __align__(16) u16 sbuf[2 * BATCH_U16];   // 24 KB
    __shared__ __align__(16) float yp[TB * 8 * 36];     // 18 KB padded partials

    float S0 = 0.f, S1 = 0.f;

    // stage batch 0 into buf 0 (wave w handles 1KB chunks 3w..3w+2)
    {
        const u16* g = stream + sbase;
#pragma unroll
        for (int cc = 0; cc < 3; ++cc) {
            const u16* gp = g + (3 * w + cc) * 512 + lane * 8;
            u16* lp = sbuf + (3 * w + cc) * 512;
            __builtin_amdgcn_global_load_lds(
                (const __attribute__((address_space(1))) void*)gp,
                (__attribute__((address_space(3))) void*)lp, 16, 0, 0);
        }
    }

    for (int bt = 0; bt < NB; ++bt) {
        const int cur = bt & 1;
        __syncthreads();   // vmcnt(0): batch bt resident; yp free from prev flush
        if (bt + 1 < NB) {
            const u16* g = stream + sbase + (size_t)(bt + 1) * BATCH_U16;
            u16* lbase = sbuf + (1 - cur) * BATCH_U16;
#pragma unroll
            for (int cc = 0; cc < 3; ++cc) {
                const u16* gp = g + (3 * w + cc) * 512 + lane * 8;
                u16* lp = lbase + (3 * w + cc) * 512;
                __builtin_amdgcn_global_load_lds(
                    (const __attribute__((address_space(1))) void*)gp,
                    (__attribute__((address_space(3))) void*)lp, 16, 0, 0);
            }
        }
        const u16* bp = sbuf + cur * BATCH_U16;
        const u16* cp = bp + c * 2;               // u16 offset 2c: cols 2c,2c+1
        u32 r2 = *(const u32*)(cp);
        u32 k2 = *(const u32*)(cp + 64);
        u32 a2 = *(const u32*)(cp + 128);
        u32 b2 = *(const u32*)(cp + 192);
        u32 w2 = *(const u32*)(cp + 320);
        float v = bf2f(bp[256 + row]);
#pragma unroll
        for (int s = 0; s < TB; ++s) {
            u32 nr = 0, nk = 0, na = 0, nb = 0, nw = 0;
            float nv = 0.f;
            if (s + 1 < TB) {          // compile-time under full unroll
                const u16* np = cp + (s + 1) * STEP_U16;
                nr = *(const u32*)(np);
                nk = *(const u32*)(np + 64);
                na = *(const u32*)(np + 128);
                nb = *(const u32*)(np + 192);
                nw = *(const u32*)(np + 320);
                nv = bf2f(bp[(s + 1) * STEP_U16 + 256 + row]);
            }
            float rr0, rr1, kk0, kk1, aa0, aa1, bb0, bb1, ww0, ww1;
            unpack2(r2, rr0, rr1);
            unpack2(k2, kk0, kk1);
            unpack2(a2, aa0, aa1);
            unpack2(b2, bb0, bb1);
            unpack2(w2, ww0, ww1);
            // sa_i = sum_j S_ij * a_j  (2 local + 32-lane all-VALU reduce)
            float sa = fmaf(S1, aa1, S0 * aa0);
            sa = red32(sa);
            // S_ij = S_ij*w_j + v_i*k_j + sa_i*b_j
            float t0 = fmaf(v, kk0, sa * bb0);
            float t1 = fmaf(v, kk1, sa * bb1);
            S0 = fmaf(S0, ww0, t0);
            S1 = fmaf(S1, ww1, t1);
            // y partial (2 cols) -> LDS; reduction deferred to flush
            float y = fmaf(S1, rr1, S0 * rr0);
            yp[(s * 8 + lr) * 36 + c] = y;
            r2 = nr; k2 = nk; a2 = na; b2 = nb; w2 = nw; v = nv;
        }
        __syncthreads();   // yp visible; batch bt+1 loads still in flight (vmem)
        // flush: 128 threads, each sums 32 partials of one (step,row) and stores
        if (tid < TB * 8) {
            const float* rp = &yp[tid * 36];
            f32x4 a4 = *(const f32x4*)(rp);
#pragma unroll
            for (int i = 1; i < 8; ++i) {
                f32x4 t4 = *(const f32x4*)(rp + i * 4);
                a4 += t4;
            }
            float yy = (a4[0] + a4[1]) + (a4[2] + a4[3]);
            int s = tid >> 3, j = tid & 7;
            Y[ybase + (size_t)(bt * TB + s) * Dx + part * 8 + j] = yy;
        }
    }
}

// ---------------- group-norm + rkr residual + gate (OG in-place over GATE) ----------------
__global__ __launch_bounds__(256) void gnorm_kernel(
    const float* __restrict__ Y, const u16* __restrict__ Rb, const u16* __restrict__ Kb,
    const u16* __restrict__ Vb, const float* __restrict__ r_k,
    const float* __restrict__ gnw, const float* __restrict__ gnb,
    u16* __restrict__ GATE_OG)
{
    int g = blockIdx.x * 4 + (threadIdx.x >> 6);
    int lane = threadIdx.x & 63;
    int h = g & (Hx - 1);
    size_t idx = (size_t)g * 64 + lane;
    int hd = h * 64 + lane;
    float y = Y[idx];
    float r = bf2f(Rb[idx]), k = bf2f(Kb[idx]), v = bf2f(Vb[idx]);
    float rkr = r * k * r_k[hd];
    float s1 = y, s2 = y * y, s3 = rkr;
#pragma unroll
    for (int off = 32; off > 0; off >>= 1) {
        s1 += __shfl_xor(s1, off, 64);
        s2 += __shfl_xor(s2, off, 64);
        s3 += __shfl_xor(s3, off, 64);
    }
    float mean = s1 * (1.f / 64.f);
    float var  = s2 * (1.f / 64.f) - mean * mean;
    float inv = 1.f / sqrtf(var + EPS_GN);
    float o = gnw[hd] * ((y - mean) * inv) + gnb[hd];
    o += s3 * v;
    GATE_OG[idx] = f2bf(o * bf2f(GATE_OG[idx]));
}

// ---------------- launch ----------------
extern "C" void kernel_launch(void* const* d_in, const int* in_sizes, int n_in,
                              void* d_out, int out_size, void* d_ws, size_t ws_size,
                              hipStream_t stream_)
{
    const float* x      = (const float*)d_in[0];
    const float* vfirst = (const float*)d_in[1];
    const float* x_r = (const float*)d_in[2];
    const float* x_w = (const float*)d_in[3];
    const float* x_k = (const float*)d_in[4];
    const float* x_v = (const float*)d_in[5];
    const float* x_a = (const float*)d_in[6];
    const float* x_g = (const float*)d_in[7];
    const float* k_k = (const float*)d_in[8];
    const float* k_a = (const float*)d_in[9];
    const float* r_k = (const float*)d_in[10];
    const float* Wr  = (const float*)d_in[11];
    const float* Wk  = (const float*)d_in[12];
    const float* Wv  = (const float*)d_in[13];
    const float* Wo  = (const float*)d_in[14];
    const float* gnw = (const float*)d_in[15];
    const float* gnb = (const float*)d_in[16];
    const float* wA  = (const float*)d_in[17];
    const float* wB  = (const float*)d_in[18];
    const float* wb  = (const float*)d_in[19];
    const float* vA  = (const float*)d_in[20];
    const float* vB  = (const float*)d_in[21];
    const float* vb  = (const float*)d_in[22];
    const float* aA  = (const float*)d_in[23];
    const float* aB  = (const float*)d_in[24];
    const float* ab  = (const float*)d_in[25];
    const float* gA  = (const float*)d_in[26];
    const float* gB  = (const float*)d_in[27];

    char* ws = (char*)d_ws;
    const size_t SLOT = (size_t)NTOK * Dx * 2;   // 16 MiB; 14 slots total (224 MiB, proven)
    u16* XR = (u16*)(ws + 0 * SLOT);
    u16* XW = (u16*)(ws + 1 * SLOT);
    u16* XK = (u16*)(ws + 2 * SLOT);
    u16* XV = (u16*)(ws + 3 * SLOT);
    u16* XA = (u16*)(ws + 4 * SLOT);
    u16* XG = (u16*)(ws + 5 * SLOT);
    u16* STREAM = (u16*)(ws + 0 * SLOT);         // 96MB, overwrites XR..XG after consumption
    u16* Rbuf = (u16*)(ws + 6 * SLOT);
    u16* Kbuf = (u16*)(ws + 7 * SLOT);
    u16* Vbuf = (u16*)(ws + 8 * SLOT);
    // slot 9 internal layout:
    u16* HW = (u16*)(ws + 9 * SLOT);             // lora hiddens (4.5MB)
    u16* HA = HW + (size_t)NTOK * 64;
    u16* HV = HA + (size_t)NTOK * 64;
    u16* HG = HV + (size_t)NTOK * 32;
    u16* Wo16 = HG + (size_t)NTOK * 128;         // +4.5MB, 2MB
    u16* SW = (u16*)(ws + 9 * SLOT + 8 * 1024 * 1024);  // small bf16 weights (1.2MB)
    u16* wAB = SW;
    u16* wBB = wAB + 65536;
    u16* vAB = wBB + 65536;
    u16* vBB = vAB + 32768;
    u16* aAB = vBB + 32768;
    u16* aBB = aAB + 65536;
    u16* gAB = aBB + 65536;
    u16* gBB = gAB + 131072;
    u16* Wr16 = (u16*)(ws + 9 * SLOT + 10 * 1024 * 1024);  // 3 x 2MB -> ends at 16MB
    u16* Wk16 = Wr16 + 1048576;
    u16* Wv16 = Wk16 + 1048576;
    u16* Wdec16 = (u16*)(ws + 10 * SLOT);        // bf16 decay; dead after prep_pack
    u16* ICLR   = (u16*)(ws + 11 * SLOT);        // dead after prep_pack
    u16* VVb    = (u16*)(ws + 12 * SLOT);        // dead after prep_pack
    float* Yb   = (float*)(ws + 10 * SLOT);      // fp32, slots 10-11 (aliases Wdec16/ICLR, ordered)
    u16* GATE   = (u16*)(ws + 13 * SLOT);        // gnorm writes OG in-place

    dim3 blk(256);
    conv_kernel<<<dim3(1024, 12), blk, 0, stream_>>>(
        wA, wB, vA, vB, aA, aB, gA, gB, Wr, Wk, Wv, Wo,
        wAB, wBB, vAB, vBB, aAB, aBB, gAB, gBB, Wr16, Wk16, Wv16, Wo16);
    mix_kernel<<<(NTOK * Dx / 4) / 256, blk, 0, stream_>>>(x, x_r, x_w, x_k, x_v, x_a, x_g,
                                                           XR, XW, XK, XV, XA, XG);
    // fused R/K/V projections (bf16 weights, m97-staging)
    gemm_rkv_kernel<<<dim3(64, 8, 3), blk, 0, stream_>>>(XR, XK, XV, Wr16, Wk16, Wv16,
                                                         Rbuf, Kbuf, Vbuf);
    // lora stage 1 (fused: W,A,V,G-lo,G-hi)
    lora1_kernel<<<dim3(64, 5), blk, 0, stream_>>>(XW, XA, XV, XG, wAB, aAB, vAB, gAB,
                                                   HW, HA, HV, HG);
    // lora stage 2
    gemm_nt<128, 3, true,  false><<<dim3(64, 8), blk, 0, stream_>>>(HW, wBB, wb, Wdec16, NTOK, 1024, 64);
    gemm_nt<128, 1, true,  false><<<dim3(64, 8), blk, 0, stream_>>>(HA, aBB, ab, ICLR, NTOK, 1024, 64);
    gemm_nt<128, 1, true,  false><<<dim3(64, 8), blk, 0, stream_>>>(HV, vBB, vb, VVb, NTOK, 1024, 32);
    gemm_nt<128, 0, false, false><<<dim3(64, 8), blk, 0, stream_>>>(HG, gBB, nullptr, GATE, NTOK, 1024, 128);

    prep_pack_kernel<<<(NTOK * Hx) / 4, blk, 0, stream_>>>(Kbuf, Vbuf, Rbuf, Wdec16, ICLR, VVb,
                                                           vfirst, k_k, k_a, STREAM);
    scan_kernel<<<512, blk, 0, stream_>>>(STREAM, Yb);
    gnorm_kernel<<<(NTOK * Hx) / 4, blk, 0, stream_>>>(Yb, Rbuf, Kbuf, Vbuf, r_k, gnw, gnb, GATE);
    gemm_nt<128, 0, false, true><<<dim3(64, 8), blk, 0, stream_>>>(GATE, Wo16, nullptr, d_out, NTOK, 1024, 1024);
}

// Round 7
// 700.739 us; speedup vs baseline: 1.3092x; 1.0078x over previous
//
#include <hip/hip_runtime.h>
#include <cmath>

// RWKV7 time-mixing, B=4 L=2048 D=1024 H=16 Dh=64. Inputs/outputs fp32; internal bf16.
// conv(all wts->bf16) -> mix -> proj(RKV + lora1 fused, grid.z) -> lora2(4-in-1, grid.z)
// -> prep_pack -> scan v9 (XCD-colocated, permlane reduce, deferred y) -> gnorm(stream k/v)
// -> out GEMM. GEMMs: m97-style staging (global_load_lds width=16, linear LDS).

#define DEV __device__ __forceinline__

typedef unsigned short u16;
typedef unsigned int u32;
typedef __bf16 bf16x8 __attribute__((ext_vector_type(8)));
typedef float f32x4 __attribute__((ext_vector_type(4)));

constexpr int Bx = 4, Lx = 2048, Dx = 1024, Hx = 16, Dh = 64;
constexpr int NTOK = Bx * Lx;       // 8192
constexpr float EPS_GN = 0.00064f;
constexpr int STEP_U16 = 384;       // 768B per step: r|k|a|b|v|w (64 bf16 each)
constexpr int TB = 16;              // steps per scan batch
constexpr int NB = Lx / TB;         // 128 batches
constexpr int BATCH_U16 = TB * STEP_U16;   // 6144 u16 = 12288 B

DEV float bf2f(u16 u) { union { u32 i; float f; } c; c.i = ((u32)u) << 16; return c.f; }
DEV u16 f2bf(float f) {
    union { float f; u32 i; } c; c.f = f;
    u32 r = c.i + 0x7FFFu + ((c.i >> 16) & 1u);
    return (u16)(r >> 16);
}
DEV void unpack2(u32 u, float& a, float& b) {
    union { u32 i; float f; } c0, c1;
    c0.i = u << 16; c1.i = u & 0xFFFF0000u;
    a = c0.f; b = c1.f;
}

// DPP butterfly add: v + v[lane ^ mask] for masks {1,2,7,15}, pure VALU.
template <int CTRL>
DEV float dpp_add(float v) {
    int p = __builtin_amdgcn_update_dpp(0, __float_as_int(v), CTRL, 0xF, 0xF, true);
    return v + __int_as_float(p);
}

// xor32 add via v_permlane32_swap_b32 (pure VALU).
DEV float xor32_add(float x) {
    float a = x, b = x;
    asm volatile("s_nop 1\n\tv_permlane32_swap_b32 %0, %1" : "+v"(a), "+v"(b));
    return a + b;
}

// Full reduce over a 32-lane row laid out as 16-group pair {G, G^32} (lanes i, i+32):
// 4 DPP hops (16-group sums) + xor32 cross. All VALU, no LDS pipe.
DEV float red32(float x) {
    x = dpp_add<0xB1>(x);
    x = dpp_add<0x4E>(x);
    x = dpp_add<0x141>(x);
    x = dpp_add<0x140>(x);
    return xor32_add(x);
}

// ---------------- f32 -> bf16 conversion: 8 lora tensors + 4 big projection weights ----------------
__global__ __launch_bounds__(256) void conv_kernel(
    const float* s0, const float* s1, const float* s2, const float* s3,
    const float* s4, const float* s5, const float* s6, const float* s7,
    const float* s8, const float* s9, const float* s10, const float* s11,
    u16* d0, u16* d1, u16* d2, u16* d3, u16* d4, u16* d5, u16* d6, u16* d7,
    u16* d8, u16* d9, u16* d10, u16* d11)
{
    const float* srcs[12] = {s0,s1,s2,s3,s4,s5,s6,s7,s8,s9,s10,s11};
    u16* dsts[12] = {d0,d1,d2,d3,d4,d5,d6,d7,d8,d9,d10,d11};
    const int ns[12] = {65536,65536,32768,32768,65536,65536,131072,131072,
                        1048576,1048576,1048576,1048576};
    int t = blockIdx.y;
    int i = (blockIdx.x * 256 + threadIdx.x) * 4;
    if (i >= ns[t]) return;
    float4 v = *(const float4*)(srcs[t] + i);
    ushort4 o;
    o.x = f2bf(v.x); o.y = f2bf(v.y); o.z = f2bf(v.z); o.w = f2bf(v.w);
    *(ushort4*)(dsts[t] + i) = o;
}

// ---------------- token-shift mix ----------------
__global__ __launch_bounds__(256) void mix_kernel(
    const float* __restrict__ x,
    const float* __restrict__ mr, const float* __restrict__ mw, const float* __restrict__ mk,
    const float* __restrict__ mv, const float* __restrict__ ma, const float* __restrict__ mg,
    u16* __restrict__ XR, u16* __restrict__ XW, u16* __restrict__ XK,
    u16* __restrict__ XV, u16* __restrict__ XA, u16* __restrict__ XG)
{
    int gi = blockIdx.x * 256 + threadIdx.x;
    int n  = gi >> 8;
    int d4 = (gi & 255) << 2;
    int l  = n & (Lx - 1);
    size_t o = (size_t)n * Dx + d4;
    float4 xc = *(const float4*)(x + o);
    float4 xp = make_float4(0.f, 0.f, 0.f, 0.f);
    if (l != 0) xp = *(const float4*)(x + o - Dx);
    float dx0 = xp.x - xc.x, dx1 = xp.y - xc.y, dx2 = xp.z - xc.z, dx3 = xp.w - xc.w;
    const float* mvs[6] = {mr, mw, mk, mv, ma, mg};
    u16* dsts[6] = {XR, XW, XK, XV, XA, XG};
#pragma unroll
    for (int j = 0; j < 6; ++j) {
        float4 m = *(const float4*)(mvs[j] + d4);
        ushort4 r;
        r.x = f2bf(fmaf(dx0, m.x, xc.x));
        r.y = f2bf(fmaf(dx1, m.y, xc.y));
        r.z = f2bf(fmaf(dx2, m.z, xc.z));
        r.w = f2bf(fmaf(dx3, m.w, xc.w));
        *(ushort4*)(dsts[j] + o) = r;
    }
}

// ---------------- bf16 MFMA GEMM body (template act), m97-style staging ----------------
template <int BN, int ACT, bool BIAS, bool F32OUT>
DEV void gemm_body(const u16* __restrict__ A, const u16* __restrict__ B16,
                   const float* __restrict__ bias, void* __restrict__ Cv,
                   int M, int N, int K, int bx, int by)
{
    constexpr int BM = 128, BK = 32;
    constexpr int WGM = (BN == 128) ? 2 : 4;
    constexpr int WGN = (BN == 128) ? 2 : 1;
    constexpr int WTM = BM / WGM, WTN = BN / WGN;
    constexpr int ITM = WTM / 16, ITN = WTN / 16;
    __shared__ __align__(16) u16 Asm[BM * BK];   // 8 KB
    __shared__ __align__(16) u16 Bsm[BN * BK];   // <= 8 KB
    const int tid = threadIdx.x;
    const int wid = tid >> 6, lane = tid & 63;
    const int q = lane >> 4, r16 = lane & 15;
    const size_t m0 = (size_t)bx * BM;
    const size_t n0 = (size_t)by * BN;
    const int wm = (wid % WGM) * WTM;
    const int wn = (wid / WGM) * WTN;
    f32x4 acc[ITM][ITN];
    const f32x4 zf = {0.f, 0.f, 0.f, 0.f};
#pragma unroll
    for (int i = 0; i < ITM; ++i)
#pragma unroll
        for (int j = 0; j < ITN; ++j) acc[i][j] = zf;

    for (int k0 = 0; k0 < K; k0 += BK) {
#pragma unroll
        for (int it = 0; it < 2; ++it) {
            int base = it * 2048 + wid * 512;            // u16 index, wave-uniform
            int pp = base + lane * 8;
            int row = pp >> 5, col = pp & 31;
            __builtin_amdgcn_global_load_lds(
                (const __attribute__((address_space(1))) void*)(A + (m0 + row) * K + k0 + col),
                (__attribute__((address_space(3))) void*)(Asm + base), 16, 0, 0);
        }
#pragma unroll
        for (int it = 0; it < (BN * BK + 2047) / 2048; ++it) {
            int base = it * 2048 + wid * 512;
            if (BN * BK >= 2048 || base < BN * BK) {
                int pp = base + lane * 8;
                int row = pp >> 5, col = pp & 31;
                __builtin_amdgcn_global_load_lds(
                    (const __attribute__((address_space(1))) void*)(B16 + (n0 + row) * K + k0 + col),
                    (__attribute__((address_space(3))) void*)(Bsm + base), 16, 0, 0);
            }
        }
        __syncthreads();   // vmcnt(0): tiles resident
        bf16x8 af[ITM], bfr[ITN];
#pragma unroll
        for (int im = 0; im < ITM; ++im)
            af[im] = *(const bf16x8*)&Asm[(wm + im * 16 + r16) * BK + q * 8];
#pragma unroll
        for (int in = 0; in < ITN; ++in)
            bfr[in] = *(const bf16x8*)&Bsm[(wn + in * 16 + r16) * BK + q * 8];
#pragma unroll
        for (int im = 0; im < ITM; ++im)
#pragma unroll
            for (int in = 0; in < ITN; ++in)
                acc[im][in] = __builtin_amdgcn_mfma_f32_16x16x32_bf16(af[im], bfr[in], acc[im][in], 0, 0, 0);
        __syncthreads();   // all reads done before next stage overwrites
    }
#pragma unroll
    for (int im = 0; im < ITM; ++im) {
#pragma unroll
        for (int in = 0; in < ITN; ++in) {
#pragma unroll
            for (int e = 0; e < 4; ++e) {
                size_t row = m0 + wm + im * 16 + q * 4 + e;
                size_t col = n0 + wn + in * 16 + r16;
                float val = acc[im][in][e];
                if constexpr (BIAS) val += bias[col];
                if constexpr (ACT == 1) val = 1.f / (1.f + __expf(-val));
                else if constexpr (ACT == 2) val = tanhf(val);
                else if constexpr (ACT == 3) val = __expf(-0.606531f / (1.f + __expf(-val)));
                if constexpr (F32OUT) ((float*)Cv)[row * (size_t)N + col] = val;
                else ((u16*)Cv)[row * (size_t)N + col] = f2bf(val);
            }
        }
    }
}

// Runtime act/bias variant (BN=128, bf16 out) for the fused lora2 dispatch.
DEV void gemm_body_rt(const u16* __restrict__ A, const u16* __restrict__ B16,
                      const float* __restrict__ bias, u16* __restrict__ C,
                      int N, int K, int act, int bx, int by)
{
    constexpr int BM = 128, BN = 128, BK = 32;
    constexpr int ITM = 4, ITN = 4;   // WGM=2, WGN=2
    __shared__ __align__(16) u16 Asm[BM * BK];
    __shared__ __align__(16) u16 Bsm[BN * BK];
    const int tid = threadIdx.x;
    const int wid = tid >> 6, lane = tid & 63;
    const int q = lane >> 4, r16 = lane & 15;
    const size_t m0 = (size_t)bx * BM;
    const size_t n0 = (size_t)by * BN;
    const int wm = (wid % 2) * 64;
    const int wn = (wid / 2) * 64;
    f32x4 acc[ITM][ITN];
    const f32x4 zf = {0.f, 0.f, 0.f, 0.f};
#pragma unroll
    for (int i = 0; i < ITM; ++i)
#pragma unroll
        for (int j = 0; j < ITN; ++j) acc[i][j] = zf;

    for (int k0 = 0; k0 < K; k0 += BK) {
#pragma unroll
        for (int it = 0; it < 2; ++it) {
            int base = it * 2048 + wid * 512;
            int pp = base + lane * 8;
            int row = pp >> 5, col = pp & 31;
            __builtin_amdgcn_global_load_lds(
                (const __attribute__((address_space(1))) void*)(A + (m0 + row) * K + k0 + col),
                (__attribute__((address_space(3))) void*)(Asm + base), 16, 0, 0);
        }
#pragma unroll
        for (int it = 0; it < 2; ++it) {
            int base = it * 2048 + wid * 512;
            int pp = base + lane * 8;
            int row = pp >> 5, col = pp & 31;
            __builtin_amdgcn_global_load_lds(
                (const __attribute__((address_space(1))) void*)(B16 + (n0 + row) * K + k0 + col),
                (__attribute__((address_space(3))) void*)(Bsm + base), 16, 0, 0);
        }
        __syncthreads();
        bf16x8 af[ITM], bfr[ITN];
#pragma unroll
        for (int im = 0; im < ITM; ++im)
            af[im] = *(const bf16x8*)&Asm[(wm + im * 16 + r16) * BK + q * 8];
#pragma unroll
        for (int in = 0; in < ITN; ++in)
            bfr[in] = *(const bf16x8*)&Bsm[(wn + in * 16 + r16) * BK + q * 8];
#pragma unroll
        for (int im = 0; im < ITM; ++im)
#pragma unroll
            for (int in = 0; in < ITN; ++in)
                acc[im][in] = __builtin_amdgcn_mfma_f32_16x16x32_bf16(af[im], bfr[in], acc[im][in], 0, 0, 0);
        __syncthreads();
    }
#pragma unroll
    for (int im = 0; im < ITM; ++im) {
#pragma unroll
        for (int in = 0; in < ITN; ++in) {
#pragma unroll
            for (int e = 0; e < 4; ++e) {
                size_t row = m0 + wm + im * 16 + q * 4 + e;
                size_t col = n0 + wn + in * 16 + r16;
                float val = acc[im][in][e];
                if (bias) val += bias[col];
                if (act == 1) val = 1.f / (1.f + __expf(-val));
                else if (act == 3) val = __expf(-0.606531f / (1.f + __expf(-val)));
                C[row * (size_t)N + col] = f2bf(val);
            }
        }
    }
}

// lora1 body (BM=128, BN=64, K=1024), cfg selects slice.
DEV void lora1_body(int cfg,
    const u16* __restrict__ XW, const u16* __restrict__ XA,
    const u16* __restrict__ XV, const u16* __restrict__ XG,
    const u16* __restrict__ wAB, const u16* __restrict__ aAB,
    const u16* __restrict__ vAB, const u16* __restrict__ gAB,
    u16* __restrict__ HW, u16* __restrict__ HA,
    u16* __restrict__ HV, u16* __restrict__ HG, int bx)
{
    constexpr int BM = 128, BK = 32, K = 1024;
    constexpr int ITM = 2, ITN = 4;   // wave: 32 rows x 64 cols
    const u16* A; const u16* Bm; u16* C; int ldC, Nv, act;
    if (cfg == 0)      { A = XW; Bm = wAB;            C = HW;      ldC = 64;  Nv = 64; act = 2; }
    else if (cfg == 1) { A = XA; Bm = aAB;            C = HA;      ldC = 64;  Nv = 64; act = 0; }
    else if (cfg == 2) { A = XV; Bm = vAB;            C = HV;      ldC = 32;  Nv = 32; act = 0; }
    else if (cfg == 3) { A = XG; Bm = gAB;            C = HG;      ldC = 128; Nv = 64; act = 1; }
    else               { A = XG; Bm = gAB + 64 * K;   C = HG + 64; ldC = 128; Nv = 64; act = 1; }

    __shared__ __align__(16) u16 Asm1[BM * BK];
    __shared__ __align__(16) u16 Bsm1[64 * BK];
    const int tid = threadIdx.x;
    const int wid = tid >> 6, lane = tid & 63;
    const int q = lane >> 4, r16 = lane & 15;
    const size_t m0 = (size_t)bx * BM;
    const int wm = wid * 32;
    f32x4 acc[ITM][ITN];
    const f32x4 zf = {0.f, 0.f, 0.f, 0.f};
#pragma unroll
    for (int i = 0; i < ITM; ++i)
#pragma unroll
        for (int j = 0; j < ITN; ++j) acc[i][j] = zf;

    for (int k0 = 0; k0 < K; k0 += BK) {
#pragma unroll
        for (int it = 0; it < 2; ++it) {
            int base = it * 2048 + wid * 512;
            int pp = base + lane * 8;
            int row = pp >> 5, col = pp & 31;
            __builtin_amdgcn_global_load_lds(
                (const __attribute__((address_space(1))) void*)(A + (m0 + row) * K + k0 + col),
                (__attribute__((address_space(3))) void*)(Asm1 + base), 16, 0, 0);
        }
        {
            int base = wid * 512;
            int pp = base + lane * 8;
            int row = pp >> 5, col = pp & 31;
            __builtin_amdgcn_global_load_lds(
                (const __attribute__((address_space(1))) void*)(Bm + row * K + k0 + col),
                (__attribute__((address_space(3))) void*)(Bsm1 + base), 16, 0, 0);
        }
        __syncthreads();
        bf16x8 af[ITM], bfr[ITN];
#pragma unroll
        for (int im = 0; im < ITM; ++im)
            af[im] = *(const bf16x8*)&Asm1[(wm + im * 16 + r16) * BK + q * 8];
#pragma unroll
        for (int in = 0; in < ITN; ++in)
            bfr[in] = *(const bf16x8*)&Bsm1[(in * 16 + r16) * BK + q * 8];
#pragma unroll
        for (int im = 0; im < ITM; ++im)
#pragma unroll
            for (int in = 0; in < ITN; ++in)
                acc[im][in] = __builtin_amdgcn_mfma_f32_16x16x32_bf16(af[im], bfr[in], acc[im][in], 0, 0, 0);
        __syncthreads();
    }
#pragma unroll
    for (int im = 0; im < ITM; ++im) {
#pragma unroll
        for (int in = 0; in < ITN; ++in) {
#pragma unroll
            for (int e = 0; e < 4; ++e) {
                size_t row = m0 + wm + im * 16 + q * 4 + e;
                int col = in * 16 + r16;
                if (col < Nv) {
                    float val = acc[im][in][e];
                    if (act == 1) val = 1.f / (1.f + __expf(-val));
                    else if (act == 2) val = tanhf(val);
                    C[row * (size_t)ldC + col] = f2bf(val);
                }
            }
        }
    }
}

// fused projections: z 0-2 = R/K/V GEMMs; z=3 = lora1 slices (y=cfg, y>=5 idle)
__global__ __launch_bounds__(256) void proj_kernel(
    const u16* __restrict__ XR, const u16* __restrict__ XK, const u16* __restrict__ XV,
    const u16* __restrict__ XW, const u16* __restrict__ XA, const u16* __restrict__ XG,
    const u16* __restrict__ Wr16, const u16* __restrict__ Wk16, const u16* __restrict__ Wv16,
    const u16* __restrict__ wAB, const u16* __restrict__ aAB,
    const u16* __restrict__ vAB, const u16* __restrict__ gAB,
    u16* __restrict__ Rbuf, u16* __restrict__ Kbuf, u16* __restrict__ Vbuf,
    u16* __restrict__ HW, u16* __restrict__ HA, u16* __restrict__ HV, u16* __restrict__ HG)
{
    const int z = blockIdx.z;
    if (z < 3) {
        const u16* A; const u16* Bm; u16* C;
        if (z == 0)      { A = XR; Bm = Wr16; C = Rbuf; }
        else if (z == 1) { A = XK; Bm = Wk16; C = Kbuf; }
        else             { A = XV; Bm = Wv16; C = Vbuf; }
        gemm_body<128, 0, false, false>(A, Bm, nullptr, C, NTOK, 1024, 1024,
                                        blockIdx.x, blockIdx.y);
    } else {
        if (blockIdx.y >= 5) return;
        lora1_body(blockIdx.y, XW, XA, XV, XG, wAB, aAB, vAB, gAB, HW, HA, HV, HG,
                   blockIdx.x);
    }
}

// fused lora stage-2: z selects {decay, iclr, vv, gate}
__global__ __launch_bounds__(256) void lora2_kernel(
    const u16* __restrict__ HW, const u16* __restrict__ HA,
    const u16* __restrict__ HV, const u16* __restrict__ HG,
    const u16* __restrict__ wBB, const u16* __restrict__ aBB,
    const u16* __restrict__ vBB, const u16* __restrict__ gBB,
    const float* __restrict__ wb, const float* __restrict__ ab, const float* __restrict__ vb,
    u16* __restrict__ Wdec16, u16* __restrict__ ICLR,
    u16* __restrict__ VVb, u16* __restrict__ GATE)
{
    const int z = blockIdx.z;
    const u16* A; const u16* Bm; const float* bias; u16* C; int K, act;
    if (z == 0)      { A = HW; Bm = wBB; bias = wb;      C = Wdec16; K = 64;  act = 3; }
    else if (z == 1) { A = HA; Bm = aBB; bias = ab;      C = ICLR;   K = 64;  act = 1; }
    else if (z == 2) { A = HV; Bm = vBB; bias = vb;      C = VVb;    K = 32;  act = 1; }
    else             { A = HG; Bm = gBB; bias = nullptr; C = GATE;   K = 128; act = 0; }
    gemm_body_rt(A, Bm, bias, C, 1024, K, act, blockIdx.x, blockIdx.y);
}

// final output GEMM (f32 out)
__global__ __launch_bounds__(256) void gemm_out_kernel(
    const u16* __restrict__ A, const u16* __restrict__ B16, float* __restrict__ C)
{
    gemm_body<128, 0, false, true>(A, B16, nullptr, C, NTOK, 1024, 1024,
                                   blockIdx.x, blockIdx.y);
}

// ---------------- prep + pack: kk-norm, a/b, k/v updates, emit packed stream ----------------
__global__ __launch_bounds__(256) void prep_pack_kernel(
    const u16* __restrict__ Kb, const u16* __restrict__ Vb,
    const u16* __restrict__ Rb, const u16* __restrict__ Wd16,
    const u16* __restrict__ ICLR, const u16* __restrict__ VVb, const float* __restrict__ vfirst,
    const float* __restrict__ k_k, const float* __restrict__ k_a,
    u16* __restrict__ stream)
{
    int g = blockIdx.x * 4 + (threadIdx.x >> 6);   // (token,head) pair: n = g>>4, h = g&15
    int lane = threadIdx.x & 63;
    int h = g & (Hx - 1);
    int n = g >> 4;
    size_t idx = (size_t)g * 64 + lane;            // == n*1024 + h*64 + lane
    int hd = h * 64 + lane;
    int l = n & (Lx - 1), b = n >> 11;
    size_t so = ((size_t)((b * 16 + h) * Lx + l)) * STEP_U16;

    float k = bf2f(Kb[idx]);
    float iclr = bf2f(ICLR[idx]);
    float kkn = k * k_k[hd];
    float s = kkn * kkn;
#pragma unroll
    for (int off = 32; off > 0; off >>= 1) s += __shfl_xor(s, off, 64);
    float nrm = fmaxf(sqrtf(s), 1e-7f);
    float kk = kkn / nrm;
    u16 knew = f2bf(k * (1.f + (iclr - 1.f) * k_a[hd]));
    float v = bf2f(Vb[idx]), vv = bf2f(VVb[idx]), vf = vfirst[idx];
    u16 vnew = f2bf(fmaf(vf - v, vv, v));
    stream[so + lane]       = Rb[idx];
    stream[so + 64 + lane]  = knew;
    stream[so + 128 + lane] = f2bf(-kk);
    stream[so + 192 + lane] = f2bf(kk * iclr);
    stream[so + 256 + lane] = vnew;
    stream[so + 320 + lane] = Wd16[idx];
}

// ---------------- WKV7 scan v9 (unchanged) ----------------
// 512 blocks = 64 (b,h) x 8 row-eighths, XCD-colocated; 4 waves/block;
// wave = 2 rows x 32 lanes, row lanes = {0-15 U 32-47} / {16-31 U 48-63};
// c=(lane&15)|((lane>>1)&16) owns cols 2c,2c+1. sa reduce = 4 DPP + permlane32_swap.
// y reduction deferred: per-step partial to padded LDS; per-batch flush sums.
__global__ __launch_bounds__(256, 2) void scan_kernel(
    const u16* __restrict__ stream, float* __restrict__ Y)
{
    const int bid = blockIdx.x;                   // 0..511; dispatch round-robins XCDs
    const int xcd = bid & 7, slot = bid >> 3;
    const int bh = xcd + ((slot & 7) << 3);       // 0..63: bh%8 == XCD -> co-located
    const int part = slot >> 3;                   // 0..7 (8 rows each)
    const int tid = threadIdx.x;
    const int lane = tid & 63;
    const int w = tid >> 6;
    const int c = (lane & 15) | ((lane >> 1) & 16);   // col-pair idx 0..31 (cols 2c,2c+1)
    const int rhalf = (lane >> 4) & 1;
    const int lr = w * 2 + rhalf;                 // local row 0..7
    const int row = part * 8 + lr;                // global row 0..63
    const size_t sbase = (size_t)bh * Lx * STEP_U16;
    const size_t ybase = (size_t)(bh >> 4) * ((size_t)Lx * Dx) + (size_t)(bh & 15) * 64;

    __shared__ __align__(16) u16 sbuf[2 * BATCH_U16];   // 24 KB
    __shared__ __align__(16) float yp[TB * 8 * 36];     // 18 KB padded partials

    float S0 = 0.f, S1 = 0.f;

    // stage batch 0 into buf 0 (wave w handles 1KB chunks 3w..3w+2)
    {
        const u16* g = stream + sbase;
#pragma unroll
        for (int cc = 0; cc < 3; ++cc) {
            const u16* gp = g + (3 * w + cc) * 512 + lane * 8;
            u16* lp = sbuf + (3 * w + cc) * 512;
            __builtin_amdgcn_global_load_lds(
                (const __attribute__((address_space(1))) void*)gp,
                (__attribute__((address_space(3))) void*)lp, 16, 0, 0);
        }
    }

    for (int bt = 0; bt < NB; ++bt) {
        const int cur = bt & 1;
        __syncthreads();   // vmcnt(0): batch bt resident; yp free from prev flush
        if (bt + 1 < NB) {
            const u16* g = stream + sbase + (size_t)(bt + 1) * BATCH_U16;
            u16* lbase = sbuf + (1 - cur) * BATCH_U16;
#pragma unroll
            for (int cc = 0; cc < 3; ++cc) {
                const u16* gp = g + (3 * w + cc) * 512 + lane * 8;
                u16* lp = lbase + (3 * w + cc) * 512;
                __builtin_amdgcn_global_load_lds(
                    (const __attribute__((address_space(1))) void*)gp,
                    (__attribute__((address_space(3))) void*)lp, 16, 0, 0);
            }
        }
        const u16* bp = sbuf + cur * BATCH_U16;
        const u16* cp = bp + c * 2;               // u16 offset 2c: cols 2c,2c+1
        u32 r2 = *(const u32*)(cp);
        u32 k2 = *(const u32*)(cp + 64);
        u32 a2 = *(const u32*)(cp + 128);
        u32 b2 = *(const u32*)(cp + 192);
        u32 w2 = *(const u32*)(cp + 320);
        float v = bf2f(bp[256 + row]);
#pragma unroll
        for (int s = 0; s < TB; ++s) {
            u32 nr = 0, nk = 0, na = 0, nb = 0, nw = 0;
            float nv = 0.f;
            if (s + 1 < TB) {          // compile-time under full unroll
                const u16* np = cp + (s + 1) * STEP_U16;
                nr = *(const u32*)(np);
                nk = *(const u32*)(np + 64);
                na = *(const u32*)(np + 128);
                nb = *(const u32*)(np + 192);
                nw = *(const u32*)(np + 320);
                nv = bf2f(bp[(s + 1) * STEP_U16 + 256 + row]);
            }
            float rr0, rr1, kk0, kk1, aa0, aa1, bb0, bb1, ww0, ww1;
            unpack2(r2, rr0, rr1);
            unpack2(k2, kk0, kk1);
            unpack2(a2, aa0, aa1);
            unpack2(b2, bb0, bb1);
            unpack2(w2, ww0, ww1);
            // sa_i = sum_j S_ij * a_j  (2 local + 32-lane all-VALU reduce)
            float sa = fmaf(S1, aa1, S0 * aa0);
            sa = red32(sa);
            // S_ij = S_ij*w_j + v_i*k_j + sa_i*b_j
            float t0 = fmaf(v, kk0, sa * bb0);
            float t1 = fmaf(v, kk1, sa * bb1);
            S0 = fmaf(S0, ww0, t0);
            S1 = fmaf(S1, ww1, t1);
            // y partial (2 cols) -> LDS; reduction deferred to flush
            float y = fmaf(S1, rr1, S0 * rr0);
            yp[(s * 8 + lr) * 36 + c] = y;
            r2 = nr; k2 = nk; a2 = na; b2 = nb; w2 = nw; v = nv;
        }
        __syncthreads();   // yp visible; batch bt+1 loads still in flight (vmem)
        // flush: 128 threads, each sums 32 partials of one (step,row) and stores
        if (tid < TB * 8) {
            const float* rp = &yp[tid * 36];
            f32x4 a4 = *(const f32x4*)(rp);
#pragma unroll
            for (int i = 1; i < 8; ++i) {
                f32x4 t4 = *(const f32x4*)(rp + i * 4);
                a4 += t4;
            }
            float yy = (a4[0] + a4[1]) + (a4[2] + a4[3]);
            int s = tid >> 3, j = tid & 7;
            Y[ybase + (size_t)(bt * TB + s) * Dx + part * 8 + j] = yy;
        }
    }
}

// ---------------- group-norm + rkr residual + gate (k/v from stream; OG in-place) ----------------
__global__ __launch_bounds__(256) void gnorm_kernel(
    const float* __restrict__ Y, const u16* __restrict__ Rb,
    const u16* __restrict__ stream, const float* __restrict__ r_k,
    const float* __restrict__ gnw, const float* __restrict__ gnb,
    u16* __restrict__ GATE_OG)
{
    int g = blockIdx.x * 4 + (threadIdx.x >> 6);
    int lane = threadIdx.x & 63;
    int h = g & (Hx - 1);
    int n = g >> 4;
    size_t idx = (size_t)g * 64 + lane;
    int hd = h * 64 + lane;
    int l = n & (Lx - 1), b = n >> 11;
    size_t so = ((size_t)((b * 16 + h) * Lx + l)) * STEP_U16;
    float y = Y[idx];
    float r = bf2f(Rb[idx]);
    float k = bf2f(stream[so + 64 + lane]);
    float v = bf2f(stream[so + 256 + lane]);
    float rkr = r * k * r_k[hd];
    float s1 = y, s2 = y * y, s3 = rkr;
#pragma unroll
    for (int off = 32; off > 0; off >>= 1) {
        s1 += __shfl_xor(s1, off, 64);
        s2 += __shfl_xor(s2, off, 64);
        s3 += __shfl_xor(s3, off, 64);
    }
    float mean = s1 * (1.f / 64.f);
    float var  = s2 * (1.f / 64.f) - mean * mean;
    float inv = 1.f / sqrtf(var + EPS_GN);
    float o = gnw[hd] * ((y - mean) * inv) + gnb[hd];
    o += s3 * v;
    GATE_OG[idx] = f2bf(o * bf2f(GATE_OG[idx]));
}

// ---------------- launch ----------------
extern "C" void kernel_launch(void* const* d_in, const int* in_sizes, int n_in,
                              void* d_out, int out_size, void* d_ws, size_t ws_size,
                              hipStream_t stream_)
{
    const float* x      = (const float*)d_in[0];
    const float* vfirst = (const float*)d_in[1];
    const float* x_r = (const float*)d_in[2];
    const float* x_w = (const float*)d_in[3];
    const float* x_k = (const float*)d_in[4];
    const float* x_v = (const float*)d_in[5];
    const float* x_a = (const float*)d_in[6];
    const float* x_g = (const float*)d_in[7];
    const float* k_k = (const float*)d_in[8];
    const float* k_a = (const float*)d_in[9];
    const float* r_k = (const float*)d_in[10];
    const float* Wr  = (const float*)d_in[11];
    const float* Wk  = (const float*)d_in[12];
    const float* Wv  = (const float*)d_in[13];
    const float* Wo  = (const float*)d_in[14];
    const float* gnw = (const float*)d_in[15];
    const float* gnb = (const float*)d_in[16];
    const float* wA  = (const float*)d_in[17];
    const float* wB  = (const float*)d_in[18];
    const float* wb  = (const float*)d_in[19];
    const float* vA  = (const float*)d_in[20];
    const float* vB  = (const float*)d_in[21];
    const float* vb  = (const float*)d_in[22];
    const float* aA  = (const float*)d_in[23];
    const float* aB  = (const float*)d_in[24];
    const float* ab  = (const float*)d_in[25];
    const float* gA  = (const float*)d_in[26];
    const float* gB  = (const float*)d_in[27];

    char* ws = (char*)d_ws;
    const size_t SLOT = (size_t)NTOK * Dx * 2;   // 16 MiB; 14 slots total (224 MiB, proven)
    u16* XR = (u16*)(ws + 0 * SLOT);
    u16* XW = (u16*)(ws + 1 * SLOT);
    u16* XK = (u16*)(ws + 2 * SLOT);
    u16* XV = (u16*)(ws + 3 * SLOT);
    u16* XA = (u16*)(ws + 4 * SLOT);
    u16* XG = (u16*)(ws + 5 * SLOT);
    u16* STREAM = (u16*)(ws + 0 * SLOT);         // 96MB, overwrites XR..XG after consumption
    u16* Rbuf = (u16*)(ws + 6 * SLOT);
    u16* Kbuf = (u16*)(ws + 7 * SLOT);
    u16* Vbuf = (u16*)(ws + 8 * SLOT);
    // slot 9 internal layout:
    u16* HW = (u16*)(ws + 9 * SLOT);             // lora hiddens (4.5MB)
    u16* HA = HW + (size_t)NTOK * 64;
    u16* HV = HA + (size_t)NTOK * 64;
    u16* HG = HV + (size_t)NTOK * 32;
    u16* Wo16 = HG + (size_t)NTOK * 128;         // +4.5MB, 2MB
    u16* SW = (u16*)(ws + 9 * SLOT + 8 * 1024 * 1024);  // small bf16 weights (1.2MB)
    u16* wAB = SW;
    u16* wBB = wAB + 65536;
    u16* vAB = wBB + 65536;
    u16* vBB = vAB + 32768;
    u16* aAB = vBB + 32768;
    u16* aBB = aAB + 65536;
    u16* gAB = aBB + 65536;
    u16* gBB = gAB + 131072;
    u16* Wr16 = (u16*)(ws + 9 * SLOT + 10 * 1024 * 1024);  // 3 x 2MB -> ends at 16MB
    u16* Wk16 = Wr16 + 1048576;
    u16* Wv16 = Wk16 + 1048576;
    u16* Wdec16 = (u16*)(ws + 10 * SLOT);        // bf16 decay; dead after prep_pack
    u16* ICLR   = (u16*)(ws + 11 * SLOT);        // dead after prep_pack
    u16* VVb    = (u16*)(ws + 12 * SLOT);        // dead after prep_pack
    float* Yb   = (float*)(ws + 10 * SLOT);      // fp32, slots 10-11 (aliases Wdec16/ICLR, ordered)
    u16* GATE   = (u16*)(ws + 13 * SLOT);        // gnorm writes OG in-place

    dim3 blk(256);
    conv_kernel<<<dim3(1024, 12), blk, 0, stream_>>>(
        wA, wB, vA, vB, aA, aB, gA, gB, Wr, Wk, Wv, Wo,
        wAB, wBB, vAB, vBB, aAB, aBB, gAB, gBB, Wr16, Wk16, Wv16, Wo16);
    mix_kernel<<<(NTOK * Dx / 4) / 256, blk, 0, stream_>>>(x, x_r, x_w, x_k, x_v, x_a, x_g,
                                                           XR, XW, XK, XV, XA, XG);
    // fused projections: R/K/V GEMMs (z 0-2) + lora1 slices (z 3)
    proj_kernel<<<dim3(64, 8, 4), blk, 0, stream_>>>(
        XR, XK, XV, XW, XA, XG, Wr16, Wk16, Wv16, wAB, aAB, vAB, gAB,
        Rbuf, Kbuf, Vbuf, HW, HA, HV, HG);
    // fused lora stage 2: decay/iclr/vv/gate
    lora2_kernel<<<dim3(64, 8, 4), blk, 0, stream_>>>(
        HW, HA, HV, HG, wBB, aBB, vBB, gBB, wb, ab, vb, Wdec16, ICLR, VVb, GATE);

    prep_pack_kernel<<<(NTOK * Hx) / 4, blk, 0, stream_>>>(Kbuf, Vbuf, Rbuf, Wdec16, ICLR, VVb,
                                                           vfirst, k_k, k_a, STREAM);
    scan_kernel<<<512, blk, 0, stream_>>>(STREAM, Yb);
    gnorm_kernel<<<(NTOK * Hx) / 4, blk, 0, stream_>>>(Yb, Rbuf, STREAM, r_k, gnw, gnb, GATE);
    gemm_out_kernel<<<dim3(64, 8), blk, 0, stream_>>>(GATE, Wo16, (float*)d_out);
}

// Round 8
// 691.340 us; speedup vs baseline: 1.3270x; 1.0136x over previous
//
#include <hip/hip_runtime.h>
#include <cmath>

// RWKV7 time-mixing, B=4 L=2048 D=1024 H=16 Dh=64. Inputs/outputs fp32; internal bf16.
// convmix(fused) -> proj(RKV + lora1, grid.z) -> lora2(4-in-1, grid.z) -> prep_pack ->
// scan v9 (XCD-colocated, permlane reduce, deferred y) -> gnorm(stream k/v) -> out GEMM.
// GEMMs: 2-phase double-buffered global_load_lds staging (T3-min: stage t+1 after the
// single per-tile barrier, compute t; vmcnt drain lands after a full compute phase).

#define DEV __device__ __forceinline__

typedef unsigned short u16;
typedef unsigned int u32;
typedef __bf16 bf16x8 __attribute__((ext_vector_type(8)));
typedef float f32x4 __attribute__((ext_vector_type(4)));

constexpr int Bx = 4, Lx = 2048, Dx = 1024, Hx = 16, Dh = 64;
constexpr int NTOK = Bx * Lx;       // 8192
constexpr float EPS_GN = 0.00064f;
constexpr int STEP_U16 = 384;       // 768B per step: r|k|a|b|v|w (64 bf16 each)
constexpr int TB = 16;              // steps per scan batch
constexpr int NB = Lx / TB;         // 128 batches
constexpr int BATCH_U16 = TB * STEP_U16;   // 6144 u16 = 12288 B

DEV float bf2f(u16 u) { union { u32 i; float f; } c; c.i = ((u32)u) << 16; return c.f; }
DEV u16 f2bf(float f) {
    union { float f; u32 i; } c; c.f = f;
    u32 r = c.i + 0x7FFFu + ((c.i >> 16) & 1u);
    return (u16)(r >> 16);
}
DEV void unpack2(u32 u, float& a, float& b) {
    union { u32 i; float f; } c0, c1;
    c0.i = u << 16; c1.i = u & 0xFFFF0000u;
    a = c0.f; b = c1.f;
}

// DPP butterfly add: v + v[lane ^ mask] for masks {1,2,7,15}, pure VALU.
template <int CTRL>
DEV float dpp_add(float v) {
    int p = __builtin_amdgcn_update_dpp(0, __float_as_int(v), CTRL, 0xF, 0xF, true);
    return v + __int_as_float(p);
}

// xor32 add via v_permlane32_swap_b32 (pure VALU).
DEV float xor32_add(float x) {
    float a = x, b = x;
    asm volatile("s_nop 1\n\tv_permlane32_swap_b32 %0, %1" : "+v"(a), "+v"(b));
    return a + b;
}

// Full reduce over a 32-lane row laid out as 16-group pair {G, G^32} (lanes i, i+32):
// 4 DPP hops (16-group sums) + xor32 cross. All VALU, no LDS pipe.
DEV float red32(float x) {
    x = dpp_add<0xB1>(x);
    x = dpp_add<0x4E>(x);
    x = dpp_add<0x141>(x);
    x = dpp_add<0x140>(x);
    return xor32_add(x);
}

// ---------------- fused conv (12 tensors f32->bf16) + token-shift mix ----------------
// blocks 0..8191: mix; blocks 8192..20479: conv (t = (bid-8192)>>10).
__global__ __launch_bounds__(256) void convmix_kernel(
    const float* __restrict__ x,
    const float* __restrict__ mr, const float* __restrict__ mw, const float* __restrict__ mk,
    const float* __restrict__ mv, const float* __restrict__ ma, const float* __restrict__ mg,
    u16* __restrict__ XR, u16* __restrict__ XW, u16* __restrict__ XK,
    u16* __restrict__ XV, u16* __restrict__ XA, u16* __restrict__ XG,
    const float* s0, const float* s1, const float* s2, const float* s3,
    const float* s4, const float* s5, const float* s6, const float* s7,
    const float* s8, const float* s9, const float* s10, const float* s11,
    u16* d0, u16* d1, u16* d2, u16* d3, u16* d4, u16* d5, u16* d6, u16* d7,
    u16* d8, u16* d9, u16* d10, u16* d11)
{
    const int bid = blockIdx.x;
    const int tid = threadIdx.x;
    if (bid < 8192) {
        int gi = bid * 256 + tid;
        int n  = gi >> 8;
        int d4v = (gi & 255) << 2;
        int l  = n & (Lx - 1);
        size_t o = (size_t)n * Dx + d4v;
        float4 xc = *(const float4*)(x + o);
        float4 xp = make_float4(0.f, 0.f, 0.f, 0.f);
        if (l != 0) xp = *(const float4*)(x + o - Dx);
        float dx0 = xp.x - xc.x, dx1 = xp.y - xc.y, dx2 = xp.z - xc.z, dx3 = xp.w - xc.w;
        const float* mvs[6] = {mr, mw, mk, mv, ma, mg};
        u16* dsts[6] = {XR, XW, XK, XV, XA, XG};
#pragma unroll
        for (int j = 0; j < 6; ++j) {
            float4 m = *(const float4*)(mvs[j] + d4v);
            ushort4 r;
            r.x = f2bf(fmaf(dx0, m.x, xc.x));
            r.y = f2bf(fmaf(dx1, m.y, xc.y));
            r.z = f2bf(fmaf(dx2, m.z, xc.z));
            r.w = f2bf(fmaf(dx3, m.w, xc.w));
            *(ushort4*)(dsts[j] + o) = r;
        }
    } else {
        const float* srcs[12] = {s0,s1,s2,s3,s4,s5,s6,s7,s8,s9,s10,s11};
        u16* dsts[12] = {d0,d1,d2,d3,d4,d5,d6,d7,d8,d9,d10,d11};
        const int ns[12] = {65536,65536,32768,32768,65536,65536,131072,131072,
                            1048576,1048576,1048576,1048576};
        int cb = bid - 8192;
        int t = cb >> 10;
        int i = ((cb & 1023) * 256 + tid) * 4;
        if (i >= ns[t]) return;
        float4 v = *(const float4*)(srcs[t] + i);
        ushort4 o;
        o.x = f2bf(v.x); o.y = f2bf(v.y); o.z = f2bf(v.z); o.w = f2bf(v.w);
        *(ushort4*)(dsts[t] + i) = o;
    }
}

// ---------------- bf16 MFMA GEMM body, 2-phase double-buffered staging ----------------
// smem pool: [2][BM*BK] A + [2][BN*BK] B. ACT: 0 none, 1 sigmoid, 2 tanh, 3 exp(-.6*sig).
template <int BN, int ACT, bool BIAS, bool F32OUT>
DEV void gemm_body(u16* __restrict__ smem,
                   const u16* __restrict__ A, const u16* __restrict__ B16,
                   const float* __restrict__ bias, void* __restrict__ Cv,
                   int M, int N, int K, int bx, int by)
{
    constexpr int BM = 128, BK = 32;
    constexpr int WGM = (BN == 128) ? 2 : 4;
    constexpr int WGN = (BN == 128) ? 2 : 1;
    constexpr int WTM = BM / WGM, WTN = BN / WGN;
    constexpr int ITM = WTM / 16, ITN = WTN / 16;
    u16* Asm0 = smem;                       // 2 x BM*BK
    u16* Bsm0 = smem + 2 * BM * BK;         // 2 x BN*BK
    const int tid = threadIdx.x;
    const int wid = tid >> 6, lane = tid & 63;
    const int q = lane >> 4, r16 = lane & 15;
    const size_t m0 = (size_t)bx * BM;
    const size_t n0 = (size_t)by * BN;
    const int wm = (wid % WGM) * WTM;
    const int wn = (wid / WGM) * WTN;
    f32x4 acc[ITM][ITN];
    const f32x4 zf = {0.f, 0.f, 0.f, 0.f};
#pragma unroll
    for (int i = 0; i < ITM; ++i)
#pragma unroll
        for (int j = 0; j < ITN; ++j) acc[i][j] = zf;

    // prologue: stage tile 0 into buf 0
#pragma unroll
    for (int it = 0; it < 2; ++it) {
        int base = it * 2048 + wid * 512;
        int pp = base + lane * 8;
        int row = pp >> 5, col = pp & 31;
        __builtin_amdgcn_global_load_lds(
            (const __attribute__((address_space(1))) void*)(A + (m0 + row) * K + col),
            (__attribute__((address_space(3))) void*)(Asm0 + base), 16, 0, 0);
    }
#pragma unroll
    for (int it = 0; it < (BN * BK + 2047) / 2048; ++it) {
        int base = it * 2048 + wid * 512;
        if (BN * BK >= 2048 || base < BN * BK) {
            int pp = base + lane * 8;
            int row = pp >> 5, col = pp & 31;
            __builtin_amdgcn_global_load_lds(
                (const __attribute__((address_space(1))) void*)(B16 + (n0 + row) * K + col),
                (__attribute__((address_space(3))) void*)(Bsm0 + base), 16, 0, 0);
        }
    }

    int t = 0;
    for (int k0 = 0; k0 < K; k0 += BK, ++t) {
        const int cur = t & 1;
        __syncthreads();   // one barrier/tile: drains buf[cur] loads (issued a full phase ago)
        if (k0 + BK < K) {
            u16* An = Asm0 + (cur ^ 1) * (BM * BK);
            u16* Bn = Bsm0 + (cur ^ 1) * (BN * BK);
            const int kn = k0 + BK;
#pragma unroll
            for (int it = 0; it < 2; ++it) {
                int base = it * 2048 + wid * 512;
                int pp = base + lane * 8;
                int row = pp >> 5, col = pp & 31;
                __builtin_amdgcn_global_load_lds(
                    (const __attribute__((address_space(1))) void*)(A + (m0 + row) * K + kn + col),
                    (__attribute__((address_space(3))) void*)(An + base), 16, 0, 0);
            }
#pragma unroll
            for (int it = 0; it < (BN * BK + 2047) / 2048; ++it) {
                int base = it * 2048 + wid * 512;
                if (BN * BK >= 2048 || base < BN * BK) {
                    int pp = base + lane * 8;
                    int row = pp >> 5, col = pp & 31;
                    __builtin_amdgcn_global_load_lds(
                        (const __attribute__((address_space(1))) void*)(B16 + (n0 + row) * K + kn + col),
                        (__attribute__((address_space(3))) void*)(Bn + base), 16, 0, 0);
                }
            }
        }
        const u16* Ac = Asm0 + cur * (BM * BK);
        const u16* Bc = Bsm0 + cur * (BN * BK);
        bf16x8 af[ITM], bfr[ITN];
#pragma unroll
        for (int im = 0; im < ITM; ++im)
            af[im] = *(const bf16x8*)&Ac[(wm + im * 16 + r16) * BK + q * 8];
#pragma unroll
        for (int in = 0; in < ITN; ++in)
            bfr[in] = *(const bf16x8*)&Bc[(wn + in * 16 + r16) * BK + q * 8];
#pragma unroll
        for (int im = 0; im < ITM; ++im)
#pragma unroll
            for (int in = 0; in < ITN; ++in)
                acc[im][in] = __builtin_amdgcn_mfma_f32_16x16x32_bf16(af[im], bfr[in], acc[im][in], 0, 0, 0);
    }
#pragma unroll
    for (int im = 0; im < ITM; ++im) {
#pragma unroll
        for (int in = 0; in < ITN; ++in) {
#pragma unroll
            for (int e = 0; e < 4; ++e) {
                size_t row = m0 + wm + im * 16 + q * 4 + e;
                size_t col = n0 + wn + in * 16 + r16;
                float val = acc[im][in][e];
                if constexpr (BIAS) val += bias[col];
                if constexpr (ACT == 1) val = 1.f / (1.f + __expf(-val));
                else if constexpr (ACT == 2) val = tanhf(val);
                else if constexpr (ACT == 3) val = __expf(-0.606531f / (1.f + __expf(-val)));
                if constexpr (F32OUT) ((float*)Cv)[row * (size_t)N + col] = val;
                else ((u16*)Cv)[row * (size_t)N + col] = f2bf(val);
            }
        }
    }
}

// Runtime act/bias variant (BM=BN=128, bf16 out), same 2-phase staging.
DEV void gemm_body_rt(u16* __restrict__ smem,
                      const u16* __restrict__ A, const u16* __restrict__ B16,
                      const float* __restrict__ bias, u16* __restrict__ C,
                      int N, int K, int act, int bx, int by)
{
    constexpr int BM = 128, BK = 32;
    constexpr int ITM = 4, ITN = 4;
    u16* Asm0 = smem;
    u16* Bsm0 = smem + 2 * BM * BK;
    const int tid = threadIdx.x;
    const int wid = tid >> 6, lane = tid & 63;
    const int q = lane >> 4, r16 = lane & 15;
    const size_t m0 = (size_t)bx * BM;
    const size_t n0 = (size_t)by * 128;
    const int wm = (wid % 2) * 64;
    const int wn = (wid / 2) * 64;
    f32x4 acc[ITM][ITN];
    const f32x4 zf = {0.f, 0.f, 0.f, 0.f};
#pragma unroll
    for (int i = 0; i < ITM; ++i)
#pragma unroll
        for (int j = 0; j < ITN; ++j) acc[i][j] = zf;

#pragma unroll
    for (int it = 0; it < 2; ++it) {
        int base = it * 2048 + wid * 512;
        int pp = base + lane * 8;
        int row = pp >> 5, col = pp & 31;
        __builtin_amdgcn_global_load_lds(
            (const __attribute__((address_space(1))) void*)(A + (m0 + row) * K + col),
            (__attribute__((address_space(3))) void*)(Asm0 + base), 16, 0, 0);
        __builtin_amdgcn_global_load_lds(
            (const __attribute__((address_space(1))) void*)(B16 + (n0 + row) * K + col),
            (__attribute__((address_space(3))) void*)(Bsm0 + base), 16, 0, 0);
    }

    int t = 0;
    for (int k0 = 0; k0 < K; k0 += BK, ++t) {
        const int cur = t & 1;
        __syncthreads();
        if (k0 + BK < K) {
            u16* An = Asm0 + (cur ^ 1) * (BM * BK);
            u16* Bn = Bsm0 + (cur ^ 1) * (BM * BK);
            const int kn = k0 + BK;
#pragma unroll
            for (int it = 0; it < 2; ++it) {
                int base = it * 2048 + wid * 512;
                int pp = base + lane * 8;
                int row = pp >> 5, col = pp & 31;
                __builtin_amdgcn_global_load_lds(
                    (const __attribute__((address_space(1))) void*)(A + (m0 + row) * K + kn + col),
                    (__attribute__((address_space(3))) void*)(An + base), 16, 0, 0);
                __builtin_amdgcn_global_load_lds(
                    (const __attribute__((address_space(1))) void*)(B16 + (n0 + row) * K + kn + col),
                    (__attribute__((address_space(3))) void*)(Bn + base), 16, 0, 0);
            }
        }
        const u16* Ac = Asm0 + cur * (BM * BK);
        const u16* Bc = Bsm0 + cur * (BM * BK);
        bf16x8 af[ITM], bfr[ITN];
#pragma unroll
        for (int im = 0; im < ITM; ++im)
            af[im] = *(const bf16x8*)&Ac[(wm + im * 16 + r16) * BK + q * 8];
#pragma unroll
        for (int in = 0; in < ITN; ++in)
            bfr[in] = *(const bf16x8*)&Bc[(wn + in * 16 + r16) * BK + q * 8];
#pragma unroll
        for (int im = 0; im < ITM; ++im)
#pragma unroll
            for (int in = 0; in < ITN; ++in)
                acc[im][in] = __builtin_amdgcn_mfma_f32_16x16x32_bf16(af[im], bfr[in], acc[im][in], 0, 0, 0);
    }
#pragma unroll
    for (int im = 0; im < ITM; ++im) {
#pragma unroll
        for (int in = 0; in < ITN; ++in) {
#pragma unroll
            for (int e = 0; e < 4; ++e) {
                size_t row = m0 + wm + im * 16 + q * 4 + e;
                size_t col = n0 + wn + in * 16 + r16;
                float val = acc[im][in][e];
                if (bias) val += bias[col];
                if (act == 1) val = 1.f / (1.f + __expf(-val));
                else if (act == 3) val = __expf(-0.606531f / (1.f + __expf(-val)));
                C[row * (size_t)N + col] = f2bf(val);
            }
        }
    }
}

// lora1 body (BM=128, BN=64, K=1024), 2-phase staging in shared pool, cfg selects slice.
DEV void lora1_body(u16* __restrict__ smem, int cfg,
    const u16* __restrict__ XW, const u16* __restrict__ XA,
    const u16* __restrict__ XV, const u16* __restrict__ XG,
    const u16* __restrict__ wAB, const u16* __restrict__ aAB,
    const u16* __restrict__ vAB, const u16* __restrict__ gAB,
    u16* __restrict__ HW, u16* __restrict__ HA,
    u16* __restrict__ HV, u16* __restrict__ HG, int bx)
{
    constexpr int BM = 128, BK = 32, K = 1024;
    constexpr int ITM = 2, ITN = 4;   // wave: 32 rows x 64 cols
    const u16* A; const u16* Bm; u16* C; int ldC, Nv, act;
    if (cfg == 0)      { A = XW; Bm = wAB;            C = HW;      ldC = 64;  Nv = 64; act = 2; }
    else if (cfg == 1) { A = XA; Bm = aAB;            C = HA;      ldC = 64;  Nv = 64; act = 0; }
    else if (cfg == 2) { A = XV; Bm = vAB;            C = HV;      ldC = 32;  Nv = 32; act = 0; }
    else if (cfg == 3) { A = XG; Bm = gAB;            C = HG;      ldC = 128; Nv = 64; act = 1; }
    else               { A = XG; Bm = gAB + 64 * K;   C = HG + 64; ldC = 128; Nv = 64; act = 1; }

    u16* Asm0 = smem;                 // 2 x 4096
    u16* Bsm0 = smem + 2 * BM * BK;   // 2 x 2048
    const int tid = threadIdx.x;
    const int wid = tid >> 6, lane = tid & 63;
    const int q = lane >> 4, r16 = lane & 15;
    const size_t m0 = (size_t)bx * BM;
    const int wm = wid * 32;
    f32x4 acc[ITM][ITN];
    const f32x4 zf = {0.f, 0.f, 0.f, 0.f};
#pragma unroll
    for (int i = 0; i < ITM; ++i)
#pragma unroll
        for (int j = 0; j < ITN; ++j) acc[i][j] = zf;

#pragma unroll
    for (int it = 0; it < 2; ++it) {
        int base = it * 2048 + wid * 512;
        int pp = base + lane * 8;
        int row = pp >> 5, col = pp & 31;
        __builtin_amdgcn_global_load_lds(
            (const __attribute__((address_space(1))) void*)(A + (m0 + row) * K + col),
            (__attribute__((address_space(3))) void*)(Asm0 + base), 16, 0, 0);
    }
    {
        int base = wid * 512;
        int pp = base + lane * 8;
        int row = pp >> 5, col = pp & 31;
        __builtin_amdgcn_global_load_lds(
            (const __attribute__((address_space(1))) void*)(Bm + row * K + col),
            (__attribute__((address_space(3))) void*)(Bsm0 + base), 16, 0, 0);
    }

    int t = 0;
    for (int k0 = 0; k0 < K; k0 += BK, ++t) {
        const int cur = t & 1;
        __syncthreads();
        if (k0 + BK < K) {
            u16* An = Asm0 + (cur ^ 1) * (BM * BK);
            u16* Bn = Bsm0 + (cur ^ 1) * 2048;
            const int kn = k0 + BK;
#pragma unroll
            for (int it = 0; it < 2; ++it) {
                int base = it * 2048 + wid * 512;
                int pp = base + lane * 8;
                int row = pp >> 5, col = pp & 31;
                __builtin_amdgcn_global_load_lds(
                    (const __attribute__((address_space(1))) void*)(A + (m0 + row) * K + kn + col),
                    (__attribute__((address_space(3))) void*)(An + base), 16, 0, 0);
            }
            {
                int base = wid * 512;
                int pp = base + lane * 8;
                int row = pp >> 5, col = pp & 31;
                __builtin_amdgcn_global_load_lds(
                    (const __attribute__((address_space(1))) void*)(Bm + row * K + kn + col),
                    (__attribute__((address_space(3))) void*)(Bn + base), 16, 0, 0);
            }
        }
        const u16* Ac = Asm0 + cur * (BM * BK);
        const u16* Bc = Bsm0 + cur * 2048;
        bf16x8 af[ITM], bfr[ITN];
#pragma unroll
        for (int im = 0; im < ITM; ++im)
            af[im] = *(const bf16x8*)&Ac[(wm + im * 16 + r16) * BK + q * 8];
#pragma unroll
        for (int in = 0; in < ITN; ++in)
            bfr[in] = *(const bf16x8*)&Bc[(in * 16 + r16) * BK + q * 8];
#pragma unroll
        for (int im = 0; im < ITM; ++im)
#pragma unroll
            for (int in = 0; in < ITN; ++in)
                acc[im][in] = __builtin_amdgcn_mfma_f32_16x16x32_bf16(af[im], bfr[in], acc[im][in], 0, 0, 0);
    }
#pragma unroll
    for (int im = 0; im < ITM; ++im) {
#pragma unroll
        for (int in = 0; in < ITN; ++in) {
#pragma unroll
            for (int e = 0; e < 4; ++e) {
                size_t row = m0 + wm + im * 16 + q * 4 + e;
                int col = in * 16 + r16;
                if (col < Nv) {
                    float val = acc[im][in][e];
                    if (act == 1) val = 1.f / (1.f + __expf(-val));
                    else if (act == 2) val = tanhf(val);
                    C[row * (size_t)ldC + col] = f2bf(val);
                }
            }
        }
    }
}

// fused projections: z 0-2 = R/K/V GEMMs; z=3 = lora1 slices (y=cfg, y>=5 idle)
__global__ __launch_bounds__(256) void proj_kernel(
    const u16* __restrict__ XR, const u16* __restrict__ XK, const u16* __restrict__ XV,
    const u16* __restrict__ XW, const u16* __restrict__ XA, const u16* __restrict__ XG,
    const u16* __restrict__ Wr16, const u16* __restrict__ Wk16, const u16* __restrict__ Wv16,
    const u16* __restrict__ wAB, const u16* __restrict__ aAB,
    const u16* __restrict__ vAB, const u16* __restrict__ gAB,
    u16* __restrict__ Rbuf, u16* __restrict__ Kbuf, u16* __restrict__ Vbuf,
    u16* __restrict__ HW, u16* __restrict__ HA, u16* __restrict__ HV, u16* __restrict__ HG)
{
    __shared__ __align__(16) u16 pool[16384];   // 32 KB
    const int z = blockIdx.z;
    if (z < 3) {
        const u16* A; const u16* Bm; u16* C;
        if (z == 0)      { A = XR; Bm = Wr16; C = Rbuf; }
        else if (z == 1) { A = XK; Bm = Wk16; C = Kbuf; }
        else             { A = XV; Bm = Wv16; C = Vbuf; }
        gemm_body<128, 0, false, false>(pool, A, Bm, nullptr, C, NTOK, 1024, 1024,
                                        blockIdx.x, blockIdx.y);
    } else {
        if (blockIdx.y >= 5) return;
        lora1_body(pool, blockIdx.y, XW, XA, XV, XG, wAB, aAB, vAB, gAB, HW, HA, HV, HG,
                   blockIdx.x);
    }
}

// fused lora stage-2: z selects {decay, iclr, vv, gate}
__global__ __launch_bounds__(256) void lora2_kernel(
    const u16* __restrict__ HW, const u16* __restrict__ HA,
    const u16* __restrict__ HV, const u16* __restrict__ HG,
    const u16* __restrict__ wBB, const u16* __restrict__ aBB,
    const u16* __restrict__ vBB, const u16* __restrict__ gBB,
    const float* __restrict__ wb, const float* __restrict__ ab, const float* __restrict__ vb,
    u16* __restrict__ Wdec16, u16* __restrict__ ICLR,
    u16* __restrict__ VVb, u16* __restrict__ GATE)
{
    __shared__ __align__(16) u16 pool[16384];
    const int z = blockIdx.z;
    const u16* A; const u16* Bm; const float* bias; u16* C; int K, act;
    if (z == 0)      { A = HW; Bm = wBB; bias = wb;      C = Wdec16; K = 64;  act = 3; }
    else if (z == 1) { A = HA; Bm = aBB; bias = ab;      C = ICLR;   K = 64;  act = 1; }
    else if (z == 2) { A = HV; Bm = vBB; bias = vb;      C = VVb;    K = 32;  act = 1; }
    else             { A = HG; Bm = gBB; bias = nullptr; C = GATE;   K = 128; act = 0; }
    gemm_body_rt(pool, A, Bm, bias, C, 1024, K, act, blockIdx.x, blockIdx.y);
}

// final output GEMM (f32 out)
__global__ __launch_bounds__(256) void gemm_out_kernel(
    const u16* __restrict__ A, const u16* __restrict__ B16, float* __restrict__ C)
{
    __shared__ __align__(16) u16 pool[16384];
    gemm_body<128, 0, false, true>(pool, A, B16, nullptr, C, NTOK, 1024, 1024,
                                   blockIdx.x, blockIdx.y);
}

// ---------------- prep + pack: kk-norm, a/b, k/v updates, emit packed stream ----------------
__global__ __launch_bounds__(256) void prep_pack_kernel(
    const u16* __restrict__ Kb, const u16* __restrict__ Vb,
    const u16* __restrict__ Rb, const u16* __restrict__ Wd16,
    const u16* __restrict__ ICLR, const u16* __restrict__ VVb, const float* __restrict__ vfirst,
    const float* __restrict__ k_k, const float* __restrict__ k_a,
    u16* __restrict__ stream)
{
    int g = blockIdx.x * 4 + (threadIdx.x >> 6);   // (token,head) pair: n = g>>4, h = g&15
    int lane = threadIdx.x & 63;
    int h = g & (Hx - 1);
    int n = g >> 4;
    size_t idx = (size_t)g * 64 + lane;            // == n*1024 + h*64 + lane
    int hd = h * 64 + lane;
    int l = n & (Lx - 1), b = n >> 11;
    size_t so = ((size_t)((b * 16 + h) * Lx + l)) * STEP_U16;

    float k = bf2f(Kb[idx]);
    float iclr = bf2f(ICLR[idx]);
    float kkn = k * k_k[hd];
    float s = kkn * kkn;
#pragma unroll
    for (int off = 32; off > 0; off >>= 1) s += __shfl_xor(s, off, 64);
    float nrm = fmaxf(sqrtf(s), 1e-7f);
    float kk = kkn / nrm;
    u16 knew = f2bf(k * (1.f + (iclr - 1.f) * k_a[hd]));
    float v = bf2f(Vb[idx]), vv = bf2f(VVb[idx]), vf = vfirst[idx];
    u16 vnew = f2bf(fmaf(vf - v, vv, v));
    stream[so + lane]       = Rb[idx];
    stream[so + 64 + lane]  = knew;
    stream[so + 128 + lane] = f2bf(-kk);
    stream[so + 192 + lane] = f2bf(kk * iclr);
    stream[so + 256 + lane] = vnew;
    stream[so + 320 + lane] = Wd16[idx];
}

// ---------------- WKV7 scan v9 (unchanged) ----------------
// 512 blocks = 64 (b,h) x 8 row-eighths, XCD-colocated; 4 waves/block;
// wave = 2 rows x 32 lanes, row lanes = {0-15 U 32-47} / {16-31 U 48-63};
// c=(lane&15)|((lane>>1)&16) owns cols 2c,2c+1. sa reduce = 4 DPP + permlane32_swap.
// y reduction deferred: per-step partial to padded LDS; per-batch flush sums.
__global__ __launch_bounds__(256, 2) void scan_kernel(
    const u16* __restrict__ stream, float* __restrict__ Y)
{
    const int bid = blockIdx.x;                   // 0..511; dispatch round-robins XCDs
    const int xcd = bid & 7, slot = bid >> 3;
    const int bh = xcd + ((slot & 7) << 3);       // 0..63: bh%8 == XCD -> co-located
    const int part = slot >> 3;                   // 0..7 (8 rows each)
    const int tid = threadIdx.x;
    const int lane = tid & 63;
    const int w = tid >> 6;
    const int c = (lane & 15) | ((lane >> 1) & 16);   // col-pair idx 0..31 (cols 2c,2c+1)
    const int rhalf = (lane >> 4) & 1;
    const int lr = w * 2 + rhalf;                 // local row 0..7
    const int row = part * 8 + lr;                // global row 0..63
    const size_t sbase = (size_t)bh * Lx * STEP_U16;
    const size_t ybase = (size_t)(bh >> 4) * ((size_t)Lx * Dx) + (size_t)(bh & 15) * 64;

    __shared__ __align__(16) u16 sbuf[2 * BATCH_U16];   // 24 KB
    __shared__ __align__(16) float yp[TB * 8 * 36];     // 18 KB padded partials

    float S0 = 0.f, S1 = 0.f;

    // stage batch 0 into buf 0 (wave w handles 1KB chunks 3w..3w+2)
    {
        const u16* g = stream + sbase;
#pragma unroll
        for (int cc = 0; cc < 3; ++cc) {
            const u16* gp = g + (3 * w + cc) * 512 + lane * 8;
            u16* lp = sbuf + (3 * w + cc) * 512;
            __builtin_amdgcn_global_load_lds(
                (const __attribute__((address_space(1))) void*)gp,
                (__attribute__((address_space(3))) void*)lp, 16, 0, 0);
        }
    }

    for (int bt = 0; bt < NB; ++bt) {
        const int cur = bt & 1;
        __syncthreads();   // vmcnt(0): batch bt resident; yp free from prev flush
        if (bt + 1 < NB) {
            const u16* g = stream + sbase + (size_t)(bt + 1) * BATCH_U16;
            u16* lbase = sbuf + (1 - cur) * BATCH_U16;
#pragma unroll
            for (int cc = 0; cc < 3; ++cc) {
                const u16* gp = g + (3 * w + cc) * 512 + lane * 8;
                u16* lp = lbase + (3 * w + cc) * 512;
                __builtin_amdgcn_global_load_lds(
                    (const __attribute__((address_space(1))) void*)gp,
                    (__attribute__((address_space(3))) void*)lp, 16, 0, 0);
            }
        }
        const u16* bp = sbuf + cur * BATCH_U16;
        const u16* cp = bp + c * 2;               // u16 offset 2c: cols 2c,2c+1
        u32 r2 = *(const u32*)(cp);
        u32 k2 = *(const u32*)(cp + 64);
        u32 a2 = *(const u32*)(cp + 128);
        u32 b2 = *(const u32*)(cp + 192);
        u32 w2 = *(const u32*)(cp + 320);
        float v = bf2f(bp[256 + row]);
#pragma unroll
        for (int s = 0; s < TB; ++s) {
            u32 nr = 0, nk = 0, na = 0, nb = 0, nw = 0;
            float nv = 0.f;
            if (s + 1 < TB) {          // compile-time under full unroll
                const u16* np = cp + (s + 1) * STEP_U16;
                nr = *(const u32*)(np);
                nk = *(const u32*)(np + 64);
                na = *(const u32*)(np + 128);
                nb = *(const u32*)(np + 192);
                nw = *(const u32*)(np + 320);
                nv = bf2f(bp[(s + 1) * STEP_U16 + 256 + row]);
            }
            float rr0, rr1, kk0, kk1, aa0, aa1, bb0, bb1, ww0, ww1;
            unpack2(r2, rr0, rr1);
            unpack2(k2, kk0, kk1);
            unpack2(a2, aa0, aa1);
            unpack2(b2, bb0, bb1);
            unpack2(w2, ww0, ww1);
            // sa_i = sum_j S_ij * a_j  (2 local + 32-lane all-VALU reduce)
            float sa = fmaf(S1, aa1, S0 * aa0);
            sa = red32(sa);
            // S_ij = S_ij*w_j + v_i*k_j + sa_i*b_j
            float t0 = fmaf(v, kk0, sa * bb0);
            float t1 = fmaf(v, kk1, sa * bb1);
            S0 = fmaf(S0, ww0, t0);
            S1 = fmaf(S1, ww1, t1);
            // y partial (2 cols) -> LDS; reduction deferred to flush
            float y = fmaf(S1, rr1, S0 * rr0);
            yp[(s * 8 + lr) * 36 + c] = y;
            r2 = nr; k2 = nk; a2 = na; b2 = nb; w2 = nw; v = nv;
        }
        __syncthreads();   // yp visible; batch bt+1 loads still in flight (vmem)
        // flush: 128 threads, each sums 32 partials of one (step,row) and stores
        if (tid < TB * 8) {
            const float* rp = &yp[tid * 36];
            f32x4 a4 = *(const f32x4*)(rp);
#pragma unroll
            for (int i = 1; i < 8; ++i) {
                f32x4 t4 = *(const f32x4*)(rp + i * 4);
                a4 += t4;
            }
            float yy = (a4[0] + a4[1]) + (a4[2] + a4[3]);
            int s = tid >> 3, j = tid & 7;
            Y[ybase + (size_t)(bt * TB + s) * Dx + part * 8 + j] = yy;
        }
    }
}

// ---------------- group-norm + rkr residual + gate (k/v from stream; OG in-place) ----------------
__global__ __launch_bounds__(256) void gnorm_kernel(
    const float* __restrict__ Y, const u16* __restrict__ Rb,
    const u16* __restrict__ stream, const float* __restrict__ r_k,
    const float* __restrict__ gnw, const float* __restrict__ gnb,
    u16* __restrict__ GATE_OG)
{
    int g = blockIdx.x * 4 + (threadIdx.x >> 6);
    int lane = threadIdx.x & 63;
    int h = g & (Hx - 1);
    int n = g >> 4;
    size_t idx = (size_t)g * 64 + lane;
    int hd = h * 64 + lane;
    int l = n & (Lx - 1), b = n >> 11;
    size_t so = ((size_t)((b * 16 + h) * Lx + l)) * STEP_U16;
    float y = Y[idx];
    float r = bf2f(Rb[idx]);
    float k = bf2f(stream[so + 64 + lane]);
    float v = bf2f(stream[so + 256 + lane]);
    float rkr = r * k * r_k[hd];
    float s1 = y, s2 = y * y, s3 = rkr;
#pragma unroll
    for (int off = 32; off > 0; off >>= 1) {
        s1 += __shfl_xor(s1, off, 64);
        s2 += __shfl_xor(s2, off, 64);
        s3 += __shfl_xor(s3, off, 64);
    }
    float mean = s1 * (1.f / 64.f);
    float var  = s2 * (1.f / 64.f) - mean * mean;
    float inv = 1.f / sqrtf(var + EPS_GN);
    float o = gnw[hd] * ((y - mean) * inv) + gnb[hd];
    o += s3 * v;
    GATE_OG[idx] = f2bf(o * bf2f(GATE_OG[idx]));
}

// ---------------- launch ----------------
extern "C" void kernel_launch(void* const* d_in, const int* in_sizes, int n_in,
                              void* d_out, int out_size, void* d_ws, size_t ws_size,
                              hipStream_t stream_)
{
    const float* x      = (const float*)d_in[0];
    const float* vfirst = (const float*)d_in[1];
    const float* x_r = (const float*)d_in[2];
    const float* x_w = (const float*)d_in[3];
    const float* x_k = (const float*)d_in[4];
    const float* x_v = (const float*)d_in[5];
    const float* x_a = (const float*)d_in[6];
    const float* x_g = (const float*)d_in[7];
    const float* k_k = (const float*)d_in[8];
    const float* k_a = (const float*)d_in[9];
    const float* r_k = (const float*)d_in[10];
    const float* Wr  = (const float*)d_in[11];
    const float* Wk  = (const float*)d_in[12];
    const float* Wv  = (const float*)d_in[13];
    const float* Wo  = (const float*)d_in[14];
    const float* gnw = (const float*)d_in[15];
    const float* gnb = (const float*)d_in[16];
    const float* wA  = (const float*)d_in[17];
    const float* wB  = (const float*)d_in[18];
    const float* wb  = (const float*)d_in[19];
    const float* vA  = (const float*)d_in[20];
    const float* vB  = (const float*)d_in[21];
    const float* vb  = (const float*)d_in[22];
    const float* aA  = (const float*)d_in[23];
    const float* aB  = (const float*)d_in[24];
    const float* ab  = (const float*)d_in[25];
    const float* gA  = (const float*)d_in[26];
    const float* gB  = (const float*)d_in[27];

    char* ws = (char*)d_ws;
    const size_t SLOT = (size_t)NTOK * Dx * 2;   // 16 MiB; 14 slots total (224 MiB, proven)
    u16* XR = (u16*)(ws + 0 * SLOT);
    u16* XW = (u16*)(ws + 1 * SLOT);
    u16* XK = (u16*)(ws + 2 * SLOT);
    u16* XV = (u16*)(ws + 3 * SLOT);
    u16* XA = (u16*)(ws + 4 * SLOT);
    u16* XG = (u16*)(ws + 5 * SLOT);
    u16* STREAM = (u16*)(ws + 0 * SLOT);         // 96MB, overwrites XR..XG after consumption
    u16* Rbuf = (u16*)(ws + 6 * SLOT);
    u16* Kbuf = (u16*)(ws + 7 * SLOT);
    u16* Vbuf = (u16*)(ws + 8 * SLOT);
    // slot 9 internal layout:
    u16* HW = (u16*)(ws + 9 * SLOT);             // lora hiddens (4.5MB)
    u16* HA = HW + (size_t)NTOK * 64;
    u16* HV = HA + (size_t)NTOK * 64;
    u16* HG = HV + (size_t)NTOK * 32;
    u16* Wo16 = HG + (size_t)NTOK * 128;         // +4.5MB, 2MB
    u16* SW = (u16*)(ws + 9 * SLOT + 8 * 1024 * 1024);  // small bf16 weights (1.2MB)
    u16* wAB = SW;
    u16* wBB = wAB + 65536;
    u16* vAB = wBB + 65536;
    u16* vBB = vAB + 32768;
    u16* aAB = vBB + 32768;
    u16* aBB = aAB + 65536;
    u16* gAB = aBB + 65536;
    u16* gBB = gAB + 131072;
    u16* Wr16 = (u16*)(ws + 9 * SLOT + 10 * 1024 * 1024);  // 3 x 2MB -> ends at 16MB
    u16* Wk16 = Wr16 + 1048576;
    u16* Wv16 = Wk16 + 1048576;
    u16* Wdec16 = (u16*)(ws + 10 * SLOT);        // bf16 decay; dead after prep_pack
    u16* ICLR   = (u16*)(ws + 11 * SLOT);        // dead after prep_pack
    u16* VVb    = (u16*)(ws + 12 * SLOT);        // dead after prep_pack
    float* Yb   = (float*)(ws + 10 * SLOT);      // fp32, slots 10-11 (aliases Wdec16/ICLR, ordered)
    u16* GATE   = (u16*)(ws + 13 * SLOT);        // gnorm writes OG in-place

    dim3 blk(256);
    // fused conv (12 tensors) + mix: blocks 0..8191 mix, 8192..20479 conv
    convmix_kernel<<<dim3(20480), blk, 0, stream_>>>(
        x, x_r, x_w, x_k, x_v, x_a, x_g, XR, XW, XK, XV, XA, XG,
        wA, wB, vA, vB, aA, aB, gA, gB, Wr, Wk, Wv, Wo,
        wAB, wBB, vAB, vBB, aAB, aBB, gAB, gBB, Wr16, Wk16, Wv16, Wo16);
    // fused projections: R/K/V GEMMs (z 0-2) + lora1 slices (z 3)
    proj_kernel<<<dim3(64, 8, 4), blk, 0, stream_>>>(
        XR, XK, XV, XW, XA, XG, Wr16, Wk16, Wv16, wAB, aAB, vAB, gAB,
        Rbuf, Kbuf, Vbuf, HW, HA, HV, HG);
    // fused lora stage 2: decay/iclr/vv/gate
    lora2_kernel<<<dim3(64, 8, 4), blk, 0, stream_>>>(
        HW, HA, HV, HG, wBB, aBB, vBB, gBB, wb, ab, vb, Wdec16, ICLR, VVb, GATE);

    prep_pack_kernel<<<(NTOK * Hx) / 4, blk, 0, stream_>>>(Kbuf, Vbuf, Rbuf, Wdec16, ICLR, VVb,
                                                           vfirst, k_k, k_a, STREAM);
    scan_kernel<<<512, blk, 0, stream_>>>(STREAM, Yb);
    gnorm_kernel<<<(NTOK * Hx) / 4, blk, 0, stream_>>>(Yb, Rbuf, STREAM, r_k, gnw, gnb, GATE);
    gemm_out_kernel<<<dim3(64, 8), blk, 0, stream_>>>(GATE, Wo16, (float*)d_out);
}

// Round 10
// 691.159 us; speedup vs baseline: 1.3273x; 1.0003x over previous
//
#include <hip/hip_runtime.h>
#include <cmath>

// RWKV7 time-mixing, B=4 L=2048 D=1024 H=16 Dh=64. Inputs/outputs fp32; internal bf16.
// convmix(fused) -> proj(RKV + lora1, grid.z) -> lora2(4-in-1, grid.z) -> prep_pack ->
// scan v10 (wide-read stream layout: RKAB-interleaved b128 reads; packed f32x2 math;
// XCD-colocated, permlane reduce, deferred y) -> gnorm(stream k/v) -> out GEMM.
// GEMMs: 2-phase double-buffered global_load_lds staging.

#define DEV __device__ __forceinline__

typedef unsigned short u16;
typedef unsigned int u32;
typedef __bf16 bf16x8 __attribute__((ext_vector_type(8)));
typedef float f32x4 __attribute__((ext_vector_type(4)));
typedef float f32x2 __attribute__((ext_vector_type(2)));

constexpr int Bx = 4, Lx = 2048, Dx = 1024, Hx = 16, Dh = 64;
constexpr int NTOK = Bx * Lx;       // 8192
constexpr float EPS_GN = 0.00064f;
// step layout (u16 offsets): [RKAB 32x{r2,k2,a2,b2} : 0..255][W 32xu32 : 256..319][V 64xu16 : 320..383]
constexpr int STEP_U16 = 384;       // 768B per step
constexpr int TB = 16;              // steps per scan batch
constexpr int NB = Lx / TB;         // 128 batches
constexpr int BATCH_U16 = TB * STEP_U16;   // 6144 u16 = 12288 B

DEV float bf2f(u16 u) { union { u32 i; float f; } c; c.i = ((u32)u) << 16; return c.f; }
DEV u16 f2bf(float f) {
    union { float f; u32 i; } c; c.f = f;
    u32 r = c.i + 0x7FFFu + ((c.i >> 16) & 1u);
    return (u16)(r >> 16);
}
DEV f32x2 up2(u32 u) {
    union { u32 i; float f; } c0, c1;
    c0.i = u << 16; c1.i = u & 0xFFFF0000u;
    f32x2 r; r.x = c0.f; r.y = c1.f; return r;
}

// DPP butterfly add: v + v[lane ^ mask] for masks {1,2,7,15}, pure VALU.
template <int CTRL>
DEV float dpp_add(float v) {
    int p = __builtin_amdgcn_update_dpp(0, __float_as_int(v), CTRL, 0xF, 0xF, true);
    return v + __int_as_float(p);
}

// xor32 add via v_permlane32_swap_b32 (pure VALU).
DEV float xor32_add(float x) {
    float a = x, b = x;
    asm volatile("s_nop 1\n\tv_permlane32_swap_b32 %0, %1" : "+v"(a), "+v"(b));
    return a + b;
}

// Full reduce over a 32-lane row laid out as 16-group pair {G, G^32} (lanes i, i+32):
// 4 DPP hops (16-group sums) + xor32 cross. All VALU, no LDS pipe.
DEV float red32(float x) {
    x = dpp_add<0xB1>(x);
    x = dpp_add<0x4E>(x);
    x = dpp_add<0x141>(x);
    x = dpp_add<0x140>(x);
    return xor32_add(x);
}

// ---------------- fused conv (12 tensors f32->bf16) + token-shift mix ----------------
// blocks 0..8191: mix; blocks 8192..20479: conv (t = (bid-8192)>>10).
__global__ __launch_bounds__(256) void convmix_kernel(
    const float* __restrict__ x,
    const float* __restrict__ mr, const float* __restrict__ mw, const float* __restrict__ mk,
    const float* __restrict__ mv, const float* __restrict__ ma, const float* __restrict__ mg,
    u16* __restrict__ XR, u16* __restrict__ XW, u16* __restrict__ XK,
    u16* __restrict__ XV, u16* __restrict__ XA, u16* __restrict__ XG,
    const float* s0, const float* s1, const float* s2, const float* s3,
    const float* s4, const float* s5, const float* s6, const float* s7,
    const float* s8, const float* s9, const float* s10, const float* s11,
    u16* d0, u16* d1, u16* d2, u16* d3, u16* d4, u16* d5, u16* d6, u16* d7,
    u16* d8, u16* d9, u16* d10, u16* d11)
{
    const int bid = blockIdx.x;
    const int tid = threadIdx.x;
    if (bid < 8192) {
        int gi = bid * 256 + tid;
        int n  = gi >> 8;
        int d4v = (gi & 255) << 2;
        int l  = n & (Lx - 1);
        size_t o = (size_t)n * Dx + d4v;
        float4 xc = *(const float4*)(x + o);
        float4 xp = make_float4(0.f, 0.f, 0.f, 0.f);
        if (l != 0) xp = *(const float4*)(x + o - Dx);
        float dx0 = xp.x - xc.x, dx1 = xp.y - xc.y, dx2 = xp.z - xc.z, dx3 = xp.w - xc.w;
        const float* mvs[6] = {mr, mw, mk, mv, ma, mg};
        u16* dsts[6] = {XR, XW, XK, XV, XA, XG};
#pragma unroll
        for (int j = 0; j < 6; ++j) {
            float4 m = *(const float4*)(mvs[j] + d4v);
            ushort4 r;
            r.x = f2bf(fmaf(dx0, m.x, xc.x));
            r.y = f2bf(fmaf(dx1, m.y, xc.y));
            r.z = f2bf(fmaf(dx2, m.z, xc.z));
            r.w = f2bf(fmaf(dx3, m.w, xc.w));
            *(ushort4*)(dsts[j] + o) = r;
        }
    } else {
        const float* srcs[12] = {s0,s1,s2,s3,s4,s5,s6,s7,s8,s9,s10,s11};
        u16* dsts[12] = {d0,d1,d2,d3,d4,d5,d6,d7,d8,d9,d10,d11};
        const int ns[12] = {65536,65536,32768,32768,65536,65536,131072,131072,
                            1048576,1048576,1048576,1048576};
        int cb = bid - 8192;
        int t = cb >> 10;
        int i = ((cb & 1023) * 256 + tid) * 4;
        if (i >= ns[t]) return;
        float4 v = *(const float4*)(srcs[t] + i);
        ushort4 o;
        o.x = f2bf(v.x); o.y = f2bf(v.y); o.z = f2bf(v.z); o.w = f2bf(v.w);
        *(ushort4*)(dsts[t] + i) = o;
    }
}

// ---------------- bf16 MFMA GEMM body, 2-phase double-buffered staging ----------------
// smem pool: [2][BM*BK] A + [2][BN*BK] B. ACT: 0 none, 1 sigmoid, 2 tanh, 3 exp(-.6*sig).
template <int BN, int ACT, bool BIAS, bool F32OUT>
DEV void gemm_body(u16* __restrict__ smem,
                   const u16* __restrict__ A, const u16* __restrict__ B16,
                   const float* __restrict__ bias, void* __restrict__ Cv,
                   int M, int N, int K, int bx, int by)
{
    constexpr int BM = 128, BK = 32;
    constexpr int WGM = (BN == 128) ? 2 : 4;
    constexpr int WGN = (BN == 128) ? 2 : 1;
    constexpr int WTM = BM / WGM, WTN = BN / WGN;
    constexpr int ITM = WTM / 16, ITN = WTN / 16;
    u16* Asm0 = smem;                       // 2 x BM*BK
    u16* Bsm0 = smem + 2 * BM * BK;         // 2 x BN*BK
    const int tid = threadIdx.x;
    const int wid = tid >> 6, lane = tid & 63;
    const int q = lane >> 4, r16 = lane & 15;
    const size_t m0 = (size_t)bx * BM;
    const size_t n0 = (size_t)by * BN;
    const int wm = (wid % WGM) * WTM;
    const int wn = (wid / WGM) * WTN;
    f32x4 acc[ITM][ITN];
    const f32x4 zf = {0.f, 0.f, 0.f, 0.f};
#pragma unroll
    for (int i = 0; i < ITM; ++i)
#pragma unroll
        for (int j = 0; j < ITN; ++j) acc[i][j] = zf;

    // prologue: stage tile 0 into buf 0
#pragma unroll
    for (int it = 0; it < 2; ++it) {
        int base = it * 2048 + wid * 512;
        int pp = base + lane * 8;
        int row = pp >> 5, col = pp & 31;
        __builtin_amdgcn_global_load_lds(
            (const __attribute__((address_space(1))) void*)(A + (m0 + row) * K + col),
            (__attribute__((address_space(3))) void*)(Asm0 + base), 16, 0, 0);
    }
#pragma unroll
    for (int it = 0; it < (BN * BK + 2047) / 2048; ++it) {
        int base = it * 2048 + wid * 512;
        if (BN * BK >= 2048 || base < BN * BK) {
            int pp = base + lane * 8;
            int row = pp >> 5, col = pp & 31;
            __builtin_amdgcn_global_load_lds(
                (const __attribute__((address_space(1))) void*)(B16 + (n0 + row) * K + col),
                (__attribute__((address_space(3))) void*)(Bsm0 + base), 16, 0, 0);
        }
    }

    int t = 0;
    for (int k0 = 0; k0 < K; k0 += BK, ++t) {
        const int cur = t & 1;
        __syncthreads();   // one barrier/tile: drains buf[cur] loads (issued a full phase ago)
        if (k0 + BK < K) {
            u16* An = Asm0 + (cur ^ 1) * (BM * BK);
            u16* Bn = Bsm0 + (cur ^ 1) * (BN * BK);
            const int kn = k0 + BK;
#pragma unroll
            for (int it = 0; it < 2; ++it) {
                int base = it * 2048 + wid * 512;
                int pp = base + lane * 8;
                int row = pp >> 5, col = pp & 31;
                __builtin_amdgcn_global_load_lds(
                    (const __attribute__((address_space(1))) void*)(A + (m0 + row) * K + kn + col),
                    (__attribute__((address_space(3))) void*)(An + base), 16, 0, 0);
            }
#pragma unroll
            for (int it = 0; it < (BN * BK + 2047) / 2048; ++it) {
                int base = it * 2048 + wid * 512;
                if (BN * BK >= 2048 || base < BN * BK) {
                    int pp = base + lane * 8;
                    int row = pp >> 5, col = pp & 31;
                    __builtin_amdgcn_global_load_lds(
                        (const __attribute__((address_space(1))) void*)(B16 + (n0 + row) * K + kn + col),
                        (__attribute__((address_space(3))) void*)(Bn + base), 16, 0, 0);
                }
            }
        }
        const u16* Ac = Asm0 + cur * (BM * BK);
        const u16* Bc = Bsm0 + cur * (BN * BK);
        bf16x8 af[ITM], bfr[ITN];
#pragma unroll
        for (int im = 0; im < ITM; ++im)
            af[im] = *(const bf16x8*)&Ac[(wm + im * 16 + r16) * BK + q * 8];
#pragma unroll
        for (int in = 0; in < ITN; ++in)
            bfr[in] = *(const bf16x8*)&Bc[(wn + in * 16 + r16) * BK + q * 8];
#pragma unroll
        for (int im = 0; im < ITM; ++im)
#pragma unroll
            for (int in = 0; in < ITN; ++in)
                acc[im][in] = __builtin_amdgcn_mfma_f32_16x16x32_bf16(af[im], bfr[in], acc[im][in], 0, 0, 0);
    }
#pragma unroll
    for (int im = 0; im < ITM; ++im) {
#pragma unroll
        for (int in = 0; in < ITN; ++in) {
#pragma unroll
            for (int e = 0; e < 4; ++e) {
                size_t row = m0 + wm + im * 16 + q * 4 + e;
                size_t col = n0 + wn + in * 16 + r16;
                float val = acc[im][in][e];
                if constexpr (BIAS) val += bias[col];
                if constexpr (ACT == 1) val = 1.f / (1.f + __expf(-val));
                else if constexpr (ACT == 2) val = tanhf(val);
                else if constexpr (ACT == 3) val = __expf(-0.606531f / (1.f + __expf(-val)));
                if constexpr (F32OUT) ((float*)Cv)[row * (size_t)N + col] = val;
                else ((u16*)Cv)[row * (size_t)N + col] = f2bf(val);
            }
        }
    }
}

// Runtime act/bias variant (BM=BN=128, bf16 out), same 2-phase staging.
DEV void gemm_body_rt(u16* __restrict__ smem,
                      const u16* __restrict__ A, const u16* __restrict__ B16,
                      const float* __restrict__ bias, u16* __restrict__ C,
                      int N, int K, int act, int bx, int by)
{
    constexpr int BM = 128, BK = 32;
    constexpr int ITM = 4, ITN = 4;
    u16* Asm0 = smem;
    u16* Bsm0 = smem + 2 * BM * BK;
    const int tid = threadIdx.x;
    const int wid = tid >> 6, lane = tid & 63;
    const int q = lane >> 4, r16 = lane & 15;
    const size_t m0 = (size_t)bx * BM;
    const size_t n0 = (size_t)by * 128;
    const int wm = (wid % 2) * 64;
    const int wn = (wid / 2) * 64;
    f32x4 acc[ITM][ITN];
    const f32x4 zf = {0.f, 0.f, 0.f, 0.f};
#pragma unroll
    for (int i = 0; i < ITM; ++i)
#pragma unroll
        for (int j = 0; j < ITN; ++j) acc[i][j] = zf;

#pragma unroll
    for (int it = 0; it < 2; ++it) {
        int base = it * 2048 + wid * 512;
        int pp = base + lane * 8;
        int row = pp >> 5, col = pp & 31;
        __builtin_amdgcn_global_load_lds(
            (const __attribute__((address_space(1))) void*)(A + (m0 + row) * K + col),
            (__attribute__((address_space(3))) void*)(Asm0 + base), 16, 0, 0);
        __builtin_amdgcn_global_load_lds(
            (const __attribute__((address_space(1))) void*)(B16 + (n0 + row) * K + col),
            (__attribute__((address_space(3))) void*)(Bsm0 + base), 16, 0, 0);
    }

    int t = 0;
    for (int k0 = 0; k0 < K; k0 += BK, ++t) {
        const int cur = t & 1;
        __syncthreads();
        if (k0 + BK < K) {
            u16* An = Asm0 + (cur ^ 1) * (BM * BK);
            u16* Bn = Bsm0 + (cur ^ 1) * (BM * BK);
            const int kn = k0 + BK;
#pragma unroll
            for (int it = 0; it < 2; ++it) {
                int base = it * 2048 + wid * 512;
                int pp = base + lane * 8;
                int row = pp >> 5, col = pp & 31;
                __builtin_amdgcn_global_load_lds(
                    (const __attribute__((address_space(1))) void*)(A + (m0 + row) * K + kn + col),
                    (__attribute__((address_space(3))) void*)(An + base), 16, 0, 0);
                __builtin_amdgcn_global_load_lds(
                    (const __attribute__((address_space(1))) void*)(B16 + (n0 + row) * K + kn + col),
                    (__attribute__((address_space(3))) void*)(Bn + base), 16, 0, 0);
            }
        }
        const u16* Ac = Asm0 + cur * (BM * BK);
        const u16* Bc = Bsm0 + cur * (BM * BK);
        bf16x8 af[ITM], bfr[ITN];
#pragma unroll
        for (int im = 0; im < ITM; ++im)
            af[im] = *(const bf16x8*)&Ac[(wm + im * 16 + r16) * BK + q * 8];
#pragma unroll
        for (int in = 0; in < ITN; ++in)
            bfr[in] = *(const bf16x8*)&Bc[(wn + in * 16 + r16) * BK + q * 8];
#pragma unroll
        for (int im = 0; im < ITM; ++im)
#pragma unroll
            for (int in = 0; in < ITN; ++in)
                acc[im][in] = __builtin_amdgcn_mfma_f32_16x16x32_bf16(af[im], bfr[in], acc[im][in], 0, 0, 0);
    }
#pragma unroll
    for (int im = 0; im < ITM; ++im) {
#pragma unroll
        for (int in = 0; in < ITN; ++in) {
#pragma unroll
            for (int e = 0; e < 4; ++e) {
                size_t row = m0 + wm + im * 16 + q * 4 + e;
                size_t col = n0 + wn + in * 16 + r16;
                float val = acc[im][in][e];
                if (bias) val += bias[col];
                if (act == 1) val = 1.f / (1.f + __expf(-val));
                else if (act == 3) val = __expf(-0.606531f / (1.f + __expf(-val)));
                C[row * (size_t)N + col] = f2bf(val);
            }
        }
    }
}

// lora1 body (BM=128, BN=64, K=1024), 2-phase staging in shared pool, cfg selects slice.
DEV void lora1_body(u16* __restrict__ smem, int cfg,
    const u16* __restrict__ XW, const u16* __restrict__ XA,
    const u16* __restrict__ XV, const u16* __restrict__ XG,
    const u16* __restrict__ wAB, const u16* __restrict__ aAB,
    const u16* __restrict__ vAB, const u16* __restrict__ gAB,
    u16* __restrict__ HW, u16* __restrict__ HA,
    u16* __restrict__ HV, u16* __restrict__ HG, int bx)
{
    constexpr int BM = 128, BK = 32, K = 1024;
    constexpr int ITM = 2, ITN = 4;   // wave: 32 rows x 64 cols
    const u16* A; const u16* Bm; u16* C; int ldC, Nv, act;
    if (cfg == 0)      { A = XW; Bm = wAB;            C = HW;      ldC = 64;  Nv = 64; act = 2; }
    else if (cfg == 1) { A = XA; Bm = aAB;            C = HA;      ldC = 64;  Nv = 64; act = 0; }
    else if (cfg == 2) { A = XV; Bm = vAB;            C = HV;      ldC = 32;  Nv = 32; act = 0; }
    else if (cfg == 3) { A = XG; Bm = gAB;            C = HG;      ldC = 128; Nv = 64; act = 1; }
    else               { A = XG; Bm = gAB + 64 * K;   C = HG + 64; ldC = 128; Nv = 64; act = 1; }

    u16* Asm0 = smem;                 // 2 x 4096
    u16* Bsm0 = smem + 2 * BM * BK;   // 2 x 2048
    const int tid = threadIdx.x;
    const int wid = tid >> 6, lane = tid & 63;
    const int q = lane >> 4, r16 = lane & 15;
    const size_t m0 = (size_t)bx * BM;
    const int wm = wid * 32;
    f32x4 acc[ITM][ITN];
    const f32x4 zf = {0.f, 0.f, 0.f, 0.f};
#pragma unroll
    for (int i = 0; i < ITM; ++i)
#pragma unroll
        for (int j = 0; j < ITN; ++j) acc[i][j] = zf;

#pragma unroll
    for (int it = 0; it < 2; ++it) {
        int base = it * 2048 + wid * 512;
        int pp = base + lane * 8;
        int row = pp >> 5, col = pp & 31;
        __builtin_amdgcn_global_load_lds(
            (const __attribute__((address_space(1))) void*)(A + (m0 + row) * K + col),
            (__attribute__((address_space(3))) void*)(Asm0 + base), 16, 0, 0);
    }
    {
        int base = wid * 512;
        int pp = base + lane * 8;
        int row = pp >> 5, col = pp & 31;
        __builtin_amdgcn_global_load_lds(
            (const __attribute__((address_space(1))) void*)(Bm + row * K + col),
            (__attribute__((address_space(3))) void*)(Bsm0 + base), 16, 0, 0);
    }

    int t = 0;
    for (int k0 = 0; k0 < K; k0 += BK, ++t) {
        const int cur = t & 1;
        __syncthreads();
        if (k0 + BK < K) {
            u16* An = Asm0 + (cur ^ 1) * (BM * BK);
            u16* Bn = Bsm0 + (cur ^ 1) * 2048;
            const int kn = k0 + BK;
#pragma unroll
            for (int it = 0; it < 2; ++it) {
                int base = it * 2048 + wid * 512;
                int pp = base + lane * 8;
                int row = pp >> 5, col = pp & 31;
                __builtin_amdgcn_global_load_lds(
                    (const __attribute__((address_space(1))) void*)(A + (m0 + row) * K + kn + col),
                    (__attribute__((address_space(3))) void*)(An + base), 16, 0, 0);
            }
            {
                int base = wid * 512;
                int pp = base + lane * 8;
                int row = pp >> 5, col = pp & 31;
                __builtin_amdgcn_global_load_lds(
                    (const __attribute__((address_space(1))) void*)(Bm + row * K + kn + col),
                    (__attribute__((address_space(3))) void*)(Bn + base), 16, 0, 0);
            }
        }
        const u16* Ac = Asm0 + cur * (BM * BK);
        const u16* Bc = Bsm0 + cur * 2048;
        bf16x8 af[ITM], bfr[ITN];
#pragma unroll
        for (int im = 0; im < ITM; ++im)
            af[im] = *(const bf16x8*)&Ac[(wm + im * 16 + r16) * BK + q * 8];
#pragma unroll
        for (int in = 0; in < ITN; ++in)
            bfr[in] = *(const bf16x8*)&Bc[(in * 16 + r16) * BK + q * 8];
#pragma unroll
        for (int im = 0; im < ITM; ++im)
#pragma unroll
            for (int in = 0; in < ITN; ++in)
                acc[im][in] = __builtin_amdgcn_mfma_f32_16x16x32_bf16(af[im], bfr[in], acc[im][in], 0, 0, 0);
    }
#pragma unroll
    for (int im = 0; im < ITM; ++im) {
#pragma unroll
        for (int in = 0; in < ITN; ++in) {
#pragma unroll
            for (int e = 0; e < 4; ++e) {
                size_t row = m0 + wm + im * 16 + q * 4 + e;
                int col = in * 16 + r16;
                if (col < Nv) {
                    float val = acc[im][in][e];
                    if (act == 1) val = 1.f / (1.f + __expf(-val));
                    else if (act == 2) val = tanhf(val);
                    C[row * (size_t)ldC + col] = f2bf(val);
                }
            }
        }
    }
}

// fused projections: z 0-2 = R/K/V GEMMs; z=3 = lora1 slices (y=cfg, y>=5 idle)
__global__ __launch_bounds__(256) void proj_kernel(
    const u16* __restrict__ XR, const u16* __restrict__ XK, const u16* __restrict__ XV,
    const u16* __restrict__ XW, const u16* __restrict__ XA, const u16* __restrict__ XG,
    const u16* __restrict__ Wr16, const u16* __restrict__ Wk16, const u16* __restrict__ Wv16,
    const u16* __restrict__ wAB, const u16* __restrict__ aAB,
    const u16* __restrict__ vAB, const u16* __restrict__ gAB,
    u16* __restrict__ Rbuf, u16* __restrict__ Kbuf, u16* __restrict__ Vbuf,
    u16* __restrict__ HW, u16* __restrict__ HA, u16* __restrict__ HV, u16* __restrict__ HG)
{
    __shared__ __align__(16) u16 pool[16384];   // 32 KB
    const int z = blockIdx.z;
    if (z < 3) {
        const u16* A; const u16* Bm; u16* C;
        if (z == 0)      { A = XR; Bm = Wr16; C = Rbuf; }
        else if (z == 1) { A = XK; Bm = Wk16; C = Kbuf; }
        else             { A = XV; Bm = Wv16; C = Vbuf; }
        gemm_body<128, 0, false, false>(pool, A, Bm, nullptr, C, NTOK, 1024, 1024,
                                        blockIdx.x, blockIdx.y);
    } else {
        if (blockIdx.y >= 5) return;
        lora1_body(pool, blockIdx.y, XW, XA, XV, XG, wAB, aAB, vAB, gAB, HW, HA, HV, HG,
                   blockIdx.x);
    }
}

// fused lora stage-2: z selects {decay, iclr, vv, gate}
__global__ __launch_bounds__(256) void lora2_kernel(
    const u16* __restrict__ HW, const u16* __restrict__ HA,
    const u16* __restrict__ HV, const u16* __restrict__ HG,
    const u16* __restrict__ wBB, const u16* __restrict__ aBB,
    const u16* __restrict__ vBB, const u16* __restrict__ gBB,
    const float* __restrict__ wb, const float* __restrict__ ab, const float* __restrict__ vb,
    u16* __restrict__ Wdec16, u16* __restrict__ ICLR,
    u16* __restrict__ VVb, u16* __restrict__ GATE)
{
    __shared__ __align__(16) u16 pool[16384];
    const int z = blockIdx.z;
    const u16* A; const u16* Bm; const float* bias; u16* C; int K, act;
    if (z == 0)      { A = HW; Bm = wBB; bias = wb;      C = Wdec16; K = 64;  act = 3; }
    else if (z == 1) { A = HA; Bm = aBB; bias = ab;      C = ICLR;   K = 64;  act = 1; }
    else if (z == 2) { A = HV; Bm = vBB; bias = vb;      C = VVb;    K = 32;  act = 1; }
    else             { A = HG; Bm = gBB; bias = nullptr; C = GATE;   K = 128; act = 0; }
    gemm_body_rt(pool, A, Bm, bias, C, 1024, K, act, blockIdx.x, blockIdx.y);
}

// final output GEMM (f32 out)
__global__ __launch_bounds__(256) void gemm_out_kernel(
    const u16* __restrict__ A, const u16* __restrict__ B16, float* __restrict__ C)
{
    __shared__ __align__(16) u16 pool[16384];
    gemm_body<128, 0, false, true>(pool, A, B16, nullptr, C, NTOK, 1024, 1024,
                                   blockIdx.x, blockIdx.y);
}

// ---------------- prep + pack: kk-norm, a/b, k/v updates, emit wide-layout stream ----------------
// step layout (u16): [RKAB: c=0..31 x {r2,k2,a2,b2} u32s][W: c*u32 at 256][V: u16 at 320+d]
__global__ __launch_bounds__(256) void prep_pack_kernel(
    const u16* __restrict__ Kb, const u16* __restrict__ Vb,
    const u16* __restrict__ Rb, const u16* __restrict__ Wd16,
    const u16* __restrict__ ICLR, const u16* __restrict__ VVb, const float* __restrict__ vfirst,
    const float* __restrict__ k_k, const float* __restrict__ k_a,
    u16* __restrict__ stream)
{
    int g = blockIdx.x * 4 + (threadIdx.x >> 6);   // (token,head) pair: n = g>>4, h = g&15
    int lane = threadIdx.x & 63;
    int h = g & (Hx - 1);
    int n = g >> 4;
    size_t idx = (size_t)g * 64 + lane;            // == n*1024 + h*64 + lane
    int hd = h * 64 + lane;
    int l = n & (Lx - 1), b = n >> 11;
    size_t so = ((size_t)((b * 16 + h) * Lx + l)) * STEP_U16;

    float k = bf2f(Kb[idx]);
    float iclr = bf2f(ICLR[idx]);
    float kkn = k * k_k[hd];
    float s = kkn * kkn;
#pragma unroll
    for (int off = 32; off > 0; off >>= 1) s += __shfl_xor(s, off, 64);
    float nrm = fmaxf(sqrtf(s), 1e-7f);
    float kk = kkn / nrm;
    u16 knew = f2bf(k * (1.f + (iclr - 1.f) * k_a[hd]));
    float v = bf2f(Vb[idx]), vv = bf2f(VVb[idx]), vf = vfirst[idx];
    u16 vnew = f2bf(fmaf(vf - v, vv, v));

    // pair-pack: even lane = lo (col 2c), odd partner = hi (col 2c+1), c = lane>>1
    int r_ = Rb[idx];        int r_p = __shfl_xor(r_, 1, 64);
    int k_ = (int)knew;      int k_p = __shfl_xor(k_, 1, 64);
    float a_ = -kk;          float a_p = __shfl_xor(a_, 1, 64);
    float b_ = kk * iclr;    float b_p = __shfl_xor(b_, 1, 64);
    int w_ = Wd16[idx];      int w_p = __shfl_xor(w_, 1, 64);
    if ((lane & 1) == 0) {
        int c = lane >> 1;
        uint4 rkab;
        rkab.x = (u32)(r_ & 0xFFFF) | ((u32)(r_p & 0xFFFF) << 16);
        rkab.y = (u32)(k_ & 0xFFFF) | ((u32)(k_p & 0xFFFF) << 16);
        rkab.z = (u32)f2bf(a_) | ((u32)f2bf(a_p) << 16);
        rkab.w = (u32)f2bf(b_) | ((u32)f2bf(b_p) << 16);
        *(uint4*)(stream + so + c * 8) = rkab;
        *(u32*)(stream + so + 256 + c * 2) =
            (u32)(w_ & 0xFFFF) | ((u32)(w_p & 0xFFFF) << 16);
    }
    stream[so + 320 + lane] = vnew;
}

// ---------------- WKV7 scan v10 ----------------
// v9 structure; NEW: wide-layout stream -> per step 1 ds_read_b128 (r,k,a,b) +
// 1 b32 (w) + 1 u16 (v) instead of 5 b32 + u16. Packed f32x2 step math
// (v_pk_fma_f32). sa reduce = 4 DPP + permlane32_swap; y deferred to flush.
__global__ __launch_bounds__(256, 2) void scan_kernel(
    const u16* __restrict__ stream, float* __restrict__ Y)
{
    const int bid = blockIdx.x;                   // 0..511; dispatch round-robins XCDs
    const int xcd = bid & 7, slot = bid >> 3;
    const int bh = xcd + ((slot & 7) << 3);       // 0..63: bh%8 == XCD -> co-located
    const int part = slot >> 3;                   // 0..7 (8 rows each)
    const int tid = threadIdx.x;
    const int lane = tid & 63;
    const int w = tid >> 6;
    const int c = (lane & 15) | ((lane >> 1) & 16);   // col-pair idx 0..31 (cols 2c,2c+1)
    const int rhalf = (lane >> 4) & 1;
    const int lr = w * 2 + rhalf;                 // local row 0..7
    const int row = part * 8 + lr;                // global row 0..63
    const size_t sbase = (size_t)bh * Lx * STEP_U16;
    const size_t ybase = (size_t)(bh >> 4) * ((size_t)Lx * Dx) + (size_t)(bh & 15) * 64;

    __shared__ __align__(16) u16 sbuf[2 * BATCH_U16];   // 24 KB
    __shared__ __align__(16) float yp[TB * 8 * 36];     // 18 KB padded partials

    f32x2 S = {0.f, 0.f};

    // stage batch 0 into buf 0 (wave w handles 1KB chunks 3w..3w+2)
    {
        const u16* g = stream + sbase;
#pragma unroll
        for (int cc = 0; cc < 3; ++cc) {
            const u16* gp = g + (3 * w + cc) * 512 + lane * 8;
            u16* lp = sbuf + (3 * w + cc) * 512;
            __builtin_amdgcn_global_load_lds(
                (const __attribute__((address_space(1))) void*)gp,
                (__attribute__((address_space(3))) void*)lp, 16, 0, 0);
        }
    }

    for (int bt = 0; bt < NB; ++bt) {
        const int cur = bt & 1;
        __syncthreads();   // vmcnt(0): batch bt resident; yp free from prev flush
        if (bt + 1 < NB) {
            const u16* g = stream + sbase + (size_t)(bt + 1) * BATCH_U16;
            u16* lbase = sbuf + (1 - cur) * BATCH_U16;
#pragma unroll
            for (int cc = 0; cc < 3; ++cc) {
                const u16* gp = g + (3 * w + cc) * 512 + lane * 8;
                u16* lp = lbase + (3 * w + cc) * 512;
                __builtin_amdgcn_global_load_lds(
                    (const __attribute__((address_space(1))) void*)gp,
                    (__attribute__((address_space(3))) void*)lp, 16, 0, 0);
            }
        }
        const u16* bp = sbuf + cur * BATCH_U16;
        const u16* cp = bp + c * 8;               // 16B-aligned RKAB group
        const u16* wp = bp + 256 + c * 2;
        uint4 rkab = *(const uint4*)cp;
        u32 w2 = *(const u32*)wp;
        float v = bf2f(bp[320 + row]);
#pragma unroll
        for (int s = 0; s < TB; ++s) {
            uint4 nrkab = {0, 0, 0, 0}; u32 nw = 0; float nv = 0.f;
            if (s + 1 < TB) {          // compile-time under full unroll
                nrkab = *(const uint4*)(cp + (s + 1) * STEP_U16);
                nw = *(const u32*)(wp + (s + 1) * STEP_U16);
                nv = bf2f(bp[(s + 1) * STEP_U16 + 320 + row]);
            }
            f32x2 rr = up2(rkab.x), kk = up2(rkab.y);
            f32x2 aa = up2(rkab.z), bb = up2(rkab.w), ww = up2(w2);
            // sa_i = sum_j S_ij * a_j  (packed partial + 32-lane all-VALU reduce)
            f32x2 p = S * aa;
            float sa = p.x + p.y;
            sa = red32(sa);
            // S_ij = S_ij*w_j + v_i*k_j + sa_i*b_j   (v_pk_fma_f32)
            f32x2 sav = {sa, sa}, vv2 = {v, v};
            S = __builtin_elementwise_fma(S, ww,
                    __builtin_elementwise_fma(vv2, kk, sav * bb));
            // y partial (2 cols) -> LDS; reduction deferred to flush
            f32x2 q = S * rr;
            yp[(s * 8 + lr) * 36 + c] = q.x + q.y;
            rkab = nrkab; w2 = nw; v = nv;
        }
        __syncthreads();   // yp visible; batch bt+1 loads still in flight (vmem)
        // flush: 128 threads, each sums 32 partials of one (step,row) and stores
        if (tid < TB * 8) {
            const float* rp = &yp[tid * 36];
            f32x4 a4 = *(const f32x4*)(rp);
#pragma unroll
            for (int i = 1; i < 8; ++i) {
                f32x4 t4 = *(const f32x4*)(rp + i * 4);
                a4 += t4;
            }
            float yy = (a4[0] + a4[1]) + (a4[2] + a4[3]);
            int s = tid >> 3, j = tid & 7;
            Y[ybase + (size_t)(bt * TB + s) * Dx + part * 8 + j] = yy;
        }
    }
}

// ---------------- group-norm + rkr residual + gate (k/v from wide stream; OG in-place) ----------------
__global__ __launch_bounds__(256) void gnorm_kernel(
    const float* __restrict__ Y, const u16* __restrict__ Rb,
    const u16* __restrict__ stream, const float* __restrict__ r_k,
    const float* __restrict__ gnw, const float* __restrict__ gnb,
    u16* __restrict__ GATE_OG)
{
    int g = blockIdx.x * 4 + (threadIdx.x >> 6);
    int lane = threadIdx.x & 63;
    int h = g & (Hx - 1);
    int n = g >> 4;
    size_t idx = (size_t)g * 64 + lane;
    int hd = h * 64 + lane;
    int l = n & (Lx - 1), b = n >> 11;
    size_t so = ((size_t)((b * 16 + h) * Lx + l)) * STEP_U16;
    float y = Y[idx];
    float r = bf2f(Rb[idx]);
    // wide layout: k of col d at (d>>1)*8 + 2 + (d&1); v at 320 + d
    float k = bf2f(stream[so + (lane >> 1) * 8 + 2 + (lane & 1)]);
    float v = bf2f(stream[so + 320 + lane]);
    float rkr = r * k * r_k[hd];
    float s1 = y, s2 = y * y, s3 = rkr;
#pragma unroll
    for (int off = 32; off > 0; off >>= 1) {
        s1 += __shfl_xor(s1, off, 64);
        s2 += __shfl_xor(s2, off, 64);
        s3 += __shfl_xor(s3, off, 64);
    }
    float mean = s1 * (1.f / 64.f);
    float var  = s2 * (1.f / 64.f) - mean * mean;
    float inv = 1.f / sqrtf(var + EPS_GN);
    float o = gnw[hd] * ((y - mean) * inv) + gnb[hd];
    o += s3 * v;
    GATE_OG[idx] = f2bf(o * bf2f(GATE_OG[idx]));
}

// ---------------- launch ----------------
extern "C" void kernel_launch(void* const* d_in, const int* in_sizes, int n_in,
                              void* d_out, int out_size, void* d_ws, size_t ws_size,
                              hipStream_t stream_)
{
    const float* x      = (const float*)d_in[0];
    const float* vfirst = (const float*)d_in[1];
    const float* x_r = (const float*)d_in[2];
    const float* x_w = (const float*)d_in[3];
    const float* x_k = (const float*)d_in[4];
    const float* x_v = (const float*)d_in[5];
    const float* x_a = (const float*)d_in[6];
    const float* x_g = (const float*)d_in[7];
    const float* k_k = (const float*)d_in[8];
    const float* k_a = (const float*)d_in[9];
    const float* r_k = (const float*)d_in[10];
    const float* Wr  = (const float*)d_in[11];
    const float* Wk  = (const float*)d_in[12];
    const float* Wv  = (const float*)d_in[13];
    const float* Wo  = (const float*)d_in[14];
    const float* gnw = (const float*)d_in[15];
    const float* gnb = (const float*)d_in[16];
    const float* wA  = (const float*)d_in[17];
    const float* wB  = (const float*)d_in[18];
    const float* wb  = (const float*)d_in[19];
    const float* vA  = (const float*)d_in[20];
    const float* vB  = (const float*)d_in[21];
    const float* vb  = (const float*)d_in[22];
    const float* aA  = (const float*)d_in[23];
    const float* aB  = (const float*)d_in[24];
    const float* ab  = (const float*)d_in[25];
    const float* gA  = (const float*)d_in[26];
    const float* gB  = (const float*)d_in[27];

    char* ws = (char*)d_ws;
    const size_t SLOT = (size_t)NTOK * Dx * 2;   // 16 MiB; 14 slots total (224 MiB, proven)
    u16* XR = (u16*)(ws + 0 * SLOT);
    u16* XW = (u16*)(ws + 1 * SLOT);
    u16* XK = (u16*)(ws + 2 * SLOT);
    u16* XV = (u16*)(ws + 3 * SLOT);
    u16* XA = (u16*)(ws + 4 * SLOT);
    u16* XG = (u16*)(ws + 5 * SLOT);
    u16* STREAM = (u16*)(ws + 0 * SLOT);         // 96MB, overwrites XR..XG after consumption
    u16* Rbuf = (u16*)(ws + 6 * SLOT);
    u16* Kbuf = (u16*)(ws + 7 * SLOT);
    u16* Vbuf = (u16*)(ws + 8 * SLOT);
    // slot 9 internal layout:
    u16* HW = (u16*)(ws + 9 * SLOT);             // lora hiddens (4.5MB)
    u16* HA = HW + (size_t)NTOK * 64;
    u16* HV = HA + (size_t)NTOK * 64;
    u16* HG = HV + (size_t)NTOK * 32;
    u16* Wo16 = HG + (size_t)NTOK * 128;         // +4.5MB, 2MB
    u16* SW = (u16*)(ws + 9 * SLOT + 8 * 1024 * 1024);  // small bf16 weights (1.2MB)
    u16* wAB = SW;
    u16* wBB = wAB + 65536;
    u16* vAB = wBB + 65536;
    u16* vBB = vAB + 32768;
    u16* aAB = vBB + 32768;
    u16* aBB = aAB + 65536;
    u16* gAB = aBB + 65536;
    u16* gBB = gAB + 131072;
    u16* Wr16 = (u16*)(ws + 9 * SLOT + 10 * 1024 * 1024);  // 3 x 2MB -> ends at 16MB
    u16* Wk16 = Wr16 + 1048576;
    u16* Wv16 = Wk16 + 1048576;
    u16* Wdec16 = (u16*)(ws + 10 * SLOT);        // bf16 decay; dead after prep_pack
    u16* ICLR   = (u16*)(ws + 11 * SLOT);        // dead after prep_pack
    u16* VVb    = (u16*)(ws + 12 * SLOT);        // dead after prep_pack
    float* Yb   = (float*)(ws + 10 * SLOT);      // fp32, slots 10-11 (aliases Wdec16/ICLR, ordered)
    u16* GATE   = (u16*)(ws + 13 * SLOT);        // gnorm writes OG in-place

    dim3 blk(256);
    // fused conv (12 tensors) + mix: blocks 0..8191 mix, 8192..20479 conv
    convmix_kernel<<<dim3(20480), blk, 0, stream_>>>(
        x, x_r, x_w, x_k, x_v, x_a, x_g, XR, XW, XK, XV, XA, XG,
        wA, wB, vA, vB, aA, aB, gA, gB, Wr, Wk, Wv, Wo,
        wAB, wBB, vAB, vBB, aAB, aBB, gAB, gBB, Wr16, Wk16, Wv16, Wo16);
    // fused projections: R/K/V GEMMs (z 0-2) + lora1 slices (z 3)
    proj_kernel<<<dim3(64, 8, 4), blk, 0, stream_>>>(
        XR, XK, XV, XW, XA, XG, Wr16, Wk16, Wv16, wAB, aAB, vAB, gAB,
        Rbuf, Kbuf, Vbuf, HW, HA, HV, HG);
    // fused lora stage 2: decay/iclr/vv/gate
    lora2_kernel<<<dim3(64, 8, 4), blk, 0, stream_>>>(
        HW, HA, HV, HG, wBB, aBB, vBB, gBB, wb, ab, vb, Wdec16, ICLR, VVb, GATE);

    prep_pack_kernel<<<(NTOK * Hx) / 4, blk, 0, stream_>>>(Kbuf, Vbuf, Rbuf, Wdec16, ICLR, VVb,
                                                           vfirst, k_k, k_a, STREAM);
    scan_kernel<<<512, blk, 0, stream_>>>(STREAM, Yb);
    gnorm_kernel<<<(NTOK * Hx) / 4, blk, 0, stream_>>>(Yb, Rbuf, STREAM, r_k, gnw, gnb, GATE);
    gemm_out_kernel<<<dim3(64, 8), blk, 0, stream_>>>(GATE, Wo16, (float*)d_out);
}